// Round 3
// baseline (1191.172 us; speedup 1.0000x reference)
//
#include <hip/hip_runtime.h>
#include <hip/hip_bf16.h>

typedef unsigned short u16;

#define NN 50000
#define NE 800000

__device__ __forceinline__ float bf2f(u16 u) { return __uint_as_float(((unsigned)u) << 16); }
__device__ __forceinline__ u16 f2bf(float f) {
  unsigned u = __float_as_uint(f);
  return (u16)((u + 0x7FFFu + ((u >> 16) & 1u)) >> 16);
}

// ---------------- CSR build ----------------
__global__ void k_zero(int* __restrict__ deg) {
  int i = blockIdx.x * 256 + threadIdx.x;
  if (i < NN) deg[i] = 0;
}

__global__ void k_hist(const int* __restrict__ ei, int* __restrict__ deg) {
  int i = blockIdx.x * 256 + threadIdx.x;
  if (i < NE) {
    int d = ei[NE + i];
    if (d >= 0 && d < NN) atomicAdd(&deg[d], 1);
  }
}

#define SCAN_T 1024
#define SCAN_CH 49
__global__ __launch_bounds__(1024) void k_scan(const int* __restrict__ deg,
                                               int* __restrict__ rowptr,
                                               int* __restrict__ cursor) {
  __shared__ int sums[SCAN_T];
  const int t = threadIdx.x;
  const int start = t * SCAN_CH;
  int lsum = 0;
  for (int i = 0; i < SCAN_CH; ++i) {
    int idx = start + i;
    if (idx < NN) lsum += deg[idx];
  }
  sums[t] = lsum;
  __syncthreads();
  for (int offs = 1; offs < SCAN_T; offs <<= 1) {
    int v = (t >= offs) ? sums[t - offs] : 0;
    __syncthreads();
    sums[t] += v;
    __syncthreads();
  }
  int run = (t == 0) ? 0 : sums[t - 1];
  for (int i = 0; i < SCAN_CH; ++i) {
    int idx = start + i;
    if (idx < NN) {
      rowptr[idx] = run;
      cursor[idx] = run;
      run += deg[idx];
    }
  }
  if (t == SCAN_T - 1) rowptr[NN] = run;
}

__global__ void k_scatter(const int* __restrict__ ei, int* __restrict__ cursor,
                          int* __restrict__ elist) {
  int i = blockIdx.x * 256 + threadIdx.x;
  if (i < NE) {
    int d = ei[NE + i];
    if (d >= 0 && d < NN) {
      int pos = atomicAdd(&cursor[d], 1);
      if (pos >= 0 && pos < NE) elist[pos] = i;
    }
  }
}

// ---------------- weight prep: wedge transpose (fp32) ----------------
// wT[h*64+c][j] = wedge[j][h*64+c]   (wedge is [64,256] row-major)
__global__ void k_prep(const float* __restrict__ wedge, float* __restrict__ wT) {
  int i = blockIdx.x * 256 + threadIdx.x;  // i = c*64 + j, c in [0,256), j in [0,64)
  if (i < 16384) {
    int c = i >> 6, j = i & 63;
    wT[i] = wedge[j * 256 + c];
  }
}

// ---------------- node: x1 = relu(x@w00+b00), q/k/v projections ----------------
__global__ __launch_bounds__(256) void k_node(
    const float* __restrict__ x, const float* __restrict__ w00, const float* __restrict__ b00,
    const float* __restrict__ wq, const float* __restrict__ bq,
    const float* __restrict__ wk, const float* __restrict__ bk,
    const float* __restrict__ wv, const float* __restrict__ bv,
    u16* __restrict__ x1g, u16* __restrict__ qg, u16* __restrict__ kg, u16* __restrict__ vg) {
  __shared__ float xs[128];
  __shared__ float x1s[8 * 65];
  const int t = threadIdx.x;
  const int n0 = blockIdx.x * 8;
  if (t < 128) xs[t] = x[n0 * 16 + t];
  __syncthreads();
  #pragma unroll
  for (int it = 0; it < 2; ++it) {
    int nb = it * 4 + (t >> 6);
    int col = t & 63;
    float v = b00[col];
    #pragma unroll
    for (int i = 0; i < 16; ++i) v += xs[nb * 16 + i] * w00[i * 64 + col];
    v = fmaxf(v, 0.f);
    x1s[nb * 65 + col] = v;
    x1g[(n0 + nb) * 64 + col] = f2bf(v);
  }
  __syncthreads();
  float aq[8], ak[8], av[8];
  const float bqv = bq[t], bkv = bk[t], bvv = bv[t];
  #pragma unroll
  for (int nb = 0; nb < 8; ++nb) { aq[nb] = bqv; ak[nb] = bkv; av[nb] = bvv; }
  for (int j = 0; j < 64; ++j) {
    float wqv = wq[j * 256 + t];
    float wkv = wk[j * 256 + t];
    float wvv = wv[j * 256 + t];
    #pragma unroll
    for (int nb = 0; nb < 8; ++nb) {
      float xv = x1s[nb * 65 + j];
      aq[nb] += xv * wqv; ak[nb] += xv * wkv; av[nb] += xv * wvv;
    }
  }
  #pragma unroll
  for (int nb = 0; nb < 8; ++nb) {
    qg[(n0 + nb) * 256 + t] = f2bf(aq[nb]);
    kg[(n0 + nb) * 256 + t] = f2bf(ak[nb]);
    vg[(n0 + nb) * 256 + t] = f2bf(av[nb]);
  }
}

// ---------------- G[n,h,j] = sum_c q[n,h,c] * wedge[j, h*64+c] ----------------
__global__ __launch_bounds__(256) void k_gmat(const u16* __restrict__ qg,
                                              const float* __restrict__ wT,
                                              u16* __restrict__ Gg) {
  __shared__ float qs[8 * 256];
  const int t = threadIdx.x;
  const int n0 = blockIdx.x * 8;
  #pragma unroll
  for (int i = 0; i < 8; ++i) qs[i * 256 + t] = bf2f(qg[(n0 + i) * 256 + t]);
  __syncthreads();
  const int h = t >> 6, j = t & 63;
  float acc[8] = {0, 0, 0, 0, 0, 0, 0, 0};
  for (int c = 0; c < 64; ++c) {
    float wv = wT[(h * 64 + c) * 64 + j];
    #pragma unroll
    for (int nb = 0; nb < 8; ++nb) acc[nb] += qs[nb * 256 + h * 64 + c] * wv;
  }
  #pragma unroll
  for (int nb = 0; nb < 8; ++nb) Gg[(n0 + nb) * 256 + t] = f2bf(acc[nb]);
}

// ---------------- edge MLP: thread-per-edge, wave-uniform weight reads ----------------
__global__ __launch_bounds__(256) void k_edge_mlp(const float* __restrict__ ea,
                                                  const float* __restrict__ we1, const float* __restrict__ be1,
                                                  const float* __restrict__ we2, const float* __restrict__ be2,
                                                  const float* __restrict__ we3, const float* __restrict__ be3,
                                                  u16* __restrict__ e3g) {
  __shared__ u16 rows[256 * 66];
  const int t = threadIdx.x;
  const int e0 = blockIdx.x * 256;
  const int eid = e0 + t;

  float a[8];
  {
    const float4* pa = (const float4*)(ea + (size_t)eid * 8);
    float4 p0 = pa[0], p1 = pa[1];
    a[0] = p0.x; a[1] = p0.y; a[2] = p0.z; a[3] = p0.w;
    a[4] = p1.x; a[5] = p1.y; a[6] = p1.z; a[7] = p1.w;
  }
  u16* myrow = rows + t * 66;
  for (int j = 0; j < 64; ++j) {
    float v = be1[j];
    #pragma unroll
    for (int i = 0; i < 8; ++i) v += a[i] * we1[i * 64 + j];
    myrow[j] = f2bf(fmaxf(v, 0.f));
  }
  float acc[64];
  #pragma unroll
  for (int j = 0; j < 64; ++j) acc[j] = be2[j];
  for (int k = 0; k < 64; ++k) {
    float ev = bf2f(myrow[k]);
    #pragma unroll
    for (int j = 0; j < 64; ++j) acc[j] += ev * we2[k * 64 + j];
  }
  #pragma unroll
  for (int j = 0; j < 64; ++j) myrow[j] = f2bf(fmaxf(acc[j], 0.f));
  #pragma unroll
  for (int j = 0; j < 64; ++j) acc[j] = be3[j];
  for (int k = 0; k < 64; ++k) {
    float ev = bf2f(myrow[k]);
    #pragma unroll
    for (int j = 0; j < 64; ++j) acc[j] += ev * we3[k * 64 + j];
  }
  #pragma unroll
  for (int j = 0; j < 64; ++j) myrow[j] = f2bf(fmaxf(acc[j], 0.f));
  __syncthreads();
  for (int it = 0; it < 64; ++it) {
    int flat = it * 256 + t;
    int el = flat >> 6, c = flat & 63;
    e3g[(size_t)(e0 + el) * 64 + c] = rows[el * 66 + c];
  }
}

// ---------------- fused attention: wave-per-node, single-pass softmax + LN ----------------
__global__ __launch_bounds__(256) void k_attn(
    const int* __restrict__ ei, const int* __restrict__ rowptr, const int* __restrict__ elist,
    const u16* __restrict__ qg, const u16* __restrict__ kg, const u16* __restrict__ vg,
    const u16* __restrict__ Gg, const u16* __restrict__ x1g, const u16* __restrict__ e3g,
    const float* __restrict__ wedge, const float* __restrict__ bedge,
    const float* __restrict__ wskip, const float* __restrict__ bskip,
    const float* __restrict__ lng, const float* __restrict__ lnb,
    u16* __restrict__ postg) {
  __shared__ __align__(16) float zbuf[4][272];
  __shared__ float x1buf[4][64];
  const int t = threadIdx.x;
  const int w = t >> 6;
  const int l = t & 63;
  const int grp = l >> 4;   // head
  const int li = l & 15;
  const int chb = grp * 64 + li * 4;   // 4 consecutive channels per lane
  const int n = blockIdx.x * 4 + w;
  int base = rowptr[n];
  int end  = rowptr[n + 1];
  base = max(0, min(base, NE));
  end  = max(base, min(end, NE));

  float qf[4], Gf[4];
  {
    ushort4 qv = *(const ushort4*)(qg + (size_t)n * 256 + chb);
    qf[0] = bf2f(qv.x); qf[1] = bf2f(qv.y); qf[2] = bf2f(qv.z); qf[3] = bf2f(qv.w);
    ushort4 gv2 = *(const ushort4*)(Gg + (size_t)n * 256 + chb);
    Gf[0] = bf2f(gv2.x); Gf[1] = bf2f(gv2.y); Gf[2] = bf2f(gv2.z); Gf[3] = bf2f(gv2.w);
  }
  float4 bev = *(const float4*)(bedge + chb);
  const float bedgef[4] = {bev.x, bev.y, bev.z, bev.w};
  float bqe = qf[0] * bedgef[0] + qf[1] * bedgef[1] + qf[2] * bedgef[2] + qf[3] * bedgef[3];
  #pragma unroll
  for (int mk = 1; mk < 16; mk <<= 1) bqe += __shfl_xor(bqe, mk);
  x1buf[w][l] = bf2f(x1g[(size_t)n * 64 + l]);

  float s_run = 0.f;
  float acc[4] = {0, 0, 0, 0}, zz[4] = {0, 0, 0, 0};
  for (int d = base; d < end; ++d) {
    int eid = elist[d];
    eid = max(0, min(eid, NE - 1));
    int src = ei[eid];
    src = max(0, min(src, NN - 1));
    ushort4 kv = *(const ushort4*)(kg + (size_t)src * 256 + chb);
    ushort4 vv = *(const ushort4*)(vg + (size_t)src * 256 + chb);
    ushort4 ev = *(const ushort4*)(e3g + (size_t)eid * 64 + li * 4);
    float ef0 = bf2f(ev.x), ef1 = bf2f(ev.y), ef2 = bf2f(ev.z), ef3 = bf2f(ev.w);
    float part = qf[0] * bf2f(kv.x) + qf[1] * bf2f(kv.y) + qf[2] * bf2f(kv.z) + qf[3] * bf2f(kv.w)
               + Gf[0] * ef0 + Gf[1] * ef1 + Gf[2] * ef2 + Gf[3] * ef3;
    #pragma unroll
    for (int mk = 1; mk < 16; mk <<= 1) part += __shfl_xor(part, mk);
    // softmax is shift-invariant: skip max subtraction; clamp so exp never overflows.
    float alpha = fminf((part + bqe) * 0.125f, 60.f);
    float p = __expf(alpha);
    s_run += p;
    acc[0] += p * bf2f(vv.x); acc[1] += p * bf2f(vv.y);
    acc[2] += p * bf2f(vv.z); acc[3] += p * bf2f(vv.w);
    zz[0] += p * ef0; zz[1] += p * ef1; zz[2] += p * ef2; zz[3] += p * ef3;
  }
  {
    float4 zst = make_float4(zz[0], zz[1], zz[2], zz[3]);
    *(float4*)&zbuf[w][grp * 68 + li * 4] = zst;
  }
  __syncthreads();
  const float inv_s = 1.0f / (s_run + 1e-16f);
  float outv[4] = {acc[0], acc[1], acc[2], acc[3]};
  float skipv[4] = {0, 0, 0, 0};
  for (int j = 0; j < 64; ++j) {
    float zj = zbuf[w][grp * 68 + j];
    float xj = x1buf[w][j];
    float4 wev = *(const float4*)(wedge + j * 256 + chb);
    float4 wsv = *(const float4*)(wskip + j * 256 + chb);
    outv[0] += zj * wev.x; outv[1] += zj * wev.y;
    outv[2] += zj * wev.z; outv[3] += zj * wev.w;
    skipv[0] += xj * wsv.x; skipv[1] += xj * wsv.y;
    skipv[2] += xj * wsv.z; skipv[3] += xj * wsv.w;
  }
  float4 bsv = *(const float4*)(bskip + chb);
  const float bskf[4] = {bsv.x, bsv.y, bsv.z, bsv.w};
  float o[4];
  #pragma unroll
  for (int r = 0; r < 4; ++r)
    o[r] = (outv[r] + s_run * bedgef[r]) * inv_s + skipv[r] + bskf[r];
  // LayerNorm over 256 (full-wave reduction, 4 channels/lane)
  float sum = o[0] + o[1] + o[2] + o[3];
  #pragma unroll
  for (int mk = 1; mk < 64; mk <<= 1) sum += __shfl_xor(sum, mk);
  const float mu = sum * (1.0f / 256.0f);
  float vs = 0.f;
  #pragma unroll
  for (int r = 0; r < 4; ++r) { float dd = o[r] - mu; vs += dd * dd; }
  #pragma unroll
  for (int mk = 1; mk < 64; mk <<= 1) vs += __shfl_xor(vs, mk);
  const float rstd = rsqrtf(vs * (1.0f / 256.0f) + 1e-5f);
  float4 lgv = *(const float4*)(lng + chb);
  float4 lbv = *(const float4*)(lnb + chb);
  ushort4 op;
  op.x = f2bf(fmaxf((o[0] - mu) * rstd * lgv.x + lbv.x, 0.f));
  op.y = f2bf(fmaxf((o[1] - mu) * rstd * lgv.y + lbv.y, 0.f));
  op.z = f2bf(fmaxf((o[2] - mu) * rstd * lgv.z + lbv.z, 0.f));
  op.w = f2bf(fmaxf((o[3] - mu) * rstd * lgv.w + lbv.w, 0.f));
  *(ushort4*)(postg + (size_t)n * 256 + chb) = op;
}

// ---------------- head: relu(post@w1+b1) @ w2 + b2 -> log_softmax (fp32 out) ----------------
__global__ __launch_bounds__(256) void k_head(const u16* __restrict__ postg,
                                              const float* __restrict__ w1, const float* __restrict__ b1,
                                              const float* __restrict__ w2, const float* __restrict__ b2,
                                              float* __restrict__ outg) {
  __shared__ float ps[16 * 257];
  __shared__ float h1s[16 * 132];
  const int t = threadIdx.x;
  const int n0 = blockIdx.x * 16;
  for (int i = 0; i < 16; ++i)
    ps[i * 257 + t] = bf2f(postg[(size_t)(n0 + i) * 256 + t]);
  __syncthreads();
  const int node = t & 15, cg = t >> 4;
  float acc[8];
  #pragma unroll
  for (int i = 0; i < 8; ++i) acc[i] = b1[cg * 8 + i];
  for (int j = 0; j < 256; ++j) {
    float pv = ps[node * 257 + j];
    const float4* wp = (const float4*)(w1 + j * 128 + cg * 8);
    float4 wa = wp[0], wb = wp[1];
    acc[0] += pv * wa.x; acc[1] += pv * wa.y;
    acc[2] += pv * wa.z; acc[3] += pv * wa.w;
    acc[4] += pv * wb.x; acc[5] += pv * wb.y;
    acc[6] += pv * wb.z; acc[7] += pv * wb.w;
  }
  #pragma unroll
  for (int i = 0; i < 8; ++i) h1s[node * 132 + cg * 8 + i] = fmaxf(acc[i], 0.f);
  __syncthreads();
  const int node2 = t >> 4, tt = t & 15;
  float lg[4] = {0, 0, 0, 0};
  for (int j = tt; j < 128; j += 16) {
    float hv = h1s[node2 * 132 + j];
    float4 w2v = *(const float4*)(w2 + j * 4);
    lg[0] += hv * w2v.x; lg[1] += hv * w2v.y;
    lg[2] += hv * w2v.z; lg[3] += hv * w2v.w;
  }
  #pragma unroll
  for (int mk = 1; mk < 16; mk <<= 1) {
    lg[0] += __shfl_xor(lg[0], mk); lg[1] += __shfl_xor(lg[1], mk);
    lg[2] += __shfl_xor(lg[2], mk); lg[3] += __shfl_xor(lg[3], mk);
  }
  if (tt == 0) {
    #pragma unroll
    for (int c = 0; c < 4; ++c) lg[c] += b2[c];
    float mx = fmaxf(fmaxf(lg[0], lg[1]), fmaxf(lg[2], lg[3]));
    float se = __expf(lg[0] - mx) + __expf(lg[1] - mx) + __expf(lg[2] - mx) + __expf(lg[3] - mx);
    float lse = mx + __logf(se);
    float4 ov = make_float4(lg[0] - lse, lg[1] - lse, lg[2] - lse, lg[3] - lse);
    *(float4*)(outg + (size_t)(n0 + node2) * 4) = ov;
  }
}

extern "C" void kernel_launch(void* const* d_in, const int* in_sizes, int n_in,
                              void* d_out, int out_size, void* d_ws, size_t ws_size,
                              hipStream_t stream) {
  const float* x     = (const float*)d_in[0];
  const int*   ei    = (const int*)d_in[1];
  const float* ea    = (const float*)d_in[2];
  const float* w00   = (const float*)d_in[3];
  const float* b00   = (const float*)d_in[4];
  const float* we1   = (const float*)d_in[5];
  const float* be1   = (const float*)d_in[6];
  const float* we2   = (const float*)d_in[7];
  const float* be2   = (const float*)d_in[8];
  const float* we3   = (const float*)d_in[9];
  const float* be3   = (const float*)d_in[10];
  const float* wq    = (const float*)d_in[11];
  const float* bq    = (const float*)d_in[12];
  const float* wk    = (const float*)d_in[13];
  const float* bk    = (const float*)d_in[14];
  const float* wv    = (const float*)d_in[15];
  const float* bv    = (const float*)d_in[16];
  const float* wedge = (const float*)d_in[17];
  const float* bedge = (const float*)d_in[18];
  const float* wskip = (const float*)d_in[19];
  const float* bskip = (const float*)d_in[20];
  const float* lng   = (const float*)d_in[21];
  const float* lnb   = (const float*)d_in[22];
  const float* w1    = (const float*)d_in[23];
  const float* b1    = (const float*)d_in[24];
  const float* w2    = (const float*)d_in[25];
  const float* b2    = (const float*)d_in[26];
  float* outg = (float*)d_out;

  size_t off = 0;
  char* wsb = (char*)d_ws;
  auto carve = [&](size_t bytes) -> char* {
    char* r = wsb + off;
    off += (bytes + 255) & ~(size_t)255;
    return r;
  };
  u16* qg     = (u16*)carve((size_t)NN * 256 * 2);
  u16* kg     = (u16*)carve((size_t)NN * 256 * 2);
  u16* vg     = (u16*)carve((size_t)NN * 256 * 2);
  u16* Gg     = (u16*)carve((size_t)NN * 256 * 2);
  u16* x1g    = (u16*)carve((size_t)NN * 64 * 2);
  u16* e3g    = (u16*)carve((size_t)NE * 64 * 2);
  u16* postg  = (u16*)carve((size_t)NN * 256 * 2);
  int* deg    = (int*)carve((size_t)NN * 4);
  int* rowptr = (int*)carve((size_t)(NN + 1) * 4);
  int* cursor = (int*)carve((size_t)NN * 4);
  int* elist  = (int*)carve((size_t)NE * 4);
  float* wT   = (float*)carve(16384 * 4);
  if (off > ws_size) return;  // workspace too small: fail visibly rather than corrupt

  k_prep<<<64, 256, 0, stream>>>(wedge, wT);
  k_zero<<<(NN + 255) / 256, 256, 0, stream>>>(deg);
  k_hist<<<NE / 256, 256, 0, stream>>>(ei, deg);
  k_scan<<<1, 1024, 0, stream>>>(deg, rowptr, cursor);
  k_scatter<<<NE / 256, 256, 0, stream>>>(ei, cursor, elist);
  k_node<<<NN / 8, 256, 0, stream>>>(x, w00, b00, wq, bq, wk, bk, wv, bv, x1g, qg, kg, vg);
  k_gmat<<<NN / 8, 256, 0, stream>>>(qg, wT, Gg);
  k_edge_mlp<<<NE / 256, 256, 0, stream>>>(ea, we1, be1, we2, be2, we3, be3, e3g);
  k_attn<<<NN / 4, 256, 0, stream>>>(ei, rowptr, elist, qg, kg, vg, Gg, x1g, e3g,
                                     wedge, bedge, wskip, bskip, lng, lnb, postg);
  k_head<<<NN / 16, 256, 0, stream>>>(postg, w1, b1, w2, b2, outg);
}

// Round 4
// 1155.533 us; speedup vs baseline: 1.0308x; 1.0308x over previous
//
#include <hip/hip_runtime.h>
#include <hip/hip_bf16.h>

typedef unsigned short u16;

#define NN 50000
#define NE 800000

__device__ __forceinline__ float bf2f(u16 u) { return __uint_as_float(((unsigned)u) << 16); }
__device__ __forceinline__ u16 f2bf(float f) {
  unsigned u = __float_as_uint(f);
  return (u16)((u + 0x7FFFu + ((u >> 16) & 1u)) >> 16);
}

// ---------------- CSR build ----------------
__global__ void k_zero(int* __restrict__ deg) {
  int i = blockIdx.x * 256 + threadIdx.x;
  if (i < NN) deg[i] = 0;
}

__global__ void k_hist(const int* __restrict__ ei, int* __restrict__ deg) {
  int i = blockIdx.x * 256 + threadIdx.x;
  if (i < NE) {
    int d = ei[NE + i];
    if (d >= 0 && d < NN) atomicAdd(&deg[d], 1);
  }
}

#define SCAN_T 1024
#define SCAN_CH 49
__global__ __launch_bounds__(1024) void k_scan(const int* __restrict__ deg,
                                               int* __restrict__ rowptr,
                                               int* __restrict__ cursor) {
  __shared__ int sums[SCAN_T];
  const int t = threadIdx.x;
  const int start = t * SCAN_CH;
  int lsum = 0;
  for (int i = 0; i < SCAN_CH; ++i) {
    int idx = start + i;
    if (idx < NN) lsum += deg[idx];
  }
  sums[t] = lsum;
  __syncthreads();
  for (int offs = 1; offs < SCAN_T; offs <<= 1) {
    int v = (t >= offs) ? sums[t - offs] : 0;
    __syncthreads();
    sums[t] += v;
    __syncthreads();
  }
  int run = (t == 0) ? 0 : sums[t - 1];
  for (int i = 0; i < SCAN_CH; ++i) {
    int idx = start + i;
    if (idx < NN) {
      rowptr[idx] = run;
      cursor[idx] = run;
      run += deg[idx];
    }
  }
  if (t == SCAN_T - 1) rowptr[NN] = run;
}

// also emits slist[pos] = src so k_attn streams (elist,slist) instead of a
// dependent elist->ei chase
__global__ void k_scatter(const int* __restrict__ ei, int* __restrict__ cursor,
                          int* __restrict__ elist, int* __restrict__ slist) {
  int i = blockIdx.x * 256 + threadIdx.x;
  if (i < NE) {
    int d = ei[NE + i];
    if (d >= 0 && d < NN) {
      int pos = atomicAdd(&cursor[d], 1);
      if (pos >= 0 && pos < NE) {
        elist[pos] = i;
        int s = ei[i];
        slist[pos] = max(0, min(s, NN - 1));
      }
    }
  }
}

// ---------------- weight prep: wedge transpose (fp32) ----------------
__global__ void k_prep(const float* __restrict__ wedge, float* __restrict__ wT) {
  int i = blockIdx.x * 256 + threadIdx.x;  // i = c*64 + j
  if (i < 16384) {
    int c = i >> 6, j = i & 63;
    wT[i] = wedge[j * 256 + c];
  }
}

// ---------------- node: x1 = relu(x@w00+b00), q + interleaved k|v ----------------
__global__ __launch_bounds__(256) void k_node(
    const float* __restrict__ x, const float* __restrict__ w00, const float* __restrict__ b00,
    const float* __restrict__ wq, const float* __restrict__ bq,
    const float* __restrict__ wk, const float* __restrict__ bk,
    const float* __restrict__ wv, const float* __restrict__ bv,
    u16* __restrict__ x1g, u16* __restrict__ qg, u16* __restrict__ kvg) {
  __shared__ float xs[128];
  __shared__ float x1s[8 * 65];
  const int t = threadIdx.x;
  const int n0 = blockIdx.x * 8;
  if (t < 128) xs[t] = x[n0 * 16 + t];
  __syncthreads();
  #pragma unroll
  for (int it = 0; it < 2; ++it) {
    int nb = it * 4 + (t >> 6);
    int col = t & 63;
    float v = b00[col];
    #pragma unroll
    for (int i = 0; i < 16; ++i) v += xs[nb * 16 + i] * w00[i * 64 + col];
    v = fmaxf(v, 0.f);
    x1s[nb * 65 + col] = v;
    x1g[(n0 + nb) * 64 + col] = f2bf(v);
  }
  __syncthreads();
  float aq[8], ak[8], av[8];
  const float bqv = bq[t], bkv = bk[t], bvv = bv[t];
  #pragma unroll
  for (int nb = 0; nb < 8; ++nb) { aq[nb] = bqv; ak[nb] = bkv; av[nb] = bvv; }
  for (int j = 0; j < 64; ++j) {
    float wqv = wq[j * 256 + t];
    float wkv = wk[j * 256 + t];
    float wvv = wv[j * 256 + t];
    #pragma unroll
    for (int nb = 0; nb < 8; ++nb) {
      float xv = x1s[nb * 65 + j];
      aq[nb] += xv * wqv; ak[nb] += xv * wkv; av[nb] += xv * wvv;
    }
  }
  #pragma unroll
  for (int nb = 0; nb < 8; ++nb) {
    qg[(n0 + nb) * 256 + t] = f2bf(aq[nb]);
    kvg[(size_t)(n0 + nb) * 512 + t] = f2bf(ak[nb]);
    kvg[(size_t)(n0 + nb) * 512 + 256 + t] = f2bf(av[nb]);
  }
}

// ---------------- G[n,h,j] = sum_c q[n,h,c] * wedge[j, h*64+c] ----------------
__global__ __launch_bounds__(256) void k_gmat(const u16* __restrict__ qg,
                                              const float* __restrict__ wT,
                                              u16* __restrict__ Gg) {
  __shared__ float qs[8 * 256];
  const int t = threadIdx.x;
  const int n0 = blockIdx.x * 8;
  #pragma unroll
  for (int i = 0; i < 8; ++i) qs[i * 256 + t] = bf2f(qg[(n0 + i) * 256 + t]);
  __syncthreads();
  const int h = t >> 6, j = t & 63;
  float acc[8] = {0, 0, 0, 0, 0, 0, 0, 0};
  for (int c = 0; c < 64; ++c) {
    float wv = wT[(h * 64 + c) * 64 + j];
    #pragma unroll
    for (int nb = 0; nb < 8; ++nb) acc[nb] += qs[nb * 256 + h * 64 + c] * wv;
  }
  #pragma unroll
  for (int nb = 0; nb < 8; ++nb) Gg[(n0 + nb) * 256 + t] = f2bf(acc[nb]);
}

// ---------------- edge MLP: thread-per-edge ----------------
__global__ __launch_bounds__(256) void k_edge_mlp(const float* __restrict__ ea,
                                                  const float* __restrict__ we1, const float* __restrict__ be1,
                                                  const float* __restrict__ we2, const float* __restrict__ be2,
                                                  const float* __restrict__ we3, const float* __restrict__ be3,
                                                  u16* __restrict__ e3g) {
  __shared__ u16 rows[256 * 66];
  const int t = threadIdx.x;
  const int e0 = blockIdx.x * 256;
  const int eid = e0 + t;

  float a[8];
  {
    const float4* pa = (const float4*)(ea + (size_t)eid * 8);
    float4 p0 = pa[0], p1 = pa[1];
    a[0] = p0.x; a[1] = p0.y; a[2] = p0.z; a[3] = p0.w;
    a[4] = p1.x; a[5] = p1.y; a[6] = p1.z; a[7] = p1.w;
  }
  u16* myrow = rows + t * 66;
  for (int j = 0; j < 64; ++j) {
    float v = be1[j];
    #pragma unroll
    for (int i = 0; i < 8; ++i) v += a[i] * we1[i * 64 + j];
    myrow[j] = f2bf(fmaxf(v, 0.f));
  }
  float acc[64];
  #pragma unroll
  for (int j = 0; j < 64; ++j) acc[j] = be2[j];
  for (int k = 0; k < 64; ++k) {
    float ev = bf2f(myrow[k]);
    #pragma unroll
    for (int j = 0; j < 64; ++j) acc[j] += ev * we2[k * 64 + j];
  }
  #pragma unroll
  for (int j = 0; j < 64; ++j) myrow[j] = f2bf(fmaxf(acc[j], 0.f));
  #pragma unroll
  for (int j = 0; j < 64; ++j) acc[j] = be3[j];
  for (int k = 0; k < 64; ++k) {
    float ev = bf2f(myrow[k]);
    #pragma unroll
    for (int j = 0; j < 64; ++j) acc[j] += ev * we3[k * 64 + j];
  }
  #pragma unroll
  for (int j = 0; j < 64; ++j) myrow[j] = f2bf(fmaxf(acc[j], 0.f));
  __syncthreads();
  for (int it = 0; it < 64; ++it) {
    int flat = it * 256 + t;
    int el = flat >> 6, c = flat & 63;
    e3g[(size_t)(e0 + el) * 64 + c] = rows[el * 66 + c];
  }
}

// ---------------- attention gather: wave-per-node, single-pass softmax ----------------
// Writes o1 = (acc + s*bedge)/s over the q buffer, zn = zz/s over the G buffer
// (q/G of node n are only read by this block, before the store -> safe alias).
__global__ __launch_bounds__(256) void k_attn(
    const int* __restrict__ rowptr, const int* __restrict__ elist, const int* __restrict__ slist,
    u16* qo,            // in: q [n,256] bf16; out: o1
    const u16* __restrict__ kvg,
    u16* gz,            // in: G [n,256] bf16; out: zn
    const u16* __restrict__ e3g,
    const float* __restrict__ bedge) {
  const int t = threadIdx.x;
  const int w = t >> 6;
  const int l = t & 63;
  const int grp = l >> 4;   // head
  const int li = l & 15;
  const int chb = grp * 64 + li * 4;
  const int n = blockIdx.x * 4 + w;
  int base = rowptr[n];
  int end  = rowptr[n + 1];
  base = max(0, min(base, NE));
  end  = max(base, min(end, NE));

  float qf[4], Gf[4];
  {
    ushort4 qv = *(const ushort4*)(qo + (size_t)n * 256 + chb);
    qf[0] = bf2f(qv.x); qf[1] = bf2f(qv.y); qf[2] = bf2f(qv.z); qf[3] = bf2f(qv.w);
    ushort4 gv = *(const ushort4*)(gz + (size_t)n * 256 + chb);
    Gf[0] = bf2f(gv.x); Gf[1] = bf2f(gv.y); Gf[2] = bf2f(gv.z); Gf[3] = bf2f(gv.w);
  }
  float4 bev = *(const float4*)(bedge + chb);
  float bqe = qf[0] * bev.x + qf[1] * bev.y + qf[2] * bev.z + qf[3] * bev.w;
  #pragma unroll
  for (int mk = 1; mk < 16; mk <<= 1) bqe += __shfl_xor(bqe, mk);

  float s_run = 0.f;
  float acc[4] = {0, 0, 0, 0}, zz[4] = {0, 0, 0, 0};
  int d = base;
  for (; d + 1 < end; d += 2) {
    int eid0 = elist[d],     src0 = slist[d];
    int eid1 = elist[d + 1], src1 = slist[d + 1];
    eid0 = max(0, min(eid0, NE - 1)); eid1 = max(0, min(eid1, NE - 1));
    src0 = max(0, min(src0, NN - 1)); src1 = max(0, min(src1, NN - 1));
    ushort4 k0 = *(const ushort4*)(kvg + (size_t)src0 * 512 + chb);
    ushort4 v0 = *(const ushort4*)(kvg + (size_t)src0 * 512 + 256 + chb);
    ushort4 e0 = *(const ushort4*)(e3g + (size_t)eid0 * 64 + li * 4);
    ushort4 k1 = *(const ushort4*)(kvg + (size_t)src1 * 512 + chb);
    ushort4 v1 = *(const ushort4*)(kvg + (size_t)src1 * 512 + 256 + chb);
    ushort4 e1 = *(const ushort4*)(e3g + (size_t)eid1 * 64 + li * 4);
    float e00 = bf2f(e0.x), e01 = bf2f(e0.y), e02 = bf2f(e0.z), e03 = bf2f(e0.w);
    float e10 = bf2f(e1.x), e11 = bf2f(e1.y), e12 = bf2f(e1.z), e13 = bf2f(e1.w);
    float p0 = qf[0]*bf2f(k0.x) + qf[1]*bf2f(k0.y) + qf[2]*bf2f(k0.z) + qf[3]*bf2f(k0.w)
             + Gf[0]*e00 + Gf[1]*e01 + Gf[2]*e02 + Gf[3]*e03;
    float p1 = qf[0]*bf2f(k1.x) + qf[1]*bf2f(k1.y) + qf[2]*bf2f(k1.z) + qf[3]*bf2f(k1.w)
             + Gf[0]*e10 + Gf[1]*e11 + Gf[2]*e12 + Gf[3]*e13;
    #pragma unroll
    for (int mk = 1; mk < 16; mk <<= 1) { p0 += __shfl_xor(p0, mk); p1 += __shfl_xor(p1, mk); }
    float w0 = __expf(fminf((p0 + bqe) * 0.125f, 60.f));
    float w1 = __expf(fminf((p1 + bqe) * 0.125f, 60.f));
    s_run += w0 + w1;
    acc[0] += w0*bf2f(v0.x) + w1*bf2f(v1.x);
    acc[1] += w0*bf2f(v0.y) + w1*bf2f(v1.y);
    acc[2] += w0*bf2f(v0.z) + w1*bf2f(v1.z);
    acc[3] += w0*bf2f(v0.w) + w1*bf2f(v1.w);
    zz[0] += w0*e00 + w1*e10; zz[1] += w0*e01 + w1*e11;
    zz[2] += w0*e02 + w1*e12; zz[3] += w0*e03 + w1*e13;
  }
  if (d < end) {
    int eid0 = elist[d], src0 = slist[d];
    eid0 = max(0, min(eid0, NE - 1));
    src0 = max(0, min(src0, NN - 1));
    ushort4 k0 = *(const ushort4*)(kvg + (size_t)src0 * 512 + chb);
    ushort4 v0 = *(const ushort4*)(kvg + (size_t)src0 * 512 + 256 + chb);
    ushort4 e0 = *(const ushort4*)(e3g + (size_t)eid0 * 64 + li * 4);
    float e00 = bf2f(e0.x), e01 = bf2f(e0.y), e02 = bf2f(e0.z), e03 = bf2f(e0.w);
    float p0 = qf[0]*bf2f(k0.x) + qf[1]*bf2f(k0.y) + qf[2]*bf2f(k0.z) + qf[3]*bf2f(k0.w)
             + Gf[0]*e00 + Gf[1]*e01 + Gf[2]*e02 + Gf[3]*e03;
    #pragma unroll
    for (int mk = 1; mk < 16; mk <<= 1) p0 += __shfl_xor(p0, mk);
    float w0 = __expf(fminf((p0 + bqe) * 0.125f, 60.f));
    s_run += w0;
    acc[0] += w0*bf2f(v0.x); acc[1] += w0*bf2f(v0.y);
    acc[2] += w0*bf2f(v0.z); acc[3] += w0*bf2f(v0.w);
    zz[0] += w0*e00; zz[1] += w0*e01; zz[2] += w0*e02; zz[3] += w0*e03;
  }
  const float inv_s = 1.0f / (s_run + 1e-16f);
  ushort4 o1, znv;
  o1.x = f2bf((acc[0] + s_run * bev.x) * inv_s);
  o1.y = f2bf((acc[1] + s_run * bev.y) * inv_s);
  o1.z = f2bf((acc[2] + s_run * bev.z) * inv_s);
  o1.w = f2bf((acc[3] + s_run * bev.w) * inv_s);
  znv.x = f2bf(zz[0] * inv_s); znv.y = f2bf(zz[1] * inv_s);
  znv.z = f2bf(zz[2] * inv_s); znv.w = f2bf(zz[3] * inv_s);
  *(ushort4*)(qo + (size_t)n * 256 + chb) = o1;
  *(ushort4*)(gz + (size_t)n * 256 + chb) = znv;
}

// ---------------- post: o = o1 + zn@wedge + x1@wskip + bskip -> LN -> relu ----------------
__global__ __launch_bounds__(256) void k_post(
    const u16* __restrict__ o1g, const u16* __restrict__ zng, const u16* __restrict__ x1g,
    const float* __restrict__ wedge, const float* __restrict__ wskip,
    const float* __restrict__ bskip, const float* __restrict__ lng, const float* __restrict__ lnb,
    u16* __restrict__ postg) {
  __shared__ float zL[8 * 256];
  __shared__ float x1L[8 * 64];
  const int t = threadIdx.x;
  const int n0 = blockIdx.x * 8;
  #pragma unroll
  for (int i = 0; i < 8; ++i) zL[i * 256 + t] = bf2f(zng[(size_t)(n0 + i) * 256 + t]);
  {
    int f = t;
    x1L[f] = bf2f(x1g[(size_t)(n0 + (f >> 6)) * 64 + (f & 63)]);
    f = t + 256;
    x1L[f] = bf2f(x1g[(size_t)(n0 + (f >> 6)) * 64 + (f & 63)]);
  }
  __syncthreads();
  const int nb = t >> 5;          // node within block
  const int c0 = (t & 31) * 8;    // 8 consecutive channels (same head: c0>>6 const)
  const int h = c0 >> 6;
  float o[8];
  {
    ushort4 oa = *(const ushort4*)(o1g + (size_t)(n0 + nb) * 256 + c0);
    ushort4 ob = *(const ushort4*)(o1g + (size_t)(n0 + nb) * 256 + c0 + 4);
    float4 b0 = *(const float4*)(bskip + c0);
    float4 b1 = *(const float4*)(bskip + c0 + 4);
    o[0] = bf2f(oa.x) + b0.x; o[1] = bf2f(oa.y) + b0.y;
    o[2] = bf2f(oa.z) + b0.z; o[3] = bf2f(oa.w) + b0.w;
    o[4] = bf2f(ob.x) + b1.x; o[5] = bf2f(ob.y) + b1.y;
    o[6] = bf2f(ob.z) + b1.z; o[7] = bf2f(ob.w) + b1.w;
  }
  const float* zrow = zL + nb * 256 + h * 64;
  const float* xrow = x1L + nb * 64;
  for (int j = 0; j < 64; ++j) {
    float zv = zrow[j];
    float xv = xrow[j];
    float4 we0 = *(const float4*)(wedge + j * 256 + c0);
    float4 we1v = *(const float4*)(wedge + j * 256 + c0 + 4);
    float4 ws0 = *(const float4*)(wskip + j * 256 + c0);
    float4 ws1 = *(const float4*)(wskip + j * 256 + c0 + 4);
    o[0] += zv * we0.x + xv * ws0.x;  o[1] += zv * we0.y + xv * ws0.y;
    o[2] += zv * we0.z + xv * ws0.z;  o[3] += zv * we0.w + xv * ws0.w;
    o[4] += zv * we1v.x + xv * ws1.x; o[5] += zv * we1v.y + xv * ws1.y;
    o[6] += zv * we1v.z + xv * ws1.z; o[7] += zv * we1v.w + xv * ws1.w;
  }
  // LayerNorm: this node's 256 channels live on 32 lanes (8 each)
  float sum = ((o[0] + o[1]) + (o[2] + o[3])) + ((o[4] + o[5]) + (o[6] + o[7]));
  #pragma unroll
  for (int mk = 1; mk < 32; mk <<= 1) sum += __shfl_xor(sum, mk);
  const float mu = sum * (1.0f / 256.0f);
  float vs = 0.f;
  #pragma unroll
  for (int r = 0; r < 8; ++r) { float dd = o[r] - mu; vs += dd * dd; }
  #pragma unroll
  for (int mk = 1; mk < 32; mk <<= 1) vs += __shfl_xor(vs, mk);
  const float rstd = rsqrtf(vs * (1.0f / 256.0f) + 1e-5f);
  float4 g0 = *(const float4*)(lng + c0);
  float4 g1 = *(const float4*)(lng + c0 + 4);
  float4 lb0 = *(const float4*)(lnb + c0);
  float4 lb1 = *(const float4*)(lnb + c0 + 4);
  ushort4 pa, pb;
  pa.x = f2bf(fmaxf((o[0] - mu) * rstd * g0.x + lb0.x, 0.f));
  pa.y = f2bf(fmaxf((o[1] - mu) * rstd * g0.y + lb0.y, 0.f));
  pa.z = f2bf(fmaxf((o[2] - mu) * rstd * g0.z + lb0.z, 0.f));
  pa.w = f2bf(fmaxf((o[3] - mu) * rstd * g0.w + lb0.w, 0.f));
  pb.x = f2bf(fmaxf((o[4] - mu) * rstd * g1.x + lb1.x, 0.f));
  pb.y = f2bf(fmaxf((o[5] - mu) * rstd * g1.y + lb1.y, 0.f));
  pb.z = f2bf(fmaxf((o[6] - mu) * rstd * g1.z + lb1.z, 0.f));
  pb.w = f2bf(fmaxf((o[7] - mu) * rstd * g1.w + lb1.w, 0.f));
  *(ushort4*)(postg + (size_t)(n0 + nb) * 256 + c0) = pa;
  *(ushort4*)(postg + (size_t)(n0 + nb) * 256 + c0 + 4) = pb;
}

// ---------------- head: relu(post@w1+b1) @ w2 + b2 -> log_softmax (fp32 out) ----------------
__global__ __launch_bounds__(256) void k_head(const u16* __restrict__ postg,
                                              const float* __restrict__ w1, const float* __restrict__ b1,
                                              const float* __restrict__ w2, const float* __restrict__ b2,
                                              float* __restrict__ outg) {
  __shared__ float ps[16 * 257];
  __shared__ float h1s[16 * 132];
  const int t = threadIdx.x;
  const int n0 = blockIdx.x * 16;
  for (int i = 0; i < 16; ++i)
    ps[i * 257 + t] = bf2f(postg[(size_t)(n0 + i) * 256 + t]);
  __syncthreads();
  const int node = t & 15, cg = t >> 4;
  float acc[8];
  #pragma unroll
  for (int i = 0; i < 8; ++i) acc[i] = b1[cg * 8 + i];
  for (int j = 0; j < 256; ++j) {
    float pv = ps[node * 257 + j];
    const float4* wp = (const float4*)(w1 + j * 128 + cg * 8);
    float4 wa = wp[0], wb = wp[1];
    acc[0] += pv * wa.x; acc[1] += pv * wa.y;
    acc[2] += pv * wa.z; acc[3] += pv * wa.w;
    acc[4] += pv * wb.x; acc[5] += pv * wb.y;
    acc[6] += pv * wb.z; acc[7] += pv * wb.w;
  }
  #pragma unroll
  for (int i = 0; i < 8; ++i) h1s[node * 132 + cg * 8 + i] = fmaxf(acc[i], 0.f);
  __syncthreads();
  const int node2 = t >> 4, tt = t & 15;
  float lg[4] = {0, 0, 0, 0};
  for (int j = tt; j < 128; j += 16) {
    float hv = h1s[node2 * 132 + j];
    float4 w2v = *(const float4*)(w2 + j * 4);
    lg[0] += hv * w2v.x; lg[1] += hv * w2v.y;
    lg[2] += hv * w2v.z; lg[3] += hv * w2v.w;
  }
  #pragma unroll
  for (int mk = 1; mk < 16; mk <<= 1) {
    lg[0] += __shfl_xor(lg[0], mk); lg[1] += __shfl_xor(lg[1], mk);
    lg[2] += __shfl_xor(lg[2], mk); lg[3] += __shfl_xor(lg[3], mk);
  }
  if (tt == 0) {
    #pragma unroll
    for (int c = 0; c < 4; ++c) lg[c] += b2[c];
    float mx = fmaxf(fmaxf(lg[0], lg[1]), fmaxf(lg[2], lg[3]));
    float se = __expf(lg[0] - mx) + __expf(lg[1] - mx) + __expf(lg[2] - mx) + __expf(lg[3] - mx);
    float lse = mx + __logf(se);
    float4 ov = make_float4(lg[0] - lse, lg[1] - lse, lg[2] - lse, lg[3] - lse);
    *(float4*)(outg + (size_t)(n0 + node2) * 4) = ov;
  }
}

extern "C" void kernel_launch(void* const* d_in, const int* in_sizes, int n_in,
                              void* d_out, int out_size, void* d_ws, size_t ws_size,
                              hipStream_t stream) {
  const float* x     = (const float*)d_in[0];
  const int*   ei    = (const int*)d_in[1];
  const float* ea    = (const float*)d_in[2];
  const float* w00   = (const float*)d_in[3];
  const float* b00   = (const float*)d_in[4];
  const float* we1   = (const float*)d_in[5];
  const float* be1   = (const float*)d_in[6];
  const float* we2   = (const float*)d_in[7];
  const float* be2   = (const float*)d_in[8];
  const float* we3   = (const float*)d_in[9];
  const float* be3   = (const float*)d_in[10];
  const float* wq    = (const float*)d_in[11];
  const float* bq    = (const float*)d_in[12];
  const float* wk    = (const float*)d_in[13];
  const float* bk    = (const float*)d_in[14];
  const float* wv    = (const float*)d_in[15];
  const float* bv    = (const float*)d_in[16];
  const float* wedge = (const float*)d_in[17];
  const float* bedge = (const float*)d_in[18];
  const float* wskip = (const float*)d_in[19];
  const float* bskip = (const float*)d_in[20];
  const float* lng   = (const float*)d_in[21];
  const float* lnb   = (const float*)d_in[22];
  const float* w1    = (const float*)d_in[23];
  const float* b1    = (const float*)d_in[24];
  const float* w2    = (const float*)d_in[25];
  const float* b2    = (const float*)d_in[26];
  float* outg = (float*)d_out;

  size_t off = 0;
  char* wsb = (char*)d_ws;
  auto carve = [&](size_t bytes) -> char* {
    char* r = wsb + off;
    off += (bytes + 255) & ~(size_t)255;
    return r;
  };
  u16* kvg    = (u16*)carve((size_t)NN * 512 * 2);  // k|v interleaved; reused as postg after k_attn
  u16* qg     = (u16*)carve((size_t)NN * 256 * 2);  // q, overwritten by o1 in k_attn
  u16* Gg     = (u16*)carve((size_t)NN * 256 * 2);  // G, overwritten by zn in k_attn
  u16* x1g    = (u16*)carve((size_t)NN * 64 * 2);
  u16* e3g    = (u16*)carve((size_t)NE * 64 * 2);
  int* deg    = (int*)carve((size_t)NN * 4);
  int* rowptr = (int*)carve((size_t)(NN + 1) * 4);
  int* cursor = (int*)carve((size_t)NN * 4);
  int* elist  = (int*)carve((size_t)NE * 4);
  int* slist  = (int*)carve((size_t)NE * 4);
  float* wT   = (float*)carve(16384 * 4);
  u16* postg  = kvg;   // kvg dead after k_attn
  if (off > ws_size) return;

  k_prep<<<64, 256, 0, stream>>>(wedge, wT);
  k_zero<<<(NN + 255) / 256, 256, 0, stream>>>(deg);
  k_hist<<<NE / 256, 256, 0, stream>>>(ei, deg);
  k_scan<<<1, 1024, 0, stream>>>(deg, rowptr, cursor);
  k_scatter<<<NE / 256, 256, 0, stream>>>(ei, cursor, elist, slist);
  k_node<<<NN / 8, 256, 0, stream>>>(x, w00, b00, wq, bq, wk, bk, wv, bv, x1g, qg, kvg);
  k_gmat<<<NN / 8, 256, 0, stream>>>(qg, wT, Gg);
  k_edge_mlp<<<NE / 256, 256, 0, stream>>>(ea, we1, be1, we2, be2, we3, be3, e3g);
  k_attn<<<NN / 4, 256, 0, stream>>>(rowptr, elist, slist, qg, kvg, Gg, e3g, bedge);
  k_post<<<NN / 8, 256, 0, stream>>>(qg, Gg, x1g, wedge, wskip, bskip, lng, lnb, postg);
  k_head<<<NN / 16, 256, 0, stream>>>(postg, w1, b1, w2, b2, outg);
}

// Round 5
// 1023.509 us; speedup vs baseline: 1.1638x; 1.1290x over previous
//
#include <hip/hip_runtime.h>
#include <hip/hip_bf16.h>

typedef unsigned short u16;
typedef __attribute__((ext_vector_type(8))) short bf16x8;
typedef __attribute__((ext_vector_type(4))) float f32x4;

#define NN 50000
#define NE 800000

__device__ __forceinline__ float bf2f(u16 u) { return __uint_as_float(((unsigned)u) << 16); }
__device__ __forceinline__ u16 f2bf(float f) {
  unsigned u = __float_as_uint(f);
  return (u16)((u + 0x7FFFu + ((u >> 16) & 1u)) >> 16);
}

// ---------------- CSR build ----------------
__global__ void k_zero(int* __restrict__ deg) {
  int i = blockIdx.x * 256 + threadIdx.x;
  if (i < NN) deg[i] = 0;
}

__global__ void k_hist(const int* __restrict__ ei, int* __restrict__ deg) {
  int i = blockIdx.x * 256 + threadIdx.x;
  if (i < NE) {
    int d = ei[NE + i];
    if (d >= 0 && d < NN) atomicAdd(&deg[d], 1);
  }
}

#define SCAN_T 1024
#define SCAN_CH 49
__global__ __launch_bounds__(1024) void k_scan(const int* __restrict__ deg,
                                               int* __restrict__ rowptr,
                                               int* __restrict__ cursor) {
  __shared__ int sums[SCAN_T];
  const int t = threadIdx.x;
  const int start = t * SCAN_CH;
  int lsum = 0;
  for (int i = 0; i < SCAN_CH; ++i) {
    int idx = start + i;
    if (idx < NN) lsum += deg[idx];
  }
  sums[t] = lsum;
  __syncthreads();
  for (int offs = 1; offs < SCAN_T; offs <<= 1) {
    int v = (t >= offs) ? sums[t - offs] : 0;
    __syncthreads();
    sums[t] += v;
    __syncthreads();
  }
  int run = (t == 0) ? 0 : sums[t - 1];
  for (int i = 0; i < SCAN_CH; ++i) {
    int idx = start + i;
    if (idx < NN) {
      rowptr[idx] = run;
      cursor[idx] = run;
      run += deg[idx];
    }
  }
  if (t == SCAN_T - 1) rowptr[NN] = run;
}

__global__ void k_scatter(const int* __restrict__ ei, int* __restrict__ cursor,
                          int* __restrict__ elist, int* __restrict__ slist) {
  int i = blockIdx.x * 256 + threadIdx.x;
  if (i < NE) {
    int d = ei[NE + i];
    if (d >= 0 && d < NN) {
      int pos = atomicAdd(&cursor[d], 1);
      if (pos >= 0 && pos < NE) {
        elist[pos] = i;
        int s = ei[i];
        slist[pos] = max(0, min(s, NN - 1));
      }
    }
  }
}

// ---------------- weight prep ----------------
// wT (fp32): wT[h*64+c][j] = wedge[j][h*64+c]  (for k_gmat)
__global__ void k_prep(const float* __restrict__ wedge, float* __restrict__ wT) {
  int i = blockIdx.x * 256 + threadIdx.x;  // i = c*64 + j
  if (i < 16384) {
    int c = i >> 6, j = i & 63;
    wT[i] = wedge[j * 256 + c];
  }
}

// bf16 transposed edge-MLP weights for MFMA B-fragments:
// wB1t[n*8+k]  = we1[k*64+n]   (512)
// wB2t[n*64+k] = we2[k*64+n]   (4096)
// wB3t[n*64+k] = we3[k*64+n]   (4096)
__global__ void k_prep_w(const float* __restrict__ we1, const float* __restrict__ we2,
                         const float* __restrict__ we3,
                         u16* __restrict__ wB1t, u16* __restrict__ wB2t, u16* __restrict__ wB3t) {
  int i = blockIdx.x * 256 + threadIdx.x;
  if (i < 512) {
    int n = i >> 3, k = i & 7;
    wB1t[i] = f2bf(we1[k * 64 + n]);
  } else if (i < 512 + 4096) {
    int i2 = i - 512;
    int n = i2 >> 6, k = i2 & 63;
    wB2t[i2] = f2bf(we2[k * 64 + n]);
  } else if (i < 512 + 8192) {
    int i2 = i - 512 - 4096;
    int n = i2 >> 6, k = i2 & 63;
    wB3t[i2] = f2bf(we3[k * 64 + n]);
  }
}

// ---------------- node: x1 = relu(x@w00+b00), q + interleaved k|v ----------------
__global__ __launch_bounds__(256) void k_node(
    const float* __restrict__ x, const float* __restrict__ w00, const float* __restrict__ b00,
    const float* __restrict__ wq, const float* __restrict__ bq,
    const float* __restrict__ wk, const float* __restrict__ bk,
    const float* __restrict__ wv, const float* __restrict__ bv,
    u16* __restrict__ x1g, u16* __restrict__ qg, u16* __restrict__ kvg) {
  __shared__ float xs[128];
  __shared__ float x1s[8 * 65];
  const int t = threadIdx.x;
  const int n0 = blockIdx.x * 8;
  if (t < 128) xs[t] = x[n0 * 16 + t];
  __syncthreads();
  #pragma unroll
  for (int it = 0; it < 2; ++it) {
    int nb = it * 4 + (t >> 6);
    int col = t & 63;
    float v = b00[col];
    #pragma unroll
    for (int i = 0; i < 16; ++i) v += xs[nb * 16 + i] * w00[i * 64 + col];
    v = fmaxf(v, 0.f);
    x1s[nb * 65 + col] = v;
    x1g[(n0 + nb) * 64 + col] = f2bf(v);
  }
  __syncthreads();
  float aq[8], ak[8], av[8];
  const float bqv = bq[t], bkv = bk[t], bvv = bv[t];
  #pragma unroll
  for (int nb = 0; nb < 8; ++nb) { aq[nb] = bqv; ak[nb] = bkv; av[nb] = bvv; }
  for (int j = 0; j < 64; ++j) {
    float wqv = wq[j * 256 + t];
    float wkv = wk[j * 256 + t];
    float wvv = wv[j * 256 + t];
    #pragma unroll
    for (int nb = 0; nb < 8; ++nb) {
      float xv = x1s[nb * 65 + j];
      aq[nb] += xv * wqv; ak[nb] += xv * wkv; av[nb] += xv * wvv;
    }
  }
  #pragma unroll
  for (int nb = 0; nb < 8; ++nb) {
    qg[(n0 + nb) * 256 + t] = f2bf(aq[nb]);
    kvg[(size_t)(n0 + nb) * 512 + t] = f2bf(ak[nb]);
    kvg[(size_t)(n0 + nb) * 512 + 256 + t] = f2bf(av[nb]);
  }
}

// ---------------- G[n,h,j] = sum_c q[n,h,c] * wedge[j, h*64+c] ----------------
__global__ __launch_bounds__(256) void k_gmat(const u16* __restrict__ qg,
                                              const float* __restrict__ wT,
                                              u16* __restrict__ Gg) {
  __shared__ float qs[8 * 256];
  const int t = threadIdx.x;
  const int n0 = blockIdx.x * 8;
  #pragma unroll
  for (int i = 0; i < 8; ++i) qs[i * 256 + t] = bf2f(qg[(n0 + i) * 256 + t]);
  __syncthreads();
  const int h = t >> 6, j = t & 63;
  float acc[8] = {0, 0, 0, 0, 0, 0, 0, 0};
  for (int c = 0; c < 64; ++c) {
    float wv = wT[(h * 64 + c) * 64 + j];
    #pragma unroll
    for (int nb = 0; nb < 8; ++nb) acc[nb] += qs[nb * 256 + h * 64 + c] * wv;
  }
  #pragma unroll
  for (int nb = 0; nb < 8; ++nb) Gg[(n0 + nb) * 256 + t] = f2bf(acc[nb]);
}

// ---------------- edge MLP via MFMA bf16 ----------------
// A-frag: A[m=lane&15][k=quad*8+j]; B-frag: B[k=quad*8+j][n=lane&15];
// C/D: col=lane&15, row=quad*4+reg. 128 edges/block, 4 waves x 2 M-tiles.
#define EPB 128
#define APAD 72   // row pad (u16): 16B-aligned b128 reads, <=2-way banks
__global__ __launch_bounds__(256) void k_edge_mlp(
    const float* __restrict__ ea,
    const u16* __restrict__ wB1t, const u16* __restrict__ wB2t, const u16* __restrict__ wB3t,
    const float* __restrict__ be1, const float* __restrict__ be2, const float* __restrict__ be3,
    u16* __restrict__ e3g) {
  __shared__ u16 actA[EPB * APAD];
  __shared__ u16 actB[EPB * APAD];
  const int t = threadIdx.x;
  const int w = t >> 6, l = t & 63;
  const int quad = l >> 4, li = l & 15;
  const int e0 = blockIdx.x * EPB;
  const f32x4 zc = {0.f, 0.f, 0.f, 0.f};

  float b1c[4], b2c[4], b3c[4];
  #pragma unroll
  for (int nt = 0; nt < 4; ++nt) {
    b1c[nt] = be1[nt * 16 + li];
    b2c[nt] = be2[nt * 16 + li];
    b3c[nt] = be3[nt * 16 + li];
  }

  // ---- layer 1: K=8 (zero-padded to 32; only quad 0 carries data) ----
  bf16x8 b1f[4];
  #pragma unroll
  for (int nt = 0; nt < 4; ++nt) {
    bf16x8 z = {};
    if (quad == 0) z = *(const bf16x8*)(wB1t + (nt * 16 + li) * 8);
    b1f[nt] = z;
  }
  #pragma unroll
  for (int mi = 0; mi < 2; ++mi) {
    const int mt = w * 2 + mi;
    bf16x8 af = {};
    if (quad == 0) {
      const float4* pa = (const float4*)(ea + (size_t)(e0 + mt * 16 + li) * 8);
      float4 p0 = pa[0], p1 = pa[1];
      af[0] = (short)f2bf(p0.x); af[1] = (short)f2bf(p0.y);
      af[2] = (short)f2bf(p0.z); af[3] = (short)f2bf(p0.w);
      af[4] = (short)f2bf(p1.x); af[5] = (short)f2bf(p1.y);
      af[6] = (short)f2bf(p1.z); af[7] = (short)f2bf(p1.w);
    }
    #pragma unroll
    for (int nt = 0; nt < 4; ++nt) {
      f32x4 d = __builtin_amdgcn_mfma_f32_16x16x32_bf16(af, b1f[nt], zc, 0, 0, 0);
      #pragma unroll
      for (int r = 0; r < 4; ++r)
        actA[(mt * 16 + quad * 4 + r) * APAD + nt * 16 + li] = f2bf(fmaxf(d[r] + b1c[nt], 0.f));
    }
  }
  __syncthreads();

  // ---- layer 2: actA -> actB ----
  {
    bf16x8 bf[4][2];
    #pragma unroll
    for (int nt = 0; nt < 4; ++nt)
      #pragma unroll
      for (int kk = 0; kk < 2; ++kk)
        bf[nt][kk] = *(const bf16x8*)(wB2t + (nt * 16 + li) * 64 + kk * 32 + quad * 8);
    #pragma unroll
    for (int mi = 0; mi < 2; ++mi) {
      const int mt = w * 2 + mi;
      bf16x8 a0 = *(const bf16x8*)(actA + (mt * 16 + li) * APAD + quad * 8);
      bf16x8 a1 = *(const bf16x8*)(actA + (mt * 16 + li) * APAD + 32 + quad * 8);
      #pragma unroll
      for (int nt = 0; nt < 4; ++nt) {
        f32x4 d = __builtin_amdgcn_mfma_f32_16x16x32_bf16(a0, bf[nt][0], zc, 0, 0, 0);
        d = __builtin_amdgcn_mfma_f32_16x16x32_bf16(a1, bf[nt][1], d, 0, 0, 0);
        #pragma unroll
        for (int r = 0; r < 4; ++r)
          actB[(mt * 16 + quad * 4 + r) * APAD + nt * 16 + li] = f2bf(fmaxf(d[r] + b2c[nt], 0.f));
      }
    }
  }
  __syncthreads();

  // ---- layer 3: actB -> actA ----
  {
    bf16x8 bf[4][2];
    #pragma unroll
    for (int nt = 0; nt < 4; ++nt)
      #pragma unroll
      for (int kk = 0; kk < 2; ++kk)
        bf[nt][kk] = *(const bf16x8*)(wB3t + (nt * 16 + li) * 64 + kk * 32 + quad * 8);
    #pragma unroll
    for (int mi = 0; mi < 2; ++mi) {
      const int mt = w * 2 + mi;
      bf16x8 a0 = *(const bf16x8*)(actB + (mt * 16 + li) * APAD + quad * 8);
      bf16x8 a1 = *(const bf16x8*)(actB + (mt * 16 + li) * APAD + 32 + quad * 8);
      #pragma unroll
      for (int nt = 0; nt < 4; ++nt) {
        f32x4 d = __builtin_amdgcn_mfma_f32_16x16x32_bf16(a0, bf[nt][0], zc, 0, 0, 0);
        d = __builtin_amdgcn_mfma_f32_16x16x32_bf16(a1, bf[nt][1], d, 0, 0, 0);
        #pragma unroll
        for (int r = 0; r < 4; ++r)
          actA[(mt * 16 + quad * 4 + r) * APAD + nt * 16 + li] = f2bf(fmaxf(d[r] + b3c[nt], 0.f));
      }
    }
  }
  __syncthreads();

  // ---- coalesced store: 128x64 u16 ----
  #pragma unroll
  for (int it = 0; it < 4; ++it) {
    int flat = it * 2048 + t * 8;
    int el = flat >> 6, c = flat & 63;
    uint4 v = *(const uint4*)(actA + el * APAD + c);
    *(uint4*)(e3g + (size_t)(e0 + el) * 64 + c) = v;
  }
}

// ---------------- attention gather: wave-per-node, single-pass softmax ----------------
__global__ __launch_bounds__(256) void k_attn(
    const int* __restrict__ rowptr, const int* __restrict__ elist, const int* __restrict__ slist,
    u16* qo, const u16* __restrict__ kvg, u16* gz, const u16* __restrict__ e3g,
    const float* __restrict__ bedge) {
  const int t = threadIdx.x;
  const int w = t >> 6;
  const int l = t & 63;
  const int grp = l >> 4;
  const int li = l & 15;
  const int chb = grp * 64 + li * 4;
  const int n = blockIdx.x * 4 + w;
  int base = rowptr[n];
  int end  = rowptr[n + 1];
  base = max(0, min(base, NE));
  end  = max(base, min(end, NE));

  float qf[4], Gf[4];
  {
    ushort4 qv = *(const ushort4*)(qo + (size_t)n * 256 + chb);
    qf[0] = bf2f(qv.x); qf[1] = bf2f(qv.y); qf[2] = bf2f(qv.z); qf[3] = bf2f(qv.w);
    ushort4 gv = *(const ushort4*)(gz + (size_t)n * 256 + chb);
    Gf[0] = bf2f(gv.x); Gf[1] = bf2f(gv.y); Gf[2] = bf2f(gv.z); Gf[3] = bf2f(gv.w);
  }
  float4 bev = *(const float4*)(bedge + chb);
  float bqe = qf[0] * bev.x + qf[1] * bev.y + qf[2] * bev.z + qf[3] * bev.w;
  #pragma unroll
  for (int mk = 1; mk < 16; mk <<= 1) bqe += __shfl_xor(bqe, mk);

  float s_run = 0.f;
  float acc[4] = {0, 0, 0, 0}, zz[4] = {0, 0, 0, 0};
  int d = base;
  for (; d + 1 < end; d += 2) {
    int eid0 = elist[d],     src0 = slist[d];
    int eid1 = elist[d + 1], src1 = slist[d + 1];
    eid0 = max(0, min(eid0, NE - 1)); eid1 = max(0, min(eid1, NE - 1));
    src0 = max(0, min(src0, NN - 1)); src1 = max(0, min(src1, NN - 1));
    ushort4 k0 = *(const ushort4*)(kvg + (size_t)src0 * 512 + chb);
    ushort4 v0 = *(const ushort4*)(kvg + (size_t)src0 * 512 + 256 + chb);
    ushort4 e0 = *(const ushort4*)(e3g + (size_t)eid0 * 64 + li * 4);
    ushort4 k1 = *(const ushort4*)(kvg + (size_t)src1 * 512 + chb);
    ushort4 v1 = *(const ushort4*)(kvg + (size_t)src1 * 512 + 256 + chb);
    ushort4 e1 = *(const ushort4*)(e3g + (size_t)eid1 * 64 + li * 4);
    float e00 = bf2f(e0.x), e01 = bf2f(e0.y), e02 = bf2f(e0.z), e03 = bf2f(e0.w);
    float e10 = bf2f(e1.x), e11 = bf2f(e1.y), e12 = bf2f(e1.z), e13 = bf2f(e1.w);
    float p0 = qf[0]*bf2f(k0.x) + qf[1]*bf2f(k0.y) + qf[2]*bf2f(k0.z) + qf[3]*bf2f(k0.w)
             + Gf[0]*e00 + Gf[1]*e01 + Gf[2]*e02 + Gf[3]*e03;
    float p1 = qf[0]*bf2f(k1.x) + qf[1]*bf2f(k1.y) + qf[2]*bf2f(k1.z) + qf[3]*bf2f(k1.w)
             + Gf[0]*e10 + Gf[1]*e11 + Gf[2]*e12 + Gf[3]*e13;
    #pragma unroll
    for (int mk = 1; mk < 16; mk <<= 1) { p0 += __shfl_xor(p0, mk); p1 += __shfl_xor(p1, mk); }
    float w0 = __expf(fminf((p0 + bqe) * 0.125f, 60.f));
    float w1 = __expf(fminf((p1 + bqe) * 0.125f, 60.f));
    s_run += w0 + w1;
    acc[0] += w0*bf2f(v0.x) + w1*bf2f(v1.x);
    acc[1] += w0*bf2f(v0.y) + w1*bf2f(v1.y);
    acc[2] += w0*bf2f(v0.z) + w1*bf2f(v1.z);
    acc[3] += w0*bf2f(v0.w) + w1*bf2f(v1.w);
    zz[0] += w0*e00 + w1*e10; zz[1] += w0*e01 + w1*e11;
    zz[2] += w0*e02 + w1*e12; zz[3] += w0*e03 + w1*e13;
  }
  if (d < end) {
    int eid0 = elist[d], src0 = slist[d];
    eid0 = max(0, min(eid0, NE - 1));
    src0 = max(0, min(src0, NN - 1));
    ushort4 k0 = *(const ushort4*)(kvg + (size_t)src0 * 512 + chb);
    ushort4 v0 = *(const ushort4*)(kvg + (size_t)src0 * 512 + 256 + chb);
    ushort4 e0 = *(const ushort4*)(e3g + (size_t)eid0 * 64 + li * 4);
    float e00 = bf2f(e0.x), e01 = bf2f(e0.y), e02 = bf2f(e0.z), e03 = bf2f(e0.w);
    float p0 = qf[0]*bf2f(k0.x) + qf[1]*bf2f(k0.y) + qf[2]*bf2f(k0.z) + qf[3]*bf2f(k0.w)
             + Gf[0]*e00 + Gf[1]*e01 + Gf[2]*e02 + Gf[3]*e03;
    #pragma unroll
    for (int mk = 1; mk < 16; mk <<= 1) p0 += __shfl_xor(p0, mk);
    float w0 = __expf(fminf((p0 + bqe) * 0.125f, 60.f));
    s_run += w0;
    acc[0] += w0*bf2f(v0.x); acc[1] += w0*bf2f(v0.y);
    acc[2] += w0*bf2f(v0.z); acc[3] += w0*bf2f(v0.w);
    zz[0] += w0*e00; zz[1] += w0*e01; zz[2] += w0*e02; zz[3] += w0*e03;
  }
  const float inv_s = 1.0f / (s_run + 1e-16f);
  ushort4 o1, znv;
  o1.x = f2bf((acc[0] + s_run * bev.x) * inv_s);
  o1.y = f2bf((acc[1] + s_run * bev.y) * inv_s);
  o1.z = f2bf((acc[2] + s_run * bev.z) * inv_s);
  o1.w = f2bf((acc[3] + s_run * bev.w) * inv_s);
  znv.x = f2bf(zz[0] * inv_s); znv.y = f2bf(zz[1] * inv_s);
  znv.z = f2bf(zz[2] * inv_s); znv.w = f2bf(zz[3] * inv_s);
  *(ushort4*)(qo + (size_t)n * 256 + chb) = o1;
  *(ushort4*)(gz + (size_t)n * 256 + chb) = znv;
}

// ---------------- post: o = o1 + zn@wedge + x1@wskip + bskip -> LN -> relu ----------------
__global__ __launch_bounds__(256) void k_post(
    const u16* __restrict__ o1g, const u16* __restrict__ zng, const u16* __restrict__ x1g,
    const float* __restrict__ wedge, const float* __restrict__ wskip,
    const float* __restrict__ bskip, const float* __restrict__ lng, const float* __restrict__ lnb,
    u16* __restrict__ postg) {
  __shared__ float zL[8 * 256];
  __shared__ float x1L[8 * 64];
  const int t = threadIdx.x;
  const int n0 = blockIdx.x * 8;
  #pragma unroll
  for (int i = 0; i < 8; ++i) zL[i * 256 + t] = bf2f(zng[(size_t)(n0 + i) * 256 + t]);
  {
    int f = t;
    x1L[f] = bf2f(x1g[(size_t)(n0 + (f >> 6)) * 64 + (f & 63)]);
    f = t + 256;
    x1L[f] = bf2f(x1g[(size_t)(n0 + (f >> 6)) * 64 + (f & 63)]);
  }
  __syncthreads();
  const int nb = t >> 5;
  const int c0 = (t & 31) * 8;
  const int h = c0 >> 6;
  float o[8];
  {
    ushort4 oa = *(const ushort4*)(o1g + (size_t)(n0 + nb) * 256 + c0);
    ushort4 ob = *(const ushort4*)(o1g + (size_t)(n0 + nb) * 256 + c0 + 4);
    float4 b0 = *(const float4*)(bskip + c0);
    float4 b1 = *(const float4*)(bskip + c0 + 4);
    o[0] = bf2f(oa.x) + b0.x; o[1] = bf2f(oa.y) + b0.y;
    o[2] = bf2f(oa.z) + b0.z; o[3] = bf2f(oa.w) + b0.w;
    o[4] = bf2f(ob.x) + b1.x; o[5] = bf2f(ob.y) + b1.y;
    o[6] = bf2f(ob.z) + b1.z; o[7] = bf2f(ob.w) + b1.w;
  }
  const float* zrow = zL + nb * 256 + h * 64;
  const float* xrow = x1L + nb * 64;
  for (int j = 0; j < 64; ++j) {
    float zv = zrow[j];
    float xv = xrow[j];
    float4 we0 = *(const float4*)(wedge + j * 256 + c0);
    float4 we1v = *(const float4*)(wedge + j * 256 + c0 + 4);
    float4 ws0 = *(const float4*)(wskip + j * 256 + c0);
    float4 ws1 = *(const float4*)(wskip + j * 256 + c0 + 4);
    o[0] += zv * we0.x + xv * ws0.x;  o[1] += zv * we0.y + xv * ws0.y;
    o[2] += zv * we0.z + xv * ws0.z;  o[3] += zv * we0.w + xv * ws0.w;
    o[4] += zv * we1v.x + xv * ws1.x; o[5] += zv * we1v.y + xv * ws1.y;
    o[6] += zv * we1v.z + xv * ws1.z; o[7] += zv * we1v.w + xv * ws1.w;
  }
  float sum = ((o[0] + o[1]) + (o[2] + o[3])) + ((o[4] + o[5]) + (o[6] + o[7]));
  #pragma unroll
  for (int mk = 1; mk < 32; mk <<= 1) sum += __shfl_xor(sum, mk);
  const float mu = sum * (1.0f / 256.0f);
  float vs = 0.f;
  #pragma unroll
  for (int r = 0; r < 8; ++r) { float dd = o[r] - mu; vs += dd * dd; }
  #pragma unroll
  for (int mk = 1; mk < 32; mk <<= 1) vs += __shfl_xor(vs, mk);
  const float rstd = rsqrtf(vs * (1.0f / 256.0f) + 1e-5f);
  float4 g0 = *(const float4*)(lng + c0);
  float4 g1 = *(const float4*)(lng + c0 + 4);
  float4 lb0 = *(const float4*)(lnb + c0);
  float4 lb1 = *(const float4*)(lnb + c0 + 4);
  ushort4 pa, pb;
  pa.x = f2bf(fmaxf((o[0] - mu) * rstd * g0.x + lb0.x, 0.f));
  pa.y = f2bf(fmaxf((o[1] - mu) * rstd * g0.y + lb0.y, 0.f));
  pa.z = f2bf(fmaxf((o[2] - mu) * rstd * g0.z + lb0.z, 0.f));
  pa.w = f2bf(fmaxf((o[3] - mu) * rstd * g0.w + lb0.w, 0.f));
  pb.x = f2bf(fmaxf((o[4] - mu) * rstd * g1.x + lb1.x, 0.f));
  pb.y = f2bf(fmaxf((o[5] - mu) * rstd * g1.y + lb1.y, 0.f));
  pb.z = f2bf(fmaxf((o[6] - mu) * rstd * g1.z + lb1.z, 0.f));
  pb.w = f2bf(fmaxf((o[7] - mu) * rstd * g1.w + lb1.w, 0.f));
  *(ushort4*)(postg + (size_t)(n0 + nb) * 256 + c0) = pa;
  *(ushort4*)(postg + (size_t)(n0 + nb) * 256 + c0 + 4) = pb;
}

// ---------------- head ----------------
__global__ __launch_bounds__(256) void k_head(const u16* __restrict__ postg,
                                              const float* __restrict__ w1, const float* __restrict__ b1,
                                              const float* __restrict__ w2, const float* __restrict__ b2,
                                              float* __restrict__ outg) {
  __shared__ float ps[16 * 257];
  __shared__ float h1s[16 * 132];
  const int t = threadIdx.x;
  const int n0 = blockIdx.x * 16;
  for (int i = 0; i < 16; ++i)
    ps[i * 257 + t] = bf2f(postg[(size_t)(n0 + i) * 256 + t]);
  __syncthreads();
  const int node = t & 15, cg = t >> 4;
  float acc[8];
  #pragma unroll
  for (int i = 0; i < 8; ++i) acc[i] = b1[cg * 8 + i];
  for (int j = 0; j < 256; ++j) {
    float pv = ps[node * 257 + j];
    const float4* wp = (const float4*)(w1 + j * 128 + cg * 8);
    float4 wa = wp[0], wb = wp[1];
    acc[0] += pv * wa.x; acc[1] += pv * wa.y;
    acc[2] += pv * wa.z; acc[3] += pv * wa.w;
    acc[4] += pv * wb.x; acc[5] += pv * wb.y;
    acc[6] += pv * wb.z; acc[7] += pv * wb.w;
  }
  #pragma unroll
  for (int i = 0; i < 8; ++i) h1s[node * 132 + cg * 8 + i] = fmaxf(acc[i], 0.f);
  __syncthreads();
  const int node2 = t >> 4, tt = t & 15;
  float lg[4] = {0, 0, 0, 0};
  for (int j = tt; j < 128; j += 16) {
    float hv = h1s[node2 * 132 + j];
    float4 w2v = *(const float4*)(w2 + j * 4);
    lg[0] += hv * w2v.x; lg[1] += hv * w2v.y;
    lg[2] += hv * w2v.z; lg[3] += hv * w2v.w;
  }
  #pragma unroll
  for (int mk = 1; mk < 16; mk <<= 1) {
    lg[0] += __shfl_xor(lg[0], mk); lg[1] += __shfl_xor(lg[1], mk);
    lg[2] += __shfl_xor(lg[2], mk); lg[3] += __shfl_xor(lg[3], mk);
  }
  if (tt == 0) {
    #pragma unroll
    for (int c = 0; c < 4; ++c) lg[c] += b2[c];
    float mx = fmaxf(fmaxf(lg[0], lg[1]), fmaxf(lg[2], lg[3]));
    float se = __expf(lg[0] - mx) + __expf(lg[1] - mx) + __expf(lg[2] - mx) + __expf(lg[3] - mx);
    float lse = mx + __logf(se);
    float4 ov = make_float4(lg[0] - lse, lg[1] - lse, lg[2] - lse, lg[3] - lse);
    *(float4*)(outg + (size_t)(n0 + node2) * 4) = ov;
  }
}

extern "C" void kernel_launch(void* const* d_in, const int* in_sizes, int n_in,
                              void* d_out, int out_size, void* d_ws, size_t ws_size,
                              hipStream_t stream) {
  const float* x     = (const float*)d_in[0];
  const int*   ei    = (const int*)d_in[1];
  const float* ea    = (const float*)d_in[2];
  const float* w00   = (const float*)d_in[3];
  const float* b00   = (const float*)d_in[4];
  const float* we1   = (const float*)d_in[5];
  const float* be1   = (const float*)d_in[6];
  const float* we2   = (const float*)d_in[7];
  const float* be2   = (const float*)d_in[8];
  const float* we3   = (const float*)d_in[9];
  const float* be3   = (const float*)d_in[10];
  const float* wq    = (const float*)d_in[11];
  const float* bq    = (const float*)d_in[12];
  const float* wk    = (const float*)d_in[13];
  const float* bk    = (const float*)d_in[14];
  const float* wv    = (const float*)d_in[15];
  const float* bv    = (const float*)d_in[16];
  const float* wedge = (const float*)d_in[17];
  const float* bedge = (const float*)d_in[18];
  const float* wskip = (const float*)d_in[19];
  const float* bskip = (const float*)d_in[20];
  const float* lng   = (const float*)d_in[21];
  const float* lnb   = (const float*)d_in[22];
  const float* w1    = (const float*)d_in[23];
  const float* b1    = (const float*)d_in[24];
  const float* w2    = (const float*)d_in[25];
  const float* b2    = (const float*)d_in[26];
  float* outg = (float*)d_out;

  size_t off = 0;
  char* wsb = (char*)d_ws;
  auto carve = [&](size_t bytes) -> char* {
    char* r = wsb + off;
    off += (bytes + 255) & ~(size_t)255;
    return r;
  };
  u16* kvg    = (u16*)carve((size_t)NN * 512 * 2);  // k|v interleaved; reused as postg
  u16* qg     = (u16*)carve((size_t)NN * 256 * 2);  // q -> o1
  u16* Gg     = (u16*)carve((size_t)NN * 256 * 2);  // G -> zn
  u16* x1g    = (u16*)carve((size_t)NN * 64 * 2);
  u16* e3g    = (u16*)carve((size_t)NE * 64 * 2);
  int* deg    = (int*)carve((size_t)NN * 4);
  int* rowptr = (int*)carve((size_t)(NN + 1) * 4);
  int* cursor = (int*)carve((size_t)NN * 4);
  int* elist  = (int*)carve((size_t)NE * 4);
  int* slist  = (int*)carve((size_t)NE * 4);
  float* wT   = (float*)carve(16384 * 4);
  u16* wB1t   = (u16*)carve(512 * 2);
  u16* wB2t   = (u16*)carve(4096 * 2);
  u16* wB3t   = (u16*)carve(4096 * 2);
  u16* postg  = kvg;
  if (off > ws_size) return;

  k_prep<<<64, 256, 0, stream>>>(wedge, wT);
  k_prep_w<<<34, 256, 0, stream>>>(we1, we2, we3, wB1t, wB2t, wB3t);
  k_zero<<<(NN + 255) / 256, 256, 0, stream>>>(deg);
  k_hist<<<NE / 256, 256, 0, stream>>>(ei, deg);
  k_scan<<<1, 1024, 0, stream>>>(deg, rowptr, cursor);
  k_scatter<<<NE / 256, 256, 0, stream>>>(ei, cursor, elist, slist);
  k_node<<<NN / 8, 256, 0, stream>>>(x, w00, b00, wq, bq, wk, bk, wv, bv, x1g, qg, kvg);
  k_gmat<<<NN / 8, 256, 0, stream>>>(qg, wT, Gg);
  k_edge_mlp<<<NE / EPB, 256, 0, stream>>>(ea, wB1t, wB2t, wB3t, be1, be2, be3, e3g);
  k_attn<<<NN / 4, 256, 0, stream>>>(rowptr, elist, slist, qg, kvg, Gg, e3g, bedge);
  k_post<<<NN / 8, 256, 0, stream>>>(qg, Gg, x1g, wedge, wskip, bskip, lng, lnb, postg);
  k_head<<<NN / 16, 256, 0, stream>>>(postg, w1, b1, w2, b2, outg);
}

// Round 6
// 882.834 us; speedup vs baseline: 1.3493x; 1.1593x over previous
//
#include <hip/hip_runtime.h>
#include <hip/hip_bf16.h>

typedef unsigned short u16;
typedef __attribute__((ext_vector_type(8))) short bf16x8;
typedef __attribute__((ext_vector_type(4))) float f32x4;

#define NN 50000
#define NE 800000

__device__ __forceinline__ float bf2f(u16 u) { return __uint_as_float(((unsigned)u) << 16); }
__device__ __forceinline__ u16 f2bf(float f) {
  unsigned u = __float_as_uint(f);
  return (u16)((u + 0x7FFFu + ((u >> 16) & 1u)) >> 16);
}

// ---------------- CSR build ----------------
__global__ void k_zero(int* __restrict__ deg) {
  int i = blockIdx.x * 256 + threadIdx.x;
  if (i < NN) deg[i] = 0;
}

__global__ void k_hist(const int* __restrict__ ei, int* __restrict__ deg) {
  int i = blockIdx.x * 256 + threadIdx.x;
  if (i < NE) {
    int d = ei[NE + i];
    if (d >= 0 && d < NN) atomicAdd(&deg[d], 1);
  }
}

#define SCAN_T 1024
#define SCAN_CH 49
__global__ __launch_bounds__(1024) void k_scan(const int* __restrict__ deg,
                                               int* __restrict__ rowptr,
                                               int* __restrict__ cursor) {
  __shared__ int sums[SCAN_T];
  const int t = threadIdx.x;
  const int start = t * SCAN_CH;
  int lsum = 0;
  for (int i = 0; i < SCAN_CH; ++i) {
    int idx = start + i;
    if (idx < NN) lsum += deg[idx];
  }
  sums[t] = lsum;
  __syncthreads();
  for (int offs = 1; offs < SCAN_T; offs <<= 1) {
    int v = (t >= offs) ? sums[t - offs] : 0;
    __syncthreads();
    sums[t] += v;
    __syncthreads();
  }
  int run = (t == 0) ? 0 : sums[t - 1];
  for (int i = 0; i < SCAN_CH; ++i) {
    int idx = start + i;
    if (idx < NN) {
      rowptr[idx] = run;
      cursor[idx] = run;
      run += deg[idx];
    }
  }
  if (t == SCAN_T - 1) rowptr[NN] = run;
}

__global__ void k_scatter(const int* __restrict__ ei, int* __restrict__ cursor,
                          int* __restrict__ elist, int* __restrict__ slist) {
  int i = blockIdx.x * 256 + threadIdx.x;
  if (i < NE) {
    int d = ei[NE + i];
    if (d >= 0 && d < NN) {
      int pos = atomicAdd(&cursor[d], 1);
      if (pos >= 0 && pos < NE) {
        elist[pos] = i;
        int s = ei[i];
        slist[pos] = max(0, min(s, NN - 1));
      }
    }
  }
}

// ---------------- weight prep ----------------
// wT (fp32): wT[h*64+c][j] = wedge[j][h*64+c]  (for k_gmat)
__global__ void k_prep(const float* __restrict__ wedge, float* __restrict__ wT) {
  int i = blockIdx.x * 256 + threadIdx.x;  // i = c*64 + j
  if (i < 16384) {
    int c = i >> 6, j = i & 63;
    wT[i] = wedge[j * 256 + c];
  }
}

// bf16 transposed edge-MLP weights for MFMA B-fragments
__global__ void k_prep_w(const float* __restrict__ we1, const float* __restrict__ we2,
                         const float* __restrict__ we3,
                         u16* __restrict__ wB1t, u16* __restrict__ wB2t, u16* __restrict__ wB3t) {
  int i = blockIdx.x * 256 + threadIdx.x;
  if (i < 512) {
    int n = i >> 3, k = i & 7;
    wB1t[i] = f2bf(we1[k * 64 + n]);
  } else if (i < 512 + 4096) {
    int i2 = i - 512;
    int n = i2 >> 6, k = i2 & 63;
    wB2t[i2] = f2bf(we2[k * 64 + n]);
  } else if (i < 512 + 8192) {
    int i2 = i - 512 - 4096;
    int n = i2 >> 6, k = i2 & 63;
    wB3t[i2] = f2bf(we3[k * 64 + n]);
  }
}

// Bt[col][k] (bf16, K=320): rows 0..255 block-diag wedge, rows 256..319 wskip.
// Bt[col*320+k] = (k<256) ? ((k>>6)==(col>>6) ? wedge[(k&63)*256+col] : 0)
//                         : wskip[(k-256)*256+col]
__global__ void k_prep_b(const float* __restrict__ wedge, const float* __restrict__ wskip,
                         u16* __restrict__ Bt) {
  const int col = blockIdx.x;
  const int k = threadIdx.x;
  float v;
  if (k < 256) v = ((k >> 6) == (col >> 6)) ? wedge[(k & 63) * 256 + col] : 0.f;
  else v = wskip[(k - 256) * 256 + col];
  Bt[col * 320 + k] = f2bf(v);
}

// ---------------- node: x1 = relu(x@w00+b00), q + interleaved k|v ----------------
__global__ __launch_bounds__(256) void k_node(
    const float* __restrict__ x, const float* __restrict__ w00, const float* __restrict__ b00,
    const float* __restrict__ wq, const float* __restrict__ bq,
    const float* __restrict__ wk, const float* __restrict__ bk,
    const float* __restrict__ wv, const float* __restrict__ bv,
    u16* __restrict__ x1g, u16* __restrict__ qg, u16* __restrict__ kvg) {
  __shared__ float xs[128];
  __shared__ float x1s[8 * 65];
  const int t = threadIdx.x;
  const int n0 = blockIdx.x * 8;
  if (t < 128) xs[t] = x[n0 * 16 + t];
  __syncthreads();
  #pragma unroll
  for (int it = 0; it < 2; ++it) {
    int nb = it * 4 + (t >> 6);
    int col = t & 63;
    float v = b00[col];
    #pragma unroll
    for (int i = 0; i < 16; ++i) v += xs[nb * 16 + i] * w00[i * 64 + col];
    v = fmaxf(v, 0.f);
    x1s[nb * 65 + col] = v;
    x1g[(n0 + nb) * 64 + col] = f2bf(v);
  }
  __syncthreads();
  float aq[8], ak[8], av[8];
  const float bqv = bq[t], bkv = bk[t], bvv = bv[t];
  #pragma unroll
  for (int nb = 0; nb < 8; ++nb) { aq[nb] = bqv; ak[nb] = bkv; av[nb] = bvv; }
  for (int j = 0; j < 64; ++j) {
    float wqv = wq[j * 256 + t];
    float wkv = wk[j * 256 + t];
    float wvv = wv[j * 256 + t];
    #pragma unroll
    for (int nb = 0; nb < 8; ++nb) {
      float xv = x1s[nb * 65 + j];
      aq[nb] += xv * wqv; ak[nb] += xv * wkv; av[nb] += xv * wvv;
    }
  }
  #pragma unroll
  for (int nb = 0; nb < 8; ++nb) {
    qg[(n0 + nb) * 256 + t] = f2bf(aq[nb]);
    kvg[(size_t)(n0 + nb) * 512 + t] = f2bf(ak[nb]);
    kvg[(size_t)(n0 + nb) * 512 + 256 + t] = f2bf(av[nb]);
  }
}

// ---------------- G[n,h,j] = sum_c q[n,h,c] * wedge[j, h*64+c] ----------------
__global__ __launch_bounds__(256) void k_gmat(const u16* __restrict__ qg,
                                              const float* __restrict__ wT,
                                              u16* __restrict__ Gg) {
  __shared__ float qs[8 * 256];
  const int t = threadIdx.x;
  const int n0 = blockIdx.x * 8;
  #pragma unroll
  for (int i = 0; i < 8; ++i) qs[i * 256 + t] = bf2f(qg[(n0 + i) * 256 + t]);
  __syncthreads();
  const int h = t >> 6, j = t & 63;
  float acc[8] = {0, 0, 0, 0, 0, 0, 0, 0};
  for (int c = 0; c < 64; ++c) {
    float wv = wT[(h * 64 + c) * 64 + j];
    #pragma unroll
    for (int nb = 0; nb < 8; ++nb) acc[nb] += qs[nb * 256 + h * 64 + c] * wv;
  }
  #pragma unroll
  for (int nb = 0; nb < 8; ++nb) Gg[(n0 + nb) * 256 + t] = f2bf(acc[nb]);
}

// ---------------- edge MLP via MFMA bf16 ----------------
#define EPB 128
#define APAD 72
__global__ __launch_bounds__(256) void k_edge_mlp(
    const float* __restrict__ ea,
    const u16* __restrict__ wB1t, const u16* __restrict__ wB2t, const u16* __restrict__ wB3t,
    const float* __restrict__ be1, const float* __restrict__ be2, const float* __restrict__ be3,
    u16* __restrict__ e3g) {
  __shared__ u16 actA[EPB * APAD];
  __shared__ u16 actB[EPB * APAD];
  const int t = threadIdx.x;
  const int w = t >> 6, l = t & 63;
  const int quad = l >> 4, li = l & 15;
  const int e0 = blockIdx.x * EPB;
  const f32x4 zc = {0.f, 0.f, 0.f, 0.f};

  float b1c[4], b2c[4], b3c[4];
  #pragma unroll
  for (int nt = 0; nt < 4; ++nt) {
    b1c[nt] = be1[nt * 16 + li];
    b2c[nt] = be2[nt * 16 + li];
    b3c[nt] = be3[nt * 16 + li];
  }

  bf16x8 b1f[4];
  #pragma unroll
  for (int nt = 0; nt < 4; ++nt) {
    bf16x8 z = {};
    if (quad == 0) z = *(const bf16x8*)(wB1t + (nt * 16 + li) * 8);
    b1f[nt] = z;
  }
  #pragma unroll
  for (int mi = 0; mi < 2; ++mi) {
    const int mt = w * 2 + mi;
    bf16x8 af = {};
    if (quad == 0) {
      const float4* pa = (const float4*)(ea + (size_t)(e0 + mt * 16 + li) * 8);
      float4 p0 = pa[0], p1 = pa[1];
      af[0] = (short)f2bf(p0.x); af[1] = (short)f2bf(p0.y);
      af[2] = (short)f2bf(p0.z); af[3] = (short)f2bf(p0.w);
      af[4] = (short)f2bf(p1.x); af[5] = (short)f2bf(p1.y);
      af[6] = (short)f2bf(p1.z); af[7] = (short)f2bf(p1.w);
    }
    #pragma unroll
    for (int nt = 0; nt < 4; ++nt) {
      f32x4 d = __builtin_amdgcn_mfma_f32_16x16x32_bf16(af, b1f[nt], zc, 0, 0, 0);
      #pragma unroll
      for (int r = 0; r < 4; ++r)
        actA[(mt * 16 + quad * 4 + r) * APAD + nt * 16 + li] = f2bf(fmaxf(d[r] + b1c[nt], 0.f));
    }
  }
  __syncthreads();

  {
    bf16x8 bf[4][2];
    #pragma unroll
    for (int nt = 0; nt < 4; ++nt)
      #pragma unroll
      for (int kk = 0; kk < 2; ++kk)
        bf[nt][kk] = *(const bf16x8*)(wB2t + (nt * 16 + li) * 64 + kk * 32 + quad * 8);
    #pragma unroll
    for (int mi = 0; mi < 2; ++mi) {
      const int mt = w * 2 + mi;
      bf16x8 a0 = *(const bf16x8*)(actA + (mt * 16 + li) * APAD + quad * 8);
      bf16x8 a1 = *(const bf16x8*)(actA + (mt * 16 + li) * APAD + 32 + quad * 8);
      #pragma unroll
      for (int nt = 0; nt < 4; ++nt) {
        f32x4 d = __builtin_amdgcn_mfma_f32_16x16x32_bf16(a0, bf[nt][0], zc, 0, 0, 0);
        d = __builtin_amdgcn_mfma_f32_16x16x32_bf16(a1, bf[nt][1], d, 0, 0, 0);
        #pragma unroll
        for (int r = 0; r < 4; ++r)
          actB[(mt * 16 + quad * 4 + r) * APAD + nt * 16 + li] = f2bf(fmaxf(d[r] + b2c[nt], 0.f));
      }
    }
  }
  __syncthreads();

  {
    bf16x8 bf[4][2];
    #pragma unroll
    for (int nt = 0; nt < 4; ++nt)
      #pragma unroll
      for (int kk = 0; kk < 2; ++kk)
        bf[nt][kk] = *(const bf16x8*)(wB3t + (nt * 16 + li) * 64 + kk * 32 + quad * 8);
    #pragma unroll
    for (int mi = 0; mi < 2; ++mi) {
      const int mt = w * 2 + mi;
      bf16x8 a0 = *(const bf16x8*)(actB + (mt * 16 + li) * APAD + quad * 8);
      bf16x8 a1 = *(const bf16x8*)(actB + (mt * 16 + li) * APAD + 32 + quad * 8);
      #pragma unroll
      for (int nt = 0; nt < 4; ++nt) {
        f32x4 d = __builtin_amdgcn_mfma_f32_16x16x32_bf16(a0, bf[nt][0], zc, 0, 0, 0);
        d = __builtin_amdgcn_mfma_f32_16x16x32_bf16(a1, bf[nt][1], d, 0, 0, 0);
        #pragma unroll
        for (int r = 0; r < 4; ++r)
          actA[(mt * 16 + quad * 4 + r) * APAD + nt * 16 + li] = f2bf(fmaxf(d[r] + b3c[nt], 0.f));
      }
    }
  }
  __syncthreads();

  #pragma unroll
  for (int it = 0; it < 4; ++it) {
    int flat = it * 2048 + t * 8;
    int el = flat >> 6, c = flat & 63;
    uint4 v = *(const uint4*)(actA + el * APAD + c);
    *(uint4*)(e3g + (size_t)(e0 + el) * 64 + c) = v;
  }
}

// ---------------- attention gather: wave-per-node, single-pass softmax ----------------
__global__ __launch_bounds__(256) void k_attn(
    const int* __restrict__ rowptr, const int* __restrict__ elist, const int* __restrict__ slist,
    u16* qo, const u16* __restrict__ kvg, u16* gz, const u16* __restrict__ e3g,
    const float* __restrict__ bedge) {
  const int t = threadIdx.x;
  const int w = t >> 6;
  const int l = t & 63;
  const int grp = l >> 4;
  const int li = l & 15;
  const int chb = grp * 64 + li * 4;
  const int n = blockIdx.x * 4 + w;
  int base = rowptr[n];
  int end  = rowptr[n + 1];
  base = max(0, min(base, NE));
  end  = max(base, min(end, NE));

  float qf[4], Gf[4];
  {
    ushort4 qv = *(const ushort4*)(qo + (size_t)n * 256 + chb);
    qf[0] = bf2f(qv.x); qf[1] = bf2f(qv.y); qf[2] = bf2f(qv.z); qf[3] = bf2f(qv.w);
    ushort4 gv = *(const ushort4*)(gz + (size_t)n * 256 + chb);
    Gf[0] = bf2f(gv.x); Gf[1] = bf2f(gv.y); Gf[2] = bf2f(gv.z); Gf[3] = bf2f(gv.w);
  }
  float4 bev = *(const float4*)(bedge + chb);
  float bqe = qf[0] * bev.x + qf[1] * bev.y + qf[2] * bev.z + qf[3] * bev.w;
  #pragma unroll
  for (int mk = 1; mk < 16; mk <<= 1) bqe += __shfl_xor(bqe, mk);

  float s_run = 0.f;
  float acc[4] = {0, 0, 0, 0}, zz[4] = {0, 0, 0, 0};
  int d = base;
  for (; d + 1 < end; d += 2) {
    int eid0 = elist[d],     src0 = slist[d];
    int eid1 = elist[d + 1], src1 = slist[d + 1];
    eid0 = max(0, min(eid0, NE - 1)); eid1 = max(0, min(eid1, NE - 1));
    src0 = max(0, min(src0, NN - 1)); src1 = max(0, min(src1, NN - 1));
    ushort4 k0 = *(const ushort4*)(kvg + (size_t)src0 * 512 + chb);
    ushort4 v0 = *(const ushort4*)(kvg + (size_t)src0 * 512 + 256 + chb);
    ushort4 e0 = *(const ushort4*)(e3g + (size_t)eid0 * 64 + li * 4);
    ushort4 k1 = *(const ushort4*)(kvg + (size_t)src1 * 512 + chb);
    ushort4 v1 = *(const ushort4*)(kvg + (size_t)src1 * 512 + 256 + chb);
    ushort4 e1 = *(const ushort4*)(e3g + (size_t)eid1 * 64 + li * 4);
    float e00 = bf2f(e0.x), e01 = bf2f(e0.y), e02 = bf2f(e0.z), e03 = bf2f(e0.w);
    float e10 = bf2f(e1.x), e11 = bf2f(e1.y), e12 = bf2f(e1.z), e13 = bf2f(e1.w);
    float p0 = qf[0]*bf2f(k0.x) + qf[1]*bf2f(k0.y) + qf[2]*bf2f(k0.z) + qf[3]*bf2f(k0.w)
             + Gf[0]*e00 + Gf[1]*e01 + Gf[2]*e02 + Gf[3]*e03;
    float p1 = qf[0]*bf2f(k1.x) + qf[1]*bf2f(k1.y) + qf[2]*bf2f(k1.z) + qf[3]*bf2f(k1.w)
             + Gf[0]*e10 + Gf[1]*e11 + Gf[2]*e12 + Gf[3]*e13;
    #pragma unroll
    for (int mk = 1; mk < 16; mk <<= 1) { p0 += __shfl_xor(p0, mk); p1 += __shfl_xor(p1, mk); }
    float w0 = __expf(fminf((p0 + bqe) * 0.125f, 60.f));
    float w1 = __expf(fminf((p1 + bqe) * 0.125f, 60.f));
    s_run += w0 + w1;
    acc[0] += w0*bf2f(v0.x) + w1*bf2f(v1.x);
    acc[1] += w0*bf2f(v0.y) + w1*bf2f(v1.y);
    acc[2] += w0*bf2f(v0.z) + w1*bf2f(v1.z);
    acc[3] += w0*bf2f(v0.w) + w1*bf2f(v1.w);
    zz[0] += w0*e00 + w1*e10; zz[1] += w0*e01 + w1*e11;
    zz[2] += w0*e02 + w1*e12; zz[3] += w0*e03 + w1*e13;
  }
  if (d < end) {
    int eid0 = elist[d], src0 = slist[d];
    eid0 = max(0, min(eid0, NE - 1));
    src0 = max(0, min(src0, NN - 1));
    ushort4 k0 = *(const ushort4*)(kvg + (size_t)src0 * 512 + chb);
    ushort4 v0 = *(const ushort4*)(kvg + (size_t)src0 * 512 + 256 + chb);
    ushort4 e0 = *(const ushort4*)(e3g + (size_t)eid0 * 64 + li * 4);
    float e00 = bf2f(e0.x), e01 = bf2f(e0.y), e02 = bf2f(e0.z), e03 = bf2f(e0.w);
    float p0 = qf[0]*bf2f(k0.x) + qf[1]*bf2f(k0.y) + qf[2]*bf2f(k0.z) + qf[3]*bf2f(k0.w)
             + Gf[0]*e00 + Gf[1]*e01 + Gf[2]*e02 + Gf[3]*e03;
    #pragma unroll
    for (int mk = 1; mk < 16; mk <<= 1) p0 += __shfl_xor(p0, mk);
    float w0 = __expf(fminf((p0 + bqe) * 0.125f, 60.f));
    s_run += w0;
    acc[0] += w0*bf2f(v0.x); acc[1] += w0*bf2f(v0.y);
    acc[2] += w0*bf2f(v0.z); acc[3] += w0*bf2f(v0.w);
    zz[0] += w0*e00; zz[1] += w0*e01; zz[2] += w0*e02; zz[3] += w0*e03;
  }
  const float inv_s = 1.0f / (s_run + 1e-16f);
  ushort4 o1, znv;
  o1.x = f2bf((acc[0] + s_run * bev.x) * inv_s);
  o1.y = f2bf((acc[1] + s_run * bev.y) * inv_s);
  o1.z = f2bf((acc[2] + s_run * bev.z) * inv_s);
  o1.w = f2bf((acc[3] + s_run * bev.w) * inv_s);
  znv.x = f2bf(zz[0] * inv_s); znv.y = f2bf(zz[1] * inv_s);
  znv.z = f2bf(zz[2] * inv_s); znv.w = f2bf(zz[3] * inv_s);
  *(ushort4*)(qo + (size_t)n * 256 + chb) = o1;
  *(ushort4*)(gz + (size_t)n * 256 + chb) = znv;
}

// ---------------- post via MFMA: out = o1 + [zn|x1]@Bt^T + bskip -> LN -> relu ----------------
// A [64 x 320] bf16 in LDS; B-frags streamed from Bt (L2-resident).
// C/D: col=lane&15, row=quad*4+reg (m89/m91-verified).
#define PM 64
#define PK 320
#define PAPAD 328   // u16 stride: 656 B/row (16B-aligned, 2-way banks max)
__global__ __launch_bounds__(256) void k_post(
    const u16* __restrict__ o1g, const u16* __restrict__ zng, const u16* __restrict__ x1g,
    const u16* __restrict__ Bt,
    const float* __restrict__ bskip, const float* __restrict__ lng, const float* __restrict__ lnb,
    u16* __restrict__ postg) {
  __shared__ u16 As[PM * PAPAD];
  __shared__ float ps1[PM * 4];
  __shared__ float ps2[PM * 4];
  const int t = threadIdx.x;
  const int w = t >> 6, l = t & 63;
  const int quad = l >> 4, li = l & 15;
  const int n0 = blockIdx.x * PM;

  // stage A = [zn | x1], zero-padded beyond NN
  for (int q = t; q < 2048; q += 256) {
    int row = q >> 5, off = (q & 31) * 8;
    uint4 v = make_uint4(0, 0, 0, 0);
    if (n0 + row < NN) v = *(const uint4*)(zng + (size_t)(n0 + row) * 256 + off);
    *(uint4*)(As + row * PAPAD + off) = v;
  }
  for (int q = t; q < 512; q += 256) {
    int row = q >> 3, off = (q & 7) * 8;
    uint4 v = make_uint4(0, 0, 0, 0);
    if (n0 + row < NN) v = *(const uint4*)(x1g + (size_t)(n0 + row) * 64 + off);
    *(uint4*)(As + row * PAPAD + 256 + off) = v;
  }
  __syncthreads();

  f32x4 acc[4][4];   // [mt][nt]
  #pragma unroll
  for (int mt = 0; mt < 4; ++mt)
    #pragma unroll
    for (int nt = 0; nt < 4; ++nt) acc[mt][nt] = (f32x4){0.f, 0.f, 0.f, 0.f};

  const int colbase = w * 64;
  #pragma unroll
  for (int s = 0; s < 10; ++s) {
    bf16x8 bf[4];
    #pragma unroll
    for (int nt = 0; nt < 4; ++nt)
      bf[nt] = *(const bf16x8*)(Bt + (size_t)(colbase + nt * 16 + li) * PK + s * 32 + quad * 8);
    #pragma unroll
    for (int mt = 0; mt < 4; ++mt) {
      bf16x8 af = *(const bf16x8*)(As + (mt * 16 + li) * PAPAD + s * 32 + quad * 8);
      #pragma unroll
      for (int nt = 0; nt < 4; ++nt)
        acc[mt][nt] = __builtin_amdgcn_mfma_f32_16x16x32_bf16(af, bf[nt], acc[mt][nt], 0, 0, 0);
    }
  }

  // epilogue: + o1 + bskip, then LN over 256 channels per row
  float bs4[4], g4[4], lb4[4];
  #pragma unroll
  for (int nt = 0; nt < 4; ++nt) {
    int col = colbase + nt * 16 + li;
    bs4[nt] = bskip[col]; g4[nt] = lng[col]; lb4[nt] = lnb[col];
  }
  #pragma unroll
  for (int mt = 0; mt < 4; ++mt) {
    #pragma unroll
    for (int r = 0; r < 4; ++r) {
      int node = n0 + mt * 16 + quad * 4 + r;
      int nodeL = min(node, NN - 1);
      #pragma unroll
      for (int nt = 0; nt < 4; ++nt) {
        int col = colbase + nt * 16 + li;
        acc[mt][nt][r] += bs4[nt] + bf2f(o1g[(size_t)nodeL * 256 + col]);
      }
    }
  }
  // phase 1: row sums
  #pragma unroll
  for (int mt = 0; mt < 4; ++mt)
    #pragma unroll
    for (int r = 0; r < 4; ++r) {
      float s = acc[mt][0][r] + acc[mt][1][r] + acc[mt][2][r] + acc[mt][3][r];
      #pragma unroll
      for (int mk = 1; mk < 16; mk <<= 1) s += __shfl_xor(s, mk);
      if (li == 0) ps1[(mt * 16 + quad * 4 + r) * 4 + w] = s;
    }
  __syncthreads();
  float mu[4][4];
  #pragma unroll
  for (int mt = 0; mt < 4; ++mt)
    #pragma unroll
    for (int r = 0; r < 4; ++r) {
      float4 p = *(const float4*)(ps1 + (mt * 16 + quad * 4 + r) * 4);
      mu[mt][r] = (p.x + p.y + p.z + p.w) * (1.0f / 256.0f);
    }
  // phase 2: variance
  #pragma unroll
  for (int mt = 0; mt < 4; ++mt)
    #pragma unroll
    for (int r = 0; r < 4; ++r) {
      float m = mu[mt][r];
      float s = 0.f;
      #pragma unroll
      for (int nt = 0; nt < 4; ++nt) { float dd = acc[mt][nt][r] - m; s += dd * dd; }
      #pragma unroll
      for (int mk = 1; mk < 16; mk <<= 1) s += __shfl_xor(s, mk);
      if (li == 0) ps2[(mt * 16 + quad * 4 + r) * 4 + w] = s;
    }
  __syncthreads();
  #pragma unroll
  for (int mt = 0; mt < 4; ++mt)
    #pragma unroll
    for (int r = 0; r < 4; ++r) {
      float4 p = *(const float4*)(ps2 + (mt * 16 + quad * 4 + r) * 4);
      float rstd = rsqrtf((p.x + p.y + p.z + p.w) * (1.0f / 256.0f) + 1e-5f);
      int node = n0 + mt * 16 + quad * 4 + r;
      if (node < NN) {
        float m = mu[mt][r];
        #pragma unroll
        for (int nt = 0; nt < 4; ++nt) {
          int col = colbase + nt * 16 + li;
          postg[(size_t)node * 256 + col] =
              f2bf(fmaxf((acc[mt][nt][r] - m) * rstd * g4[nt] + lb4[nt], 0.f));
        }
      }
    }
}

// ---------------- head ----------------
__global__ __launch_bounds__(256) void k_head(const u16* __restrict__ postg,
                                              const float* __restrict__ w1, const float* __restrict__ b1,
                                              const float* __restrict__ w2, const float* __restrict__ b2,
                                              float* __restrict__ outg) {
  __shared__ float ps[16 * 257];
  __shared__ float h1s[16 * 132];
  const int t = threadIdx.x;
  const int n0 = blockIdx.x * 16;
  for (int i = 0; i < 16; ++i)
    ps[i * 257 + t] = bf2f(postg[(size_t)(n0 + i) * 256 + t]);
  __syncthreads();
  const int node = t & 15, cg = t >> 4;
  float acc[8];
  #pragma unroll
  for (int i = 0; i < 8; ++i) acc[i] = b1[cg * 8 + i];
  for (int j = 0; j < 256; ++j) {
    float pv = ps[node * 257 + j];
    const float4* wp = (const float4*)(w1 + j * 128 + cg * 8);
    float4 wa = wp[0], wb = wp[1];
    acc[0] += pv * wa.x; acc[1] += pv * wa.y;
    acc[2] += pv * wa.z; acc[3] += pv * wa.w;
    acc[4] += pv * wb.x; acc[5] += pv * wb.y;
    acc[6] += pv * wb.z; acc[7] += pv * wb.w;
  }
  #pragma unroll
  for (int i = 0; i < 8; ++i) h1s[node * 132 + cg * 8 + i] = fmaxf(acc[i], 0.f);
  __syncthreads();
  const int node2 = t >> 4, tt = t & 15;
  float lg[4] = {0, 0, 0, 0};
  for (int j = tt; j < 128; j += 16) {
    float hv = h1s[node2 * 132 + j];
    float4 w2v = *(const float4*)(w2 + j * 4);
    lg[0] += hv * w2v.x; lg[1] += hv * w2v.y;
    lg[2] += hv * w2v.z; lg[3] += hv * w2v.w;
  }
  #pragma unroll
  for (int mk = 1; mk < 16; mk <<= 1) {
    lg[0] += __shfl_xor(lg[0], mk); lg[1] += __shfl_xor(lg[1], mk);
    lg[2] += __shfl_xor(lg[2], mk); lg[3] += __shfl_xor(lg[3], mk);
  }
  if (tt == 0) {
    #pragma unroll
    for (int c = 0; c < 4; ++c) lg[c] += b2[c];
    float mx = fmaxf(fmaxf(lg[0], lg[1]), fmaxf(lg[2], lg[3]));
    float se = __expf(lg[0] - mx) + __expf(lg[1] - mx) + __expf(lg[2] - mx) + __expf(lg[3] - mx);
    float lse = mx + __logf(se);
    float4 ov = make_float4(lg[0] - lse, lg[1] - lse, lg[2] - lse, lg[3] - lse);
    *(float4*)(outg + (size_t)(n0 + node2) * 4) = ov;
  }
}

extern "C" void kernel_launch(void* const* d_in, const int* in_sizes, int n_in,
                              void* d_out, int out_size, void* d_ws, size_t ws_size,
                              hipStream_t stream) {
  const float* x     = (const float*)d_in[0];
  const int*   ei    = (const int*)d_in[1];
  const float* ea    = (const float*)d_in[2];
  const float* w00   = (const float*)d_in[3];
  const float* b00   = (const float*)d_in[4];
  const float* we1   = (const float*)d_in[5];
  const float* be1   = (const float*)d_in[6];
  const float* we2   = (const float*)d_in[7];
  const float* be2   = (const float*)d_in[8];
  const float* we3   = (const float*)d_in[9];
  const float* be3   = (const float*)d_in[10];
  const float* wq    = (const float*)d_in[11];
  const float* bq    = (const float*)d_in[12];
  const float* wk    = (const float*)d_in[13];
  const float* bk    = (const float*)d_in[14];
  const float* wv    = (const float*)d_in[15];
  const float* bv    = (const float*)d_in[16];
  const float* wedge = (const float*)d_in[17];
  const float* bedge = (const float*)d_in[18];
  const float* wskip = (const float*)d_in[19];
  const float* bskip = (const float*)d_in[20];
  const float* lng   = (const float*)d_in[21];
  const float* lnb   = (const float*)d_in[22];
  const float* w1    = (const float*)d_in[23];
  const float* b1    = (const float*)d_in[24];
  const float* w2    = (const float*)d_in[25];
  const float* b2    = (const float*)d_in[26];
  float* outg = (float*)d_out;

  size_t off = 0;
  char* wsb = (char*)d_ws;
  auto carve = [&](size_t bytes) -> char* {
    char* r = wsb + off;
    off += (bytes + 255) & ~(size_t)255;
    return r;
  };
  u16* kvg    = (u16*)carve((size_t)NN * 512 * 2);  // k|v interleaved; reused as postg
  u16* qg     = (u16*)carve((size_t)NN * 256 * 2);  // q -> o1
  u16* Gg     = (u16*)carve((size_t)NN * 256 * 2);  // G -> zn
  u16* x1g    = (u16*)carve((size_t)NN * 64 * 2);
  u16* e3g    = (u16*)carve((size_t)NE * 64 * 2);
  int* deg    = (int*)carve((size_t)NN * 4);
  int* rowptr = (int*)carve((size_t)(NN + 1) * 4);
  int* cursor = (int*)carve((size_t)NN * 4);
  int* elist  = (int*)carve((size_t)NE * 4);
  int* slist  = (int*)carve((size_t)NE * 4);
  float* wT   = (float*)carve(16384 * 4);
  u16* wB1t   = (u16*)carve(512 * 2);
  u16* wB2t   = (u16*)carve(4096 * 2);
  u16* wB3t   = (u16*)carve(4096 * 2);
  u16* Bt     = (u16*)carve((size_t)256 * 320 * 2);
  u16* postg  = kvg;
  if (off > ws_size) return;

  k_prep<<<64, 256, 0, stream>>>(wedge, wT);
  k_prep_w<<<34, 256, 0, stream>>>(we1, we2, we3, wB1t, wB2t, wB3t);
  k_prep_b<<<256, 320, 0, stream>>>(wedge, wskip, Bt);
  k_zero<<<(NN + 255) / 256, 256, 0, stream>>>(deg);
  k_hist<<<NE / 256, 256, 0, stream>>>(ei, deg);
  k_scan<<<1, 1024, 0, stream>>>(deg, rowptr, cursor);
  k_scatter<<<NE / 256, 256, 0, stream>>>(ei, cursor, elist, slist);
  k_node<<<NN / 8, 256, 0, stream>>>(x, w00, b00, wq, bq, wk, bk, wv, bv, x1g, qg, kvg);
  k_gmat<<<NN / 8, 256, 0, stream>>>(qg, wT, Gg);
  k_edge_mlp<<<NE / EPB, 256, 0, stream>>>(ea, wB1t, wB2t, wB3t, be1, be2, be3, e3g);
  k_attn<<<NN / 4, 256, 0, stream>>>(rowptr, elist, slist, qg, kvg, Gg, e3g, bedge);
  k_post<<<(NN + PM - 1) / PM, 256, 0, stream>>>(qg, Gg, x1g, Bt, bskip, lng, lnb, postg);
  k_head<<<NN / 16, 256, 0, stream>>>(postg, w1, b1, w2, b2, outg);
}

// Round 7
// 727.070 us; speedup vs baseline: 1.6383x; 1.2142x over previous
//
#include <hip/hip_runtime.h>
#include <hip/hip_bf16.h>

typedef unsigned short u16;
typedef __attribute__((ext_vector_type(8))) short bf16x8;
typedef __attribute__((ext_vector_type(4))) float f32x4;

#define NN 50000
#define NE 800000

__device__ __forceinline__ float bf2f(u16 u) { return __uint_as_float(((unsigned)u) << 16); }
__device__ __forceinline__ u16 f2bf(float f) {
  unsigned u = __float_as_uint(f);
  return (u16)((u + 0x7FFFu + ((u >> 16) & 1u)) >> 16);
}

// ---------------- CSR build ----------------
__global__ void k_zero(int* __restrict__ deg) {
  int i = blockIdx.x * 256 + threadIdx.x;
  if (i < NN) deg[i] = 0;
}

__global__ void k_hist(const int* __restrict__ ei, int* __restrict__ deg) {
  int i = blockIdx.x * 256 + threadIdx.x;
  if (i < NE) {
    int d = ei[NE + i];
    if (d >= 0 && d < NN) atomicAdd(&deg[d], 1);
  }
}

#define SCAN_T 1024
#define SCAN_CH 49
__global__ __launch_bounds__(1024) void k_scan(const int* __restrict__ deg,
                                               int* __restrict__ rowptr,
                                               int* __restrict__ cursor) {
  __shared__ int sums[SCAN_T];
  const int t = threadIdx.x;
  const int start = t * SCAN_CH;
  int lsum = 0;
  for (int i = 0; i < SCAN_CH; ++i) {
    int idx = start + i;
    if (idx < NN) lsum += deg[idx];
  }
  sums[t] = lsum;
  __syncthreads();
  for (int offs = 1; offs < SCAN_T; offs <<= 1) {
    int v = (t >= offs) ? sums[t - offs] : 0;
    __syncthreads();
    sums[t] += v;
    __syncthreads();
  }
  int run = (t == 0) ? 0 : sums[t - 1];
  for (int i = 0; i < SCAN_CH; ++i) {
    int idx = start + i;
    if (idx < NN) {
      rowptr[idx] = run;
      cursor[idx] = run;
      run += deg[idx];
    }
  }
  if (t == SCAN_T - 1) rowptr[NN] = run;
}

__global__ void k_scatter(const int* __restrict__ ei, int* __restrict__ cursor,
                          int* __restrict__ elist, int* __restrict__ slist) {
  int i = blockIdx.x * 256 + threadIdx.x;
  if (i < NE) {
    int d = ei[NE + i];
    if (d >= 0 && d < NN) {
      int pos = atomicAdd(&cursor[d], 1);
      if (pos >= 0 && pos < NE) {
        elist[pos] = i;
        int s = ei[i];
        slist[pos] = max(0, min(s, NN - 1));
      }
    }
  }
}

// ---------------- weight prep ----------------
__global__ void k_prep(const float* __restrict__ wedge, float* __restrict__ wT) {
  int i = blockIdx.x * 256 + threadIdx.x;  // i = c*64 + j
  if (i < 16384) {
    int c = i >> 6, j = i & 63;
    wT[i] = wedge[j * 256 + c];
  }
}

__global__ void k_prep_w(const float* __restrict__ we1, const float* __restrict__ we2,
                         const float* __restrict__ we3,
                         u16* __restrict__ wB1t, u16* __restrict__ wB2t, u16* __restrict__ wB3t) {
  int i = blockIdx.x * 256 + threadIdx.x;
  if (i < 512) {
    int n = i >> 3, k = i & 7;
    wB1t[i] = f2bf(we1[k * 64 + n]);
  } else if (i < 512 + 4096) {
    int i2 = i - 512;
    int n = i2 >> 6, k = i2 & 63;
    wB2t[i2] = f2bf(we2[k * 64 + n]);
  } else if (i < 512 + 8192) {
    int i2 = i - 512 - 4096;
    int n = i2 >> 6, k = i2 & 63;
    wB3t[i2] = f2bf(we3[k * 64 + n]);
  }
}

// Bt[col][k] (bf16, K=320): rows 0..255 block-diag wedge, rows 256..319 wskip.
__global__ void k_prep_b(const float* __restrict__ wedge, const float* __restrict__ wskip,
                         u16* __restrict__ Bt) {
  const int col = blockIdx.x;
  const int k = threadIdx.x;
  float v;
  if (k < 256) v = ((k >> 6) == (col >> 6)) ? wedge[(k & 63) * 256 + col] : 0.f;
  else v = wskip[(k - 256) * 256 + col];
  Bt[col * 320 + k] = f2bf(v);
}

// Bt1[col][k] (bf16): Bt1[col*256+k] = w1[k*128+col]  (col<128, k<256)
__global__ void k_prep_h(const float* __restrict__ w1, u16* __restrict__ Bt1) {
  const int col = blockIdx.x;
  const int k = threadIdx.x;
  Bt1[col * 256 + k] = f2bf(w1[k * 128 + col]);
}

// ---------------- node: x1 = relu(x@w00+b00), q + interleaved k|v ----------------
__global__ __launch_bounds__(256) void k_node(
    const float* __restrict__ x, const float* __restrict__ w00, const float* __restrict__ b00,
    const float* __restrict__ wq, const float* __restrict__ bq,
    const float* __restrict__ wk, const float* __restrict__ bk,
    const float* __restrict__ wv, const float* __restrict__ bv,
    u16* __restrict__ x1g, u16* __restrict__ qg, u16* __restrict__ kvg) {
  __shared__ float xs[128];
  __shared__ float x1s[8 * 65];
  const int t = threadIdx.x;
  const int n0 = blockIdx.x * 8;
  if (t < 128) xs[t] = x[n0 * 16 + t];
  __syncthreads();
  #pragma unroll
  for (int it = 0; it < 2; ++it) {
    int nb = it * 4 + (t >> 6);
    int col = t & 63;
    float v = b00[col];
    #pragma unroll
    for (int i = 0; i < 16; ++i) v += xs[nb * 16 + i] * w00[i * 64 + col];
    v = fmaxf(v, 0.f);
    x1s[nb * 65 + col] = v;
    x1g[(n0 + nb) * 64 + col] = f2bf(v);
  }
  __syncthreads();
  float aq[8], ak[8], av[8];
  const float bqv = bq[t], bkv = bk[t], bvv = bv[t];
  #pragma unroll
  for (int nb = 0; nb < 8; ++nb) { aq[nb] = bqv; ak[nb] = bkv; av[nb] = bvv; }
  for (int j = 0; j < 64; ++j) {
    float wqv = wq[j * 256 + t];
    float wkv = wk[j * 256 + t];
    float wvv = wv[j * 256 + t];
    #pragma unroll
    for (int nb = 0; nb < 8; ++nb) {
      float xv = x1s[nb * 65 + j];
      aq[nb] += xv * wqv; ak[nb] += xv * wkv; av[nb] += xv * wvv;
    }
  }
  #pragma unroll
  for (int nb = 0; nb < 8; ++nb) {
    qg[(n0 + nb) * 256 + t] = f2bf(aq[nb]);
    kvg[(size_t)(n0 + nb) * 512 + t] = f2bf(ak[nb]);
    kvg[(size_t)(n0 + nb) * 512 + 256 + t] = f2bf(av[nb]);
  }
}

// ---------------- G[n,h,j] = sum_c q[n,h,c] * wedge[j, h*64+c] ----------------
__global__ __launch_bounds__(256) void k_gmat(const u16* __restrict__ qg,
                                              const float* __restrict__ wT,
                                              u16* __restrict__ Gg) {
  __shared__ float qs[8 * 256];
  const int t = threadIdx.x;
  const int n0 = blockIdx.x * 8;
  #pragma unroll
  for (int i = 0; i < 8; ++i) qs[i * 256 + t] = bf2f(qg[(n0 + i) * 256 + t]);
  __syncthreads();
  const int h = t >> 6, j = t & 63;
  float acc[8] = {0, 0, 0, 0, 0, 0, 0, 0};
  for (int c = 0; c < 64; ++c) {
    float wv = wT[(h * 64 + c) * 64 + j];
    #pragma unroll
    for (int nb = 0; nb < 8; ++nb) acc[nb] += qs[nb * 256 + h * 64 + c] * wv;
  }
  #pragma unroll
  for (int nb = 0; nb < 8; ++nb) Gg[(n0 + nb) * 256 + t] = f2bf(acc[nb]);
}

// ---------------- edge MLP via MFMA bf16 ----------------
#define EPB 128
#define APAD 72
__global__ __launch_bounds__(256) void k_edge_mlp(
    const float* __restrict__ ea,
    const u16* __restrict__ wB1t, const u16* __restrict__ wB2t, const u16* __restrict__ wB3t,
    const float* __restrict__ be1, const float* __restrict__ be2, const float* __restrict__ be3,
    u16* __restrict__ e3g) {
  __shared__ u16 actA[EPB * APAD];
  __shared__ u16 actB[EPB * APAD];
  const int t = threadIdx.x;
  const int w = t >> 6, l = t & 63;
  const int quad = l >> 4, li = l & 15;
  const int e0 = blockIdx.x * EPB;
  const f32x4 zc = {0.f, 0.f, 0.f, 0.f};

  float b1c[4], b2c[4], b3c[4];
  #pragma unroll
  for (int nt = 0; nt < 4; ++nt) {
    b1c[nt] = be1[nt * 16 + li];
    b2c[nt] = be2[nt * 16 + li];
    b3c[nt] = be3[nt * 16 + li];
  }

  bf16x8 b1f[4];
  #pragma unroll
  for (int nt = 0; nt < 4; ++nt) {
    bf16x8 z = {};
    if (quad == 0) z = *(const bf16x8*)(wB1t + (nt * 16 + li) * 8);
    b1f[nt] = z;
  }
  #pragma unroll
  for (int mi = 0; mi < 2; ++mi) {
    const int mt = w * 2 + mi;
    bf16x8 af = {};
    if (quad == 0) {
      const float4* pa = (const float4*)(ea + (size_t)(e0 + mt * 16 + li) * 8);
      float4 p0 = pa[0], p1 = pa[1];
      af[0] = (short)f2bf(p0.x); af[1] = (short)f2bf(p0.y);
      af[2] = (short)f2bf(p0.z); af[3] = (short)f2bf(p0.w);
      af[4] = (short)f2bf(p1.x); af[5] = (short)f2bf(p1.y);
      af[6] = (short)f2bf(p1.z); af[7] = (short)f2bf(p1.w);
    }
    #pragma unroll
    for (int nt = 0; nt < 4; ++nt) {
      f32x4 d = __builtin_amdgcn_mfma_f32_16x16x32_bf16(af, b1f[nt], zc, 0, 0, 0);
      #pragma unroll
      for (int r = 0; r < 4; ++r)
        actA[(mt * 16 + quad * 4 + r) * APAD + nt * 16 + li] = f2bf(fmaxf(d[r] + b1c[nt], 0.f));
    }
  }
  __syncthreads();

  {
    bf16x8 bf[4][2];
    #pragma unroll
    for (int nt = 0; nt < 4; ++nt)
      #pragma unroll
      for (int kk = 0; kk < 2; ++kk)
        bf[nt][kk] = *(const bf16x8*)(wB2t + (nt * 16 + li) * 64 + kk * 32 + quad * 8);
    #pragma unroll
    for (int mi = 0; mi < 2; ++mi) {
      const int mt = w * 2 + mi;
      bf16x8 a0 = *(const bf16x8*)(actA + (mt * 16 + li) * APAD + quad * 8);
      bf16x8 a1 = *(const bf16x8*)(actA + (mt * 16 + li) * APAD + 32 + quad * 8);
      #pragma unroll
      for (int nt = 0; nt < 4; ++nt) {
        f32x4 d = __builtin_amdgcn_mfma_f32_16x16x32_bf16(a0, bf[nt][0], zc, 0, 0, 0);
        d = __builtin_amdgcn_mfma_f32_16x16x32_bf16(a1, bf[nt][1], d, 0, 0, 0);
        #pragma unroll
        for (int r = 0; r < 4; ++r)
          actB[(mt * 16 + quad * 4 + r) * APAD + nt * 16 + li] = f2bf(fmaxf(d[r] + b2c[nt], 0.f));
      }
    }
  }
  __syncthreads();

  {
    bf16x8 bf[4][2];
    #pragma unroll
    for (int nt = 0; nt < 4; ++nt)
      #pragma unroll
      for (int kk = 0; kk < 2; ++kk)
        bf[nt][kk] = *(const bf16x8*)(wB3t + (nt * 16 + li) * 64 + kk * 32 + quad * 8);
    #pragma unroll
    for (int mi = 0; mi < 2; ++mi) {
      const int mt = w * 2 + mi;
      bf16x8 a0 = *(const bf16x8*)(actB + (mt * 16 + li) * APAD + quad * 8);
      bf16x8 a1 = *(const bf16x8*)(actB + (mt * 16 + li) * APAD + 32 + quad * 8);
      #pragma unroll
      for (int nt = 0; nt < 4; ++nt) {
        f32x4 d = __builtin_amdgcn_mfma_f32_16x16x32_bf16(a0, bf[nt][0], zc, 0, 0, 0);
        d = __builtin_amdgcn_mfma_f32_16x16x32_bf16(a1, bf[nt][1], d, 0, 0, 0);
        #pragma unroll
        for (int r = 0; r < 4; ++r)
          actA[(mt * 16 + quad * 4 + r) * APAD + nt * 16 + li] = f2bf(fmaxf(d[r] + b3c[nt], 0.f));
      }
    }
  }
  __syncthreads();

  #pragma unroll
  for (int it = 0; it < 4; ++it) {
    int flat = it * 2048 + t * 8;
    int el = flat >> 6, c = flat & 63;
    uint4 v = *(const uint4*)(actA + el * APAD + c);
    *(uint4*)(e3g + (size_t)(e0 + el) * 64 + c) = v;
  }
}

// ---------------- attention gather: wave-per-node, single-pass softmax ----------------
__global__ __launch_bounds__(256) void k_attn(
    const int* __restrict__ rowptr, const int* __restrict__ elist, const int* __restrict__ slist,
    u16* qo, const u16* __restrict__ kvg, u16* gz, const u16* __restrict__ e3g,
    const float* __restrict__ bedge) {
  const int t = threadIdx.x;
  const int w = t >> 6;
  const int l = t & 63;
  const int grp = l >> 4;
  const int li = l & 15;
  const int chb = grp * 64 + li * 4;
  const int n = blockIdx.x * 4 + w;
  int base = rowptr[n];
  int end  = rowptr[n + 1];
  base = max(0, min(base, NE));
  end  = max(base, min(end, NE));

  float qf[4], Gf[4];
  {
    ushort4 qv = *(const ushort4*)(qo + (size_t)n * 256 + chb);
    qf[0] = bf2f(qv.x); qf[1] = bf2f(qv.y); qf[2] = bf2f(qv.z); qf[3] = bf2f(qv.w);
    ushort4 gv = *(const ushort4*)(gz + (size_t)n * 256 + chb);
    Gf[0] = bf2f(gv.x); Gf[1] = bf2f(gv.y); Gf[2] = bf2f(gv.z); Gf[3] = bf2f(gv.w);
  }
  float4 bev = *(const float4*)(bedge + chb);
  float bqe = qf[0] * bev.x + qf[1] * bev.y + qf[2] * bev.z + qf[3] * bev.w;
  #pragma unroll
  for (int mk = 1; mk < 16; mk <<= 1) bqe += __shfl_xor(bqe, mk);

  float s_run = 0.f;
  float acc[4] = {0, 0, 0, 0}, zz[4] = {0, 0, 0, 0};
  int d = base;
  for (; d + 1 < end; d += 2) {
    int eid0 = elist[d],     src0 = slist[d];
    int eid1 = elist[d + 1], src1 = slist[d + 1];
    eid0 = max(0, min(eid0, NE - 1)); eid1 = max(0, min(eid1, NE - 1));
    src0 = max(0, min(src0, NN - 1)); src1 = max(0, min(src1, NN - 1));
    ushort4 k0 = *(const ushort4*)(kvg + (size_t)src0 * 512 + chb);
    ushort4 v0 = *(const ushort4*)(kvg + (size_t)src0 * 512 + 256 + chb);
    ushort4 e0 = *(const ushort4*)(e3g + (size_t)eid0 * 64 + li * 4);
    ushort4 k1 = *(const ushort4*)(kvg + (size_t)src1 * 512 + chb);
    ushort4 v1 = *(const ushort4*)(kvg + (size_t)src1 * 512 + 256 + chb);
    ushort4 e1 = *(const ushort4*)(e3g + (size_t)eid1 * 64 + li * 4);
    float e00 = bf2f(e0.x), e01 = bf2f(e0.y), e02 = bf2f(e0.z), e03 = bf2f(e0.w);
    float e10 = bf2f(e1.x), e11 = bf2f(e1.y), e12 = bf2f(e1.z), e13 = bf2f(e1.w);
    float p0 = qf[0]*bf2f(k0.x) + qf[1]*bf2f(k0.y) + qf[2]*bf2f(k0.z) + qf[3]*bf2f(k0.w)
             + Gf[0]*e00 + Gf[1]*e01 + Gf[2]*e02 + Gf[3]*e03;
    float p1 = qf[0]*bf2f(k1.x) + qf[1]*bf2f(k1.y) + qf[2]*bf2f(k1.z) + qf[3]*bf2f(k1.w)
             + Gf[0]*e10 + Gf[1]*e11 + Gf[2]*e12 + Gf[3]*e13;
    #pragma unroll
    for (int mk = 1; mk < 16; mk <<= 1) { p0 += __shfl_xor(p0, mk); p1 += __shfl_xor(p1, mk); }
    float w0 = __expf(fminf((p0 + bqe) * 0.125f, 60.f));
    float w1 = __expf(fminf((p1 + bqe) * 0.125f, 60.f));
    s_run += w0 + w1;
    acc[0] += w0*bf2f(v0.x) + w1*bf2f(v1.x);
    acc[1] += w0*bf2f(v0.y) + w1*bf2f(v1.y);
    acc[2] += w0*bf2f(v0.z) + w1*bf2f(v1.z);
    acc[3] += w0*bf2f(v0.w) + w1*bf2f(v1.w);
    zz[0] += w0*e00 + w1*e10; zz[1] += w0*e01 + w1*e11;
    zz[2] += w0*e02 + w1*e12; zz[3] += w0*e03 + w1*e13;
  }
  if (d < end) {
    int eid0 = elist[d], src0 = slist[d];
    eid0 = max(0, min(eid0, NE - 1));
    src0 = max(0, min(src0, NN - 1));
    ushort4 k0 = *(const ushort4*)(kvg + (size_t)src0 * 512 + chb);
    ushort4 v0 = *(const ushort4*)(kvg + (size_t)src0 * 512 + 256 + chb);
    ushort4 e0 = *(const ushort4*)(e3g + (size_t)eid0 * 64 + li * 4);
    float e00 = bf2f(e0.x), e01 = bf2f(e0.y), e02 = bf2f(e0.z), e03 = bf2f(e0.w);
    float p0 = qf[0]*bf2f(k0.x) + qf[1]*bf2f(k0.y) + qf[2]*bf2f(k0.z) + qf[3]*bf2f(k0.w)
             + Gf[0]*e00 + Gf[1]*e01 + Gf[2]*e02 + Gf[3]*e03;
    #pragma unroll
    for (int mk = 1; mk < 16; mk <<= 1) p0 += __shfl_xor(p0, mk);
    float w0 = __expf(fminf((p0 + bqe) * 0.125f, 60.f));
    s_run += w0;
    acc[0] += w0*bf2f(v0.x); acc[1] += w0*bf2f(v0.y);
    acc[2] += w0*bf2f(v0.z); acc[3] += w0*bf2f(v0.w);
    zz[0] += w0*e00; zz[1] += w0*e01; zz[2] += w0*e02; zz[3] += w0*e03;
  }
  const float inv_s = 1.0f / (s_run + 1e-16f);
  ushort4 o1, znv;
  o1.x = f2bf((acc[0] + s_run * bev.x) * inv_s);
  o1.y = f2bf((acc[1] + s_run * bev.y) * inv_s);
  o1.z = f2bf((acc[2] + s_run * bev.z) * inv_s);
  o1.w = f2bf((acc[3] + s_run * bev.w) * inv_s);
  znv.x = f2bf(zz[0] * inv_s); znv.y = f2bf(zz[1] * inv_s);
  znv.z = f2bf(zz[2] * inv_s); znv.w = f2bf(zz[3] * inv_s);
  *(ushort4*)(qo + (size_t)n * 256 + chb) = o1;
  *(ushort4*)(gz + (size_t)n * 256 + chb) = znv;
}

// ---------------- post via MFMA: out = o1 + [zn|x1]@Bt^T + bskip -> LN -> relu ----------------
#define PM 64
#define PK 320
#define PAPAD 328
__global__ __launch_bounds__(256) void k_post(
    const u16* __restrict__ o1g, const u16* __restrict__ zng, const u16* __restrict__ x1g,
    const u16* __restrict__ Bt,
    const float* __restrict__ bskip, const float* __restrict__ lng, const float* __restrict__ lnb,
    u16* __restrict__ postg) {
  __shared__ u16 As[PM * PAPAD];
  __shared__ float ps1[PM * 4];
  __shared__ float ps2[PM * 4];
  const int t = threadIdx.x;
  const int w = t >> 6, l = t & 63;
  const int quad = l >> 4, li = l & 15;
  const int n0 = blockIdx.x * PM;

  for (int q = t; q < 2048; q += 256) {
    int row = q >> 5, off = (q & 31) * 8;
    uint4 v = make_uint4(0, 0, 0, 0);
    if (n0 + row < NN) v = *(const uint4*)(zng + (size_t)(n0 + row) * 256 + off);
    *(uint4*)(As + row * PAPAD + off) = v;
  }
  for (int q = t; q < 512; q += 256) {
    int row = q >> 3, off = (q & 7) * 8;
    uint4 v = make_uint4(0, 0, 0, 0);
    if (n0 + row < NN) v = *(const uint4*)(x1g + (size_t)(n0 + row) * 64 + off);
    *(uint4*)(As + row * PAPAD + 256 + off) = v;
  }
  __syncthreads();

  f32x4 acc[4][4];
  #pragma unroll
  for (int mt = 0; mt < 4; ++mt)
    #pragma unroll
    for (int nt = 0; nt < 4; ++nt) acc[mt][nt] = (f32x4){0.f, 0.f, 0.f, 0.f};

  const int colbase = w * 64;
  #pragma unroll
  for (int s = 0; s < 10; ++s) {
    bf16x8 bf[4];
    #pragma unroll
    for (int nt = 0; nt < 4; ++nt)
      bf[nt] = *(const bf16x8*)(Bt + (size_t)(colbase + nt * 16 + li) * PK + s * 32 + quad * 8);
    #pragma unroll
    for (int mt = 0; mt < 4; ++mt) {
      bf16x8 af = *(const bf16x8*)(As + (mt * 16 + li) * PAPAD + s * 32 + quad * 8);
      #pragma unroll
      for (int nt = 0; nt < 4; ++nt)
        acc[mt][nt] = __builtin_amdgcn_mfma_f32_16x16x32_bf16(af, bf[nt], acc[mt][nt], 0, 0, 0);
    }
  }

  float bs4[4], g4[4], lb4[4];
  #pragma unroll
  for (int nt = 0; nt < 4; ++nt) {
    int col = colbase + nt * 16 + li;
    bs4[nt] = bskip[col]; g4[nt] = lng[col]; lb4[nt] = lnb[col];
  }
  #pragma unroll
  for (int mt = 0; mt < 4; ++mt) {
    #pragma unroll
    for (int r = 0; r < 4; ++r) {
      int node = n0 + mt * 16 + quad * 4 + r;
      int nodeL = min(node, NN - 1);
      #pragma unroll
      for (int nt = 0; nt < 4; ++nt) {
        int col = colbase + nt * 16 + li;
        acc[mt][nt][r] += bs4[nt] + bf2f(o1g[(size_t)nodeL * 256 + col]);
      }
    }
  }
  #pragma unroll
  for (int mt = 0; mt < 4; ++mt)
    #pragma unroll
    for (int r = 0; r < 4; ++r) {
      float s = acc[mt][0][r] + acc[mt][1][r] + acc[mt][2][r] + acc[mt][3][r];
      #pragma unroll
      for (int mk = 1; mk < 16; mk <<= 1) s += __shfl_xor(s, mk);
      if (li == 0) ps1[(mt * 16 + quad * 4 + r) * 4 + w] = s;
    }
  __syncthreads();
  float mu[4][4];
  #pragma unroll
  for (int mt = 0; mt < 4; ++mt)
    #pragma unroll
    for (int r = 0; r < 4; ++r) {
      float4 p = *(const float4*)(ps1 + (mt * 16 + quad * 4 + r) * 4);
      mu[mt][r] = (p.x + p.y + p.z + p.w) * (1.0f / 256.0f);
    }
  #pragma unroll
  for (int mt = 0; mt < 4; ++mt)
    #pragma unroll
    for (int r = 0; r < 4; ++r) {
      float m = mu[mt][r];
      float s = 0.f;
      #pragma unroll
      for (int nt = 0; nt < 4; ++nt) { float dd = acc[mt][nt][r] - m; s += dd * dd; }
      #pragma unroll
      for (int mk = 1; mk < 16; mk <<= 1) s += __shfl_xor(s, mk);
      if (li == 0) ps2[(mt * 16 + quad * 4 + r) * 4 + w] = s;
    }
  __syncthreads();
  #pragma unroll
  for (int mt = 0; mt < 4; ++mt)
    #pragma unroll
    for (int r = 0; r < 4; ++r) {
      float4 p = *(const float4*)(ps2 + (mt * 16 + quad * 4 + r) * 4);
      float rstd = rsqrtf((p.x + p.y + p.z + p.w) * (1.0f / 256.0f) + 1e-5f);
      int node = n0 + mt * 16 + quad * 4 + r;
      if (node < NN) {
        float m = mu[mt][r];
        #pragma unroll
        for (int nt = 0; nt < 4; ++nt) {
          int col = colbase + nt * 16 + li;
          postg[(size_t)node * 256 + col] =
              f2bf(fmaxf((acc[mt][nt][r] - m) * rstd * g4[nt] + lb4[nt], 0.f));
        }
      }
    }
}

// ---------------- head via MFMA: h1 = relu(post@w1+b1); out = log_softmax(h1@w2+b2) ----------------
// 64 nodes/block; A = post tile in LDS; B = Bt1[col][k] bf16 (L2-resident, 64 KB).
#define HAPAD 264   // u16 stride for A (K=256): 528 B/row
#define H1PAD 136   // u16 stride for h1 (128 cols): 272 B/row
__global__ __launch_bounds__(256) void k_head(
    const u16* __restrict__ postg, const u16* __restrict__ Bt1,
    const float* __restrict__ b1, const float* __restrict__ w2, const float* __restrict__ b2,
    float* __restrict__ outg) {
  __shared__ u16 As[64 * HAPAD];
  __shared__ u16 h1s[64 * H1PAD];
  const int t = threadIdx.x;
  const int w = t >> 6, l = t & 63;
  const int quad = l >> 4, li = l & 15;
  const int n0 = blockIdx.x * 64;

  // stage A = post [64 x 256] bf16 (zero-pad beyond NN)
  for (int q = t; q < 2048; q += 256) {
    int row = q >> 5, off = (q & 31) * 8;
    uint4 v = make_uint4(0, 0, 0, 0);
    if (n0 + row < NN) v = *(const uint4*)(postg + (size_t)(n0 + row) * 256 + off);
    *(uint4*)(As + row * HAPAD + off) = v;
  }
  __syncthreads();

  // layer 1: [64x256] @ [256x128] -> wave w covers cols [w*32, w*32+32)
  f32x4 acc[4][2];
  #pragma unroll
  for (int mt = 0; mt < 4; ++mt)
    #pragma unroll
    for (int nt = 0; nt < 2; ++nt) acc[mt][nt] = (f32x4){0.f, 0.f, 0.f, 0.f};
  const int colbase = w * 32;
  #pragma unroll
  for (int s = 0; s < 8; ++s) {
    bf16x8 bf[2];
    #pragma unroll
    for (int nt = 0; nt < 2; ++nt)
      bf[nt] = *(const bf16x8*)(Bt1 + (size_t)(colbase + nt * 16 + li) * 256 + s * 32 + quad * 8);
    #pragma unroll
    for (int mt = 0; mt < 4; ++mt) {
      bf16x8 af = *(const bf16x8*)(As + (mt * 16 + li) * HAPAD + s * 32 + quad * 8);
      #pragma unroll
      for (int nt = 0; nt < 2; ++nt)
        acc[mt][nt] = __builtin_amdgcn_mfma_f32_16x16x32_bf16(af, bf[nt], acc[mt][nt], 0, 0, 0);
    }
  }
  float b1c[2];
  #pragma unroll
  for (int nt = 0; nt < 2; ++nt) b1c[nt] = b1[colbase + nt * 16 + li];
  #pragma unroll
  for (int mt = 0; mt < 4; ++mt)
    #pragma unroll
    for (int nt = 0; nt < 2; ++nt)
      #pragma unroll
      for (int r = 0; r < 4; ++r)
        h1s[(mt * 16 + quad * 4 + r) * H1PAD + colbase + nt * 16 + li] =
            f2bf(fmaxf(acc[mt][nt][r] + b1c[nt], 0.f));
  __syncthreads();

  // layer 2 + log_softmax: thread t -> node t>>2, class t&3
  const int node = t >> 2, c = t & 3;
  float lg = b2[c];
  const u16* hrow = h1s + node * H1PAD;
  #pragma unroll 4
  for (int j = 0; j < 128; ++j) lg += bf2f(hrow[j]) * w2[j * 4 + c];
  // max over the 4 classes (lanes differ in low-2 bits)
  float mx = lg;
  #pragma unroll
  for (int mk = 1; mk < 4; mk <<= 1) mx = fmaxf(mx, __shfl_xor(mx, mk));
  float ex = __expf(lg - mx);
  float se = ex;
  #pragma unroll
  for (int mk = 1; mk < 4; mk <<= 1) se += __shfl_xor(se, mk);
  float res = lg - (mx + __logf(se));
  if (n0 + node < NN) outg[(size_t)(n0 + node) * 4 + c] = res;
}

extern "C" void kernel_launch(void* const* d_in, const int* in_sizes, int n_in,
                              void* d_out, int out_size, void* d_ws, size_t ws_size,
                              hipStream_t stream) {
  const float* x     = (const float*)d_in[0];
  const int*   ei    = (const int*)d_in[1];
  const float* ea    = (const float*)d_in[2];
  const float* w00   = (const float*)d_in[3];
  const float* b00   = (const float*)d_in[4];
  const float* we1   = (const float*)d_in[5];
  const float* be1   = (const float*)d_in[6];
  const float* we2   = (const float*)d_in[7];
  const float* be2   = (const float*)d_in[8];
  const float* we3   = (const float*)d_in[9];
  const float* be3   = (const float*)d_in[10];
  const float* wq    = (const float*)d_in[11];
  const float* bq    = (const float*)d_in[12];
  const float* wk    = (const float*)d_in[13];
  const float* bk    = (const float*)d_in[14];
  const float* wv    = (const float*)d_in[15];
  const float* bv    = (const float*)d_in[16];
  const float* wedge = (const float*)d_in[17];
  const float* bedge = (const float*)d_in[18];
  const float* wskip = (const float*)d_in[19];
  const float* bskip = (const float*)d_in[20];
  const float* lng   = (const float*)d_in[21];
  const float* lnb   = (const float*)d_in[22];
  const float* w1    = (const float*)d_in[23];
  const float* b1    = (const float*)d_in[24];
  const float* w2    = (const float*)d_in[25];
  const float* b2    = (const float*)d_in[26];
  float* outg = (float*)d_out;

  size_t off = 0;
  char* wsb = (char*)d_ws;
  auto carve = [&](size_t bytes) -> char* {
    char* r = wsb + off;
    off += (bytes + 255) & ~(size_t)255;
    return r;
  };
  u16* kvg    = (u16*)carve((size_t)NN * 512 * 2);  // k|v interleaved; reused as postg
  u16* qg     = (u16*)carve((size_t)NN * 256 * 2);  // q -> o1
  u16* Gg     = (u16*)carve((size_t)NN * 256 * 2);  // G -> zn
  u16* x1g    = (u16*)carve((size_t)NN * 64 * 2);
  u16* e3g    = (u16*)carve((size_t)NE * 64 * 2);
  int* deg    = (int*)carve((size_t)NN * 4);
  int* rowptr = (int*)carve((size_t)(NN + 1) * 4);
  int* cursor = (int*)carve((size_t)NN * 4);
  int* elist  = (int*)carve((size_t)NE * 4);
  int* slist  = (int*)carve((size_t)NE * 4);
  float* wT   = (float*)carve(16384 * 4);
  u16* wB1t   = (u16*)carve(512 * 2);
  u16* wB2t   = (u16*)carve(4096 * 2);
  u16* wB3t   = (u16*)carve(4096 * 2);
  u16* Bt     = (u16*)carve((size_t)256 * 320 * 2);
  u16* Bt1    = (u16*)carve((size_t)128 * 256 * 2);
  u16* postg  = kvg;
  if (off > ws_size) return;

  k_prep<<<64, 256, 0, stream>>>(wedge, wT);
  k_prep_w<<<34, 256, 0, stream>>>(we1, we2, we3, wB1t, wB2t, wB3t);
  k_prep_b<<<256, 320, 0, stream>>>(wedge, wskip, Bt);
  k_prep_h<<<128, 256, 0, stream>>>(w1, Bt1);
  k_zero<<<(NN + 255) / 256, 256, 0, stream>>>(deg);
  k_hist<<<NE / 256, 256, 0, stream>>>(ei, deg);
  k_scan<<<1, 1024, 0, stream>>>(deg, rowptr, cursor);
  k_scatter<<<NE / 256, 256, 0, stream>>>(ei, cursor, elist, slist);
  k_node<<<NN / 8, 256, 0, stream>>>(x, w00, b00, wq, bq, wk, bk, wv, bv, x1g, qg, kvg);
  k_gmat<<<NN / 8, 256, 0, stream>>>(qg, wT, Gg);
  k_edge_mlp<<<NE / EPB, 256, 0, stream>>>(ea, wB1t, wB2t, wB3t, be1, be2, be3, e3g);
  k_attn<<<NN / 4, 256, 0, stream>>>(rowptr, elist, slist, qg, kvg, Gg, e3g, bedge);
  k_post<<<(NN + PM - 1) / PM, 256, 0, stream>>>(qg, Gg, x1g, Bt, bskip, lng, lnb, postg);
  k_head<<<(NN + 63) / 64, 256, 0, stream>>>(postg, Bt1, b1, w2, b2, outg);
}

// Round 8
// 672.983 us; speedup vs baseline: 1.7700x; 1.0804x over previous
//
#include <hip/hip_runtime.h>
#include <hip/hip_bf16.h>

typedef unsigned short u16;
typedef __attribute__((ext_vector_type(8))) short bf16x8;
typedef __attribute__((ext_vector_type(4))) float f32x4;

#define NN 50000
#define NE 800000

__device__ __forceinline__ float bf2f(u16 u) { return __uint_as_float(((unsigned)u) << 16); }
__device__ __forceinline__ u16 f2bf(float f) {
  unsigned u = __float_as_uint(f);
  return (u16)((u + 0x7FFFu + ((u >> 16) & 1u)) >> 16);
}

// ---------------- CSR build ----------------
__global__ void k_zero(int* __restrict__ deg) {
  int i = blockIdx.x * 256 + threadIdx.x;
  if (i < NN) deg[i] = 0;
}

__global__ void k_hist(const int* __restrict__ ei, int* __restrict__ deg) {
  int i = blockIdx.x * 256 + threadIdx.x;
  if (i < NE) {
    int d = ei[NE + i];
    if (d >= 0 && d < NN) atomicAdd(&deg[d], 1);
  }
}

#define SCAN_T 1024
#define SCAN_CH 49
__global__ __launch_bounds__(1024) void k_scan(const int* __restrict__ deg,
                                               int* __restrict__ rowptr,
                                               int* __restrict__ cursor) {
  __shared__ int sums[SCAN_T];
  const int t = threadIdx.x;
  const int start = t * SCAN_CH;
  int lsum = 0;
  for (int i = 0; i < SCAN_CH; ++i) {
    int idx = start + i;
    if (idx < NN) lsum += deg[idx];
  }
  sums[t] = lsum;
  __syncthreads();
  for (int offs = 1; offs < SCAN_T; offs <<= 1) {
    int v = (t >= offs) ? sums[t - offs] : 0;
    __syncthreads();
    sums[t] += v;
    __syncthreads();
  }
  int run = (t == 0) ? 0 : sums[t - 1];
  for (int i = 0; i < SCAN_CH; ++i) {
    int idx = start + i;
    if (idx < NN) {
      rowptr[idx] = run;
      cursor[idx] = run;
      run += deg[idx];
    }
  }
  if (t == SCAN_T - 1) rowptr[NN] = run;
}

__global__ void k_scatter(const int* __restrict__ ei, int* __restrict__ cursor,
                          int* __restrict__ elist, int* __restrict__ slist) {
  int i = blockIdx.x * 256 + threadIdx.x;
  if (i < NE) {
    int d = ei[NE + i];
    if (d >= 0 && d < NN) {
      int pos = atomicAdd(&cursor[d], 1);
      if (pos >= 0 && pos < NE) {
        elist[pos] = i;
        int s = ei[i];
        slist[pos] = max(0, min(s, NN - 1));
      }
    }
  }
}

// ---------------- weight prep ----------------
// wT[h*64+c][j]  = wedge[j*256 + h*64+c]  (fp32, for k_gmat)
// wkT[h*64+c][j] = wk[j*256 + h*64+c]
__global__ void k_prep(const float* __restrict__ wedge, const float* __restrict__ wk,
                       float* __restrict__ wT, float* __restrict__ wkT) {
  int i = blockIdx.x * 256 + threadIdx.x;  // i = c*64 + j
  if (i < 16384) {
    int c = i >> 6, j = i & 63;
    wT[i] = wedge[j * 256 + c];
  } else if (i < 32768) {
    int i2 = i - 16384;
    int c = i2 >> 6, j = i2 & 63;
    wkT[i2] = wk[j * 256 + c];
  }
}

__global__ void k_prep_w(const float* __restrict__ we1, const float* __restrict__ we2,
                         const float* __restrict__ we3,
                         u16* __restrict__ wB1t, u16* __restrict__ wB2t, u16* __restrict__ wB3t) {
  int i = blockIdx.x * 256 + threadIdx.x;
  if (i < 512) {
    int n = i >> 3, k = i & 7;
    wB1t[i] = f2bf(we1[k * 64 + n]);
  } else if (i < 512 + 4096) {
    int i2 = i - 512;
    int n = i2 >> 6, k = i2 & 63;
    wB2t[i2] = f2bf(we2[k * 64 + n]);
  } else if (i < 512 + 8192) {
    int i2 = i - 512 - 4096;
    int n = i2 >> 6, k = i2 & 63;
    wB3t[i2] = f2bf(we3[k * 64 + n]);
  }
}

// Bt[col][k] bf16, K=576: [0,256) block-diag wedge | [256,512) block-diag wv | [512,576) wskip
__global__ void k_prep_b(const float* __restrict__ wedge, const float* __restrict__ wv,
                         const float* __restrict__ wskip, u16* __restrict__ Bt) {
  const int col = blockIdx.x;
  const int k = threadIdx.x;   // 576 threads
  float v;
  if (k < 256) v = ((k >> 6) == (col >> 6)) ? wedge[(k & 63) * 256 + col] : 0.f;
  else if (k < 512) { int k2 = k - 256; v = ((k2 >> 6) == (col >> 6)) ? wv[(k2 & 63) * 256 + col] : 0.f; }
  else v = wskip[(k - 512) * 256 + col];
  Bt[col * 576 + k] = f2bf(v);
}

// Bt1[col][k] (bf16): Bt1[col*256+k] = w1[k*128+col]
__global__ void k_prep_h(const float* __restrict__ w1, u16* __restrict__ Bt1) {
  const int col = blockIdx.x;
  const int k = threadIdx.x;
  Bt1[col * 256 + k] = f2bf(w1[k * 128 + col]);
}

// ---------------- node: x1 = relu(x@w00+b00), q projection only ----------------
__global__ __launch_bounds__(256) void k_node(
    const float* __restrict__ x, const float* __restrict__ w00, const float* __restrict__ b00,
    const float* __restrict__ wq, const float* __restrict__ bq,
    u16* __restrict__ x1g, u16* __restrict__ qg) {
  __shared__ float xs[128];
  __shared__ float x1s[8 * 65];
  const int t = threadIdx.x;
  const int n0 = blockIdx.x * 8;
  if (t < 128) xs[t] = x[n0 * 16 + t];
  __syncthreads();
  #pragma unroll
  for (int it = 0; it < 2; ++it) {
    int nb = it * 4 + (t >> 6);
    int col = t & 63;
    float v = b00[col];
    #pragma unroll
    for (int i = 0; i < 16; ++i) v += xs[nb * 16 + i] * w00[i * 64 + col];
    v = fmaxf(v, 0.f);
    x1s[nb * 65 + col] = v;
    x1g[(n0 + nb) * 64 + col] = f2bf(v);
  }
  __syncthreads();
  float aq[8];
  const float bqv = bq[t];
  #pragma unroll
  for (int nb = 0; nb < 8; ++nb) aq[nb] = bqv;
  for (int j = 0; j < 64; ++j) {
    float wqv = wq[j * 256 + t];
    #pragma unroll
    for (int nb = 0; nb < 8; ++nb) aq[nb] += x1s[nb * 65 + j] * wqv;
  }
  #pragma unroll
  for (int nb = 0; nb < 8; ++nb) qg[(n0 + nb) * 256 + t] = f2bf(aq[nb]);
}

// ---------------- G[n,h,j] = q·wedge-block, Qk[n,h,j] = q·wk-block ----------------
__global__ __launch_bounds__(256) void k_gmat(const u16* __restrict__ qg,
                                              const float* __restrict__ wT,
                                              const float* __restrict__ wkT,
                                              u16* __restrict__ Gg, u16* __restrict__ Qkg) {
  __shared__ float qs[8 * 256];
  const int t = threadIdx.x;
  const int n0 = blockIdx.x * 8;
  #pragma unroll
  for (int i = 0; i < 8; ++i) qs[i * 256 + t] = bf2f(qg[(n0 + i) * 256 + t]);
  __syncthreads();
  const int h = t >> 6, j = t & 63;
  float accG[8] = {0, 0, 0, 0, 0, 0, 0, 0};
  float accK[8] = {0, 0, 0, 0, 0, 0, 0, 0};
  for (int c = 0; c < 64; ++c) {
    float wv = wT[(h * 64 + c) * 64 + j];
    float wk = wkT[(h * 64 + c) * 64 + j];
    #pragma unroll
    for (int nb = 0; nb < 8; ++nb) {
      float qv = qs[nb * 256 + h * 64 + c];
      accG[nb] += qv * wv;
      accK[nb] += qv * wk;
    }
  }
  #pragma unroll
  for (int nb = 0; nb < 8; ++nb) {
    Gg[(n0 + nb) * 256 + t] = f2bf(accG[nb]);
    Qkg[(n0 + nb) * 256 + t] = f2bf(accK[nb]);
  }
}

// ---------------- edge MLP via MFMA bf16 ----------------
#define EPB 128
#define APAD 72
__global__ __launch_bounds__(256) void k_edge_mlp(
    const float* __restrict__ ea,
    const u16* __restrict__ wB1t, const u16* __restrict__ wB2t, const u16* __restrict__ wB3t,
    const float* __restrict__ be1, const float* __restrict__ be2, const float* __restrict__ be3,
    u16* __restrict__ e3g) {
  __shared__ u16 actA[EPB * APAD];
  __shared__ u16 actB[EPB * APAD];
  const int t = threadIdx.x;
  const int w = t >> 6, l = t & 63;
  const int quad = l >> 4, li = l & 15;
  const int e0 = blockIdx.x * EPB;
  const f32x4 zc = {0.f, 0.f, 0.f, 0.f};

  float b1c[4], b2c[4], b3c[4];
  #pragma unroll
  for (int nt = 0; nt < 4; ++nt) {
    b1c[nt] = be1[nt * 16 + li];
    b2c[nt] = be2[nt * 16 + li];
    b3c[nt] = be3[nt * 16 + li];
  }

  bf16x8 b1f[4];
  #pragma unroll
  for (int nt = 0; nt < 4; ++nt) {
    bf16x8 z = {};
    if (quad == 0) z = *(const bf16x8*)(wB1t + (nt * 16 + li) * 8);
    b1f[nt] = z;
  }
  #pragma unroll
  for (int mi = 0; mi < 2; ++mi) {
    const int mt = w * 2 + mi;
    bf16x8 af = {};
    if (quad == 0) {
      const float4* pa = (const float4*)(ea + (size_t)(e0 + mt * 16 + li) * 8);
      float4 p0 = pa[0], p1 = pa[1];
      af[0] = (short)f2bf(p0.x); af[1] = (short)f2bf(p0.y);
      af[2] = (short)f2bf(p0.z); af[3] = (short)f2bf(p0.w);
      af[4] = (short)f2bf(p1.x); af[5] = (short)f2bf(p1.y);
      af[6] = (short)f2bf(p1.z); af[7] = (short)f2bf(p1.w);
    }
    #pragma unroll
    for (int nt = 0; nt < 4; ++nt) {
      f32x4 d = __builtin_amdgcn_mfma_f32_16x16x32_bf16(af, b1f[nt], zc, 0, 0, 0);
      #pragma unroll
      for (int r = 0; r < 4; ++r)
        actA[(mt * 16 + quad * 4 + r) * APAD + nt * 16 + li] = f2bf(fmaxf(d[r] + b1c[nt], 0.f));
    }
  }
  __syncthreads();

  {
    bf16x8 bf[4][2];
    #pragma unroll
    for (int nt = 0; nt < 4; ++nt)
      #pragma unroll
      for (int kk = 0; kk < 2; ++kk)
        bf[nt][kk] = *(const bf16x8*)(wB2t + (nt * 16 + li) * 64 + kk * 32 + quad * 8);
    #pragma unroll
    for (int mi = 0; mi < 2; ++mi) {
      const int mt = w * 2 + mi;
      bf16x8 a0 = *(const bf16x8*)(actA + (mt * 16 + li) * APAD + quad * 8);
      bf16x8 a1 = *(const bf16x8*)(actA + (mt * 16 + li) * APAD + 32 + quad * 8);
      #pragma unroll
      for (int nt = 0; nt < 4; ++nt) {
        f32x4 d = __builtin_amdgcn_mfma_f32_16x16x32_bf16(a0, bf[nt][0], zc, 0, 0, 0);
        d = __builtin_amdgcn_mfma_f32_16x16x32_bf16(a1, bf[nt][1], d, 0, 0, 0);
        #pragma unroll
        for (int r = 0; r < 4; ++r)
          actB[(mt * 16 + quad * 4 + r) * APAD + nt * 16 + li] = f2bf(fmaxf(d[r] + b2c[nt], 0.f));
      }
    }
  }
  __syncthreads();

  {
    bf16x8 bf[4][2];
    #pragma unroll
    for (int nt = 0; nt < 4; ++nt)
      #pragma unroll
      for (int kk = 0; kk < 2; ++kk)
        bf[nt][kk] = *(const bf16x8*)(wB3t + (nt * 16 + li) * 64 + kk * 32 + quad * 8);
    #pragma unroll
    for (int mi = 0; mi < 2; ++mi) {
      const int mt = w * 2 + mi;
      bf16x8 a0 = *(const bf16x8*)(actB + (mt * 16 + li) * APAD + quad * 8);
      bf16x8 a1 = *(const bf16x8*)(actB + (mt * 16 + li) * APAD + 32 + quad * 8);
      #pragma unroll
      for (int nt = 0; nt < 4; ++nt) {
        f32x4 d = __builtin_amdgcn_mfma_f32_16x16x32_bf16(a0, bf[nt][0], zc, 0, 0, 0);
        d = __builtin_amdgcn_mfma_f32_16x16x32_bf16(a1, bf[nt][1], d, 0, 0, 0);
        #pragma unroll
        for (int r = 0; r < 4; ++r)
          actA[(mt * 16 + quad * 4 + r) * APAD + nt * 16 + li] = f2bf(fmaxf(d[r] + b3c[nt], 0.f));
      }
    }
  }
  __syncthreads();

  #pragma unroll
  for (int it = 0; it < 4; ++it) {
    int flat = it * 2048 + t * 8;
    int el = flat >> 6, c = flat & 63;
    uint4 v = *(const uint4*)(actA + el * APAD + c);
    *(uint4*)(e3g + (size_t)(e0 + el) * 64 + c) = v;
  }
}

// ---------------- attention gather: x1/e3 only (k,v eliminated algebraically) ----------------
// alpha = (Qk·x1[src] + G·e3[eid] + q·(bk+bedge)) / 8
// outputs: yn = (Σ p·x1[src])/s over qg,  zn = (Σ p·e3)/s over Gg,  bfac[n] = (deg>0)
__global__ __launch_bounds__(256) void k_attn(
    const int* __restrict__ rowptr, const int* __restrict__ elist, const int* __restrict__ slist,
    u16* qo, const u16* __restrict__ x1g, u16* gz, const u16* __restrict__ Qkg,
    const u16* __restrict__ e3g,
    const float* __restrict__ bk, const float* __restrict__ bedge,
    float* __restrict__ bfac) {
  const int t = threadIdx.x;
  const int w = t >> 6;
  const int l = t & 63;
  const int grp = l >> 4;
  const int li = l & 15;
  const int chb = grp * 64 + li * 4;
  const int n = blockIdx.x * 4 + w;
  int base = rowptr[n];
  int end  = rowptr[n + 1];
  base = max(0, min(base, NE));
  end  = max(base, min(end, NE));
  if (l == 0) bfac[n] = (end > base) ? 1.f : 0.f;

  float Qkf[4], Gf[4];
  {
    ushort4 kv = *(const ushort4*)(Qkg + (size_t)n * 256 + chb);
    Qkf[0] = bf2f(kv.x); Qkf[1] = bf2f(kv.y); Qkf[2] = bf2f(kv.z); Qkf[3] = bf2f(kv.w);
    ushort4 gv = *(const ushort4*)(gz + (size_t)n * 256 + chb);
    Gf[0] = bf2f(gv.x); Gf[1] = bf2f(gv.y); Gf[2] = bf2f(gv.z); Gf[3] = bf2f(gv.w);
  }
  float bqe;
  {
    ushort4 qv = *(const ushort4*)(qo + (size_t)n * 256 + chb);
    float4 bkv = *(const float4*)(bk + chb);
    float4 bev = *(const float4*)(bedge + chb);
    bqe = bf2f(qv.x) * (bkv.x + bev.x) + bf2f(qv.y) * (bkv.y + bev.y)
        + bf2f(qv.z) * (bkv.z + bev.z) + bf2f(qv.w) * (bkv.w + bev.w);
    #pragma unroll
    for (int mk = 1; mk < 16; mk <<= 1) bqe += __shfl_xor(bqe, mk);
  }

  float s_run = 0.f;
  float y[4] = {0, 0, 0, 0}, zz[4] = {0, 0, 0, 0};
  int d = base;
  for (; d + 1 < end; d += 2) {
    int eid0 = elist[d],     src0 = slist[d];
    int eid1 = elist[d + 1], src1 = slist[d + 1];
    eid0 = max(0, min(eid0, NE - 1)); eid1 = max(0, min(eid1, NE - 1));
    src0 = max(0, min(src0, NN - 1)); src1 = max(0, min(src1, NN - 1));
    ushort4 x0 = *(const ushort4*)(x1g + (size_t)src0 * 64 + li * 4);
    ushort4 e0 = *(const ushort4*)(e3g + (size_t)eid0 * 64 + li * 4);
    ushort4 x1v = *(const ushort4*)(x1g + (size_t)src1 * 64 + li * 4);
    ushort4 e1 = *(const ushort4*)(e3g + (size_t)eid1 * 64 + li * 4);
    float xf00 = bf2f(x0.x), xf01 = bf2f(x0.y), xf02 = bf2f(x0.z), xf03 = bf2f(x0.w);
    float ef00 = bf2f(e0.x), ef01 = bf2f(e0.y), ef02 = bf2f(e0.z), ef03 = bf2f(e0.w);
    float xf10 = bf2f(x1v.x), xf11 = bf2f(x1v.y), xf12 = bf2f(x1v.z), xf13 = bf2f(x1v.w);
    float ef10 = bf2f(e1.x), ef11 = bf2f(e1.y), ef12 = bf2f(e1.z), ef13 = bf2f(e1.w);
    float p0 = Qkf[0]*xf00 + Qkf[1]*xf01 + Qkf[2]*xf02 + Qkf[3]*xf03
             + Gf[0]*ef00 + Gf[1]*ef01 + Gf[2]*ef02 + Gf[3]*ef03;
    float p1 = Qkf[0]*xf10 + Qkf[1]*xf11 + Qkf[2]*xf12 + Qkf[3]*xf13
             + Gf[0]*ef10 + Gf[1]*ef11 + Gf[2]*ef12 + Gf[3]*ef13;
    #pragma unroll
    for (int mk = 1; mk < 16; mk <<= 1) { p0 += __shfl_xor(p0, mk); p1 += __shfl_xor(p1, mk); }
    float w0 = __expf(fminf((p0 + bqe) * 0.125f, 60.f));
    float w1 = __expf(fminf((p1 + bqe) * 0.125f, 60.f));
    s_run += w0 + w1;
    y[0] += w0*xf00 + w1*xf10; y[1] += w0*xf01 + w1*xf11;
    y[2] += w0*xf02 + w1*xf12; y[3] += w0*xf03 + w1*xf13;
    zz[0] += w0*ef00 + w1*ef10; zz[1] += w0*ef01 + w1*ef11;
    zz[2] += w0*ef02 + w1*ef12; zz[3] += w0*ef03 + w1*ef13;
  }
  if (d < end) {
    int eid0 = elist[d], src0 = slist[d];
    eid0 = max(0, min(eid0, NE - 1));
    src0 = max(0, min(src0, NN - 1));
    ushort4 x0 = *(const ushort4*)(x1g + (size_t)src0 * 64 + li * 4);
    ushort4 e0 = *(const ushort4*)(e3g + (size_t)eid0 * 64 + li * 4);
    float xf00 = bf2f(x0.x), xf01 = bf2f(x0.y), xf02 = bf2f(x0.z), xf03 = bf2f(x0.w);
    float ef00 = bf2f(e0.x), ef01 = bf2f(e0.y), ef02 = bf2f(e0.z), ef03 = bf2f(e0.w);
    float p0 = Qkf[0]*xf00 + Qkf[1]*xf01 + Qkf[2]*xf02 + Qkf[3]*xf03
             + Gf[0]*ef00 + Gf[1]*ef01 + Gf[2]*ef02 + Gf[3]*ef03;
    #pragma unroll
    for (int mk = 1; mk < 16; mk <<= 1) p0 += __shfl_xor(p0, mk);
    float w0 = __expf(fminf((p0 + bqe) * 0.125f, 60.f));
    s_run += w0;
    y[0] += w0*xf00; y[1] += w0*xf01; y[2] += w0*xf02; y[3] += w0*xf03;
    zz[0] += w0*ef00; zz[1] += w0*ef01; zz[2] += w0*ef02; zz[3] += w0*ef03;
  }
  const float inv_s = 1.0f / (s_run + 1e-16f);
  ushort4 ynv, znv;
  ynv.x = f2bf(y[0] * inv_s); ynv.y = f2bf(y[1] * inv_s);
  ynv.z = f2bf(y[2] * inv_s); ynv.w = f2bf(y[3] * inv_s);
  znv.x = f2bf(zz[0] * inv_s); znv.y = f2bf(zz[1] * inv_s);
  znv.z = f2bf(zz[2] * inv_s); znv.w = f2bf(zz[3] * inv_s);
  *(ushort4*)(qo + (size_t)n * 256 + chb) = ynv;
  *(ushort4*)(gz + (size_t)n * 256 + chb) = znv;
}

// ---------------- post via MFMA: out = [zn|yn|x1]@Bt^T + hasE*(bedge+bv) + bskip -> LN -> relu ----------------
#define PM 64
#define PK 576
#define PAPAD 584   // u16 stride (1168 B, 16B-aligned)
__global__ __launch_bounds__(256) void k_post(
    const u16* __restrict__ zng, const u16* __restrict__ yng, const u16* __restrict__ x1g,
    const u16* __restrict__ Bt, const float* __restrict__ bfac,
    const float* __restrict__ bedge, const float* __restrict__ bv, const float* __restrict__ bskip,
    const float* __restrict__ lng, const float* __restrict__ lnb,
    u16* __restrict__ postg) {
  __shared__ u16 As[PM * PAPAD];
  __shared__ float ps1[PM * 4];
  __shared__ float ps2[PM * 4];
  const int t = threadIdx.x;
  const int w = t >> 6, l = t & 63;
  const int quad = l >> 4, li = l & 15;
  const int n0 = blockIdx.x * PM;

  for (int q = t; q < 2048; q += 256) {
    int row = q >> 5, off = (q & 31) * 8;
    uint4 vz = make_uint4(0, 0, 0, 0), vy = make_uint4(0, 0, 0, 0);
    if (n0 + row < NN) {
      vz = *(const uint4*)(zng + (size_t)(n0 + row) * 256 + off);
      vy = *(const uint4*)(yng + (size_t)(n0 + row) * 256 + off);
    }
    *(uint4*)(As + row * PAPAD + off) = vz;
    *(uint4*)(As + row * PAPAD + 256 + off) = vy;
  }
  for (int q = t; q < 512; q += 256) {
    int row = q >> 3, off = (q & 7) * 8;
    uint4 v = make_uint4(0, 0, 0, 0);
    if (n0 + row < NN) v = *(const uint4*)(x1g + (size_t)(n0 + row) * 64 + off);
    *(uint4*)(As + row * PAPAD + 512 + off) = v;
  }
  __syncthreads();

  f32x4 acc[4][4];
  #pragma unroll
  for (int mt = 0; mt < 4; ++mt)
    #pragma unroll
    for (int nt = 0; nt < 4; ++nt) acc[mt][nt] = (f32x4){0.f, 0.f, 0.f, 0.f};

  const int colbase = w * 64;
  #pragma unroll
  for (int s = 0; s < 18; ++s) {
    bf16x8 bf[4];
    #pragma unroll
    for (int nt = 0; nt < 4; ++nt)
      bf[nt] = *(const bf16x8*)(Bt + (size_t)(colbase + nt * 16 + li) * PK + s * 32 + quad * 8);
    #pragma unroll
    for (int mt = 0; mt < 4; ++mt) {
      bf16x8 af = *(const bf16x8*)(As + (mt * 16 + li) * PAPAD + s * 32 + quad * 8);
      #pragma unroll
      for (int nt = 0; nt < 4; ++nt)
        acc[mt][nt] = __builtin_amdgcn_mfma_f32_16x16x32_bf16(af, bf[nt], acc[mt][nt], 0, 0, 0);
    }
  }

  float beb[4], bs4[4], g4[4], lb4[4];
  #pragma unroll
  for (int nt = 0; nt < 4; ++nt) {
    int col = colbase + nt * 16 + li;
    beb[nt] = bedge[col] + bv[col];
    bs4[nt] = bskip[col]; g4[nt] = lng[col]; lb4[nt] = lnb[col];
  }
  #pragma unroll
  for (int mt = 0; mt < 4; ++mt) {
    #pragma unroll
    for (int r = 0; r < 4; ++r) {
      int node = n0 + mt * 16 + quad * 4 + r;
      float hasE = bfac[min(node, NN - 1)];
      #pragma unroll
      for (int nt = 0; nt < 4; ++nt)
        acc[mt][nt][r] += hasE * beb[nt] + bs4[nt];
    }
  }
  #pragma unroll
  for (int mt = 0; mt < 4; ++mt)
    #pragma unroll
    for (int r = 0; r < 4; ++r) {
      float s = acc[mt][0][r] + acc[mt][1][r] + acc[mt][2][r] + acc[mt][3][r];
      #pragma unroll
      for (int mk = 1; mk < 16; mk <<= 1) s += __shfl_xor(s, mk);
      if (li == 0) ps1[(mt * 16 + quad * 4 + r) * 4 + w] = s;
    }
  __syncthreads();
  float mu[4][4];
  #pragma unroll
  for (int mt = 0; mt < 4; ++mt)
    #pragma unroll
    for (int r = 0; r < 4; ++r) {
      float4 p = *(const float4*)(ps1 + (mt * 16 + quad * 4 + r) * 4);
      mu[mt][r] = (p.x + p.y + p.z + p.w) * (1.0f / 256.0f);
    }
  #pragma unroll
  for (int mt = 0; mt < 4; ++mt)
    #pragma unroll
    for (int r = 0; r < 4; ++r) {
      float m = mu[mt][r];
      float s = 0.f;
      #pragma unroll
      for (int nt = 0; nt < 4; ++nt) { float dd = acc[mt][nt][r] - m; s += dd * dd; }
      #pragma unroll
      for (int mk = 1; mk < 16; mk <<= 1) s += __shfl_xor(s, mk);
      if (li == 0) ps2[(mt * 16 + quad * 4 + r) * 4 + w] = s;
    }
  __syncthreads();
  #pragma unroll
  for (int mt = 0; mt < 4; ++mt)
    #pragma unroll
    for (int r = 0; r < 4; ++r) {
      float4 p = *(const float4*)(ps2 + (mt * 16 + quad * 4 + r) * 4);
      float rstd = rsqrtf((p.x + p.y + p.z + p.w) * (1.0f / 256.0f) + 1e-5f);
      int node = n0 + mt * 16 + quad * 4 + r;
      if (node < NN) {
        float m = mu[mt][r];
        #pragma unroll
        for (int nt = 0; nt < 4; ++nt) {
          int col = colbase + nt * 16 + li;
          postg[(size_t)node * 256 + col] =
              f2bf(fmaxf((acc[mt][nt][r] - m) * rstd * g4[nt] + lb4[nt], 0.f));
        }
      }
    }
}

// ---------------- head via MFMA ----------------
#define HAPAD 264
#define H1PAD 136
__global__ __launch_bounds__(256) void k_head(
    const u16* __restrict__ postg, const u16* __restrict__ Bt1,
    const float* __restrict__ b1, const float* __restrict__ w2, const float* __restrict__ b2,
    float* __restrict__ outg) {
  __shared__ u16 As[64 * HAPAD];
  __shared__ u16 h1s[64 * H1PAD];
  const int t = threadIdx.x;
  const int w = t >> 6, l = t & 63;
  const int quad = l >> 4, li = l & 15;
  const int n0 = blockIdx.x * 64;

  for (int q = t; q < 2048; q += 256) {
    int row = q >> 5, off = (q & 31) * 8;
    uint4 v = make_uint4(0, 0, 0, 0);
    if (n0 + row < NN) v = *(const uint4*)(postg + (size_t)(n0 + row) * 256 + off);
    *(uint4*)(As + row * HAPAD + off) = v;
  }
  __syncthreads();

  f32x4 acc[4][2];
  #pragma unroll
  for (int mt = 0; mt < 4; ++mt)
    #pragma unroll
    for (int nt = 0; nt < 2; ++nt) acc[mt][nt] = (f32x4){0.f, 0.f, 0.f, 0.f};
  const int colbase = w * 32;
  #pragma unroll
  for (int s = 0; s < 8; ++s) {
    bf16x8 bf[2];
    #pragma unroll
    for (int nt = 0; nt < 2; ++nt)
      bf[nt] = *(const bf16x8*)(Bt1 + (size_t)(colbase + nt * 16 + li) * 256 + s * 32 + quad * 8);
    #pragma unroll
    for (int mt = 0; mt < 4; ++mt) {
      bf16x8 af = *(const bf16x8*)(As + (mt * 16 + li) * HAPAD + s * 32 + quad * 8);
      #pragma unroll
      for (int nt = 0; nt < 2; ++nt)
        acc[mt][nt] = __builtin_amdgcn_mfma_f32_16x16x32_bf16(af, bf[nt], acc[mt][nt], 0, 0, 0);
    }
  }
  float b1c[2];
  #pragma unroll
  for (int nt = 0; nt < 2; ++nt) b1c[nt] = b1[colbase + nt * 16 + li];
  #pragma unroll
  for (int mt = 0; mt < 4; ++mt)
    #pragma unroll
    for (int nt = 0; nt < 2; ++nt)
      #pragma unroll
      for (int r = 0; r < 4; ++r)
        h1s[(mt * 16 + quad * 4 + r) * H1PAD + colbase + nt * 16 + li] =
            f2bf(fmaxf(acc[mt][nt][r] + b1c[nt], 0.f));
  __syncthreads();

  const int node = t >> 2, c = t & 3;
  float lg = b2[c];
  const u16* hrow = h1s + node * H1PAD;
  #pragma unroll 4
  for (int j = 0; j < 128; ++j) lg += bf2f(hrow[j]) * w2[j * 4 + c];
  float mx = lg;
  #pragma unroll
  for (int mk = 1; mk < 4; mk <<= 1) mx = fmaxf(mx, __shfl_xor(mx, mk));
  float ex = __expf(lg - mx);
  float se = ex;
  #pragma unroll
  for (int mk = 1; mk < 4; mk <<= 1) se += __shfl_xor(se, mk);
  float res = lg - (mx + __logf(se));
  if (n0 + node < NN) outg[(size_t)(n0 + node) * 4 + c] = res;
}

extern "C" void kernel_launch(void* const* d_in, const int* in_sizes, int n_in,
                              void* d_out, int out_size, void* d_ws, size_t ws_size,
                              hipStream_t stream) {
  const float* x     = (const float*)d_in[0];
  const int*   ei    = (const int*)d_in[1];
  const float* ea    = (const float*)d_in[2];
  const float* w00   = (const float*)d_in[3];
  const float* b00   = (const float*)d_in[4];
  const float* we1   = (const float*)d_in[5];
  const float* be1   = (const float*)d_in[6];
  const float* we2   = (const float*)d_in[7];
  const float* be2   = (const float*)d_in[8];
  const float* we3   = (const float*)d_in[9];
  const float* be3   = (const float*)d_in[10];
  const float* wq    = (const float*)d_in[11];
  const float* bq    = (const float*)d_in[12];
  const float* wk    = (const float*)d_in[13];
  const float* bk    = (const float*)d_in[14];
  const float* wv    = (const float*)d_in[15];
  const float* bv    = (const float*)d_in[16];
  const float* wedge = (const float*)d_in[17];
  const float* bedge = (const float*)d_in[18];
  const float* wskip = (const float*)d_in[19];
  const float* bskip = (const float*)d_in[20];
  const float* lng   = (const float*)d_in[21];
  const float* lnb   = (const float*)d_in[22];
  const float* w1    = (const float*)d_in[23];
  const float* b1    = (const float*)d_in[24];
  const float* w2    = (const float*)d_in[25];
  const float* b2    = (const float*)d_in[26];
  float* outg = (float*)d_out;

  size_t off = 0;
  char* wsb = (char*)d_ws;
  auto carve = [&](size_t bytes) -> char* {
    char* r = wsb + off;
    off += (bytes + 255) & ~(size_t)255;
    return r;
  };
  u16* qg     = (u16*)carve((size_t)NN * 256 * 2);  // q -> yn
  u16* Gg     = (u16*)carve((size_t)NN * 256 * 2);  // G -> zn
  u16* Qkg    = (u16*)carve((size_t)NN * 256 * 2);  // Qk
  u16* x1g    = (u16*)carve((size_t)NN * 64 * 2);
  u16* e3g    = (u16*)carve((size_t)NE * 64 * 2);   // e3; front reused as postg after k_attn
  int* deg    = (int*)carve((size_t)NN * 4);
  int* rowptr = (int*)carve((size_t)(NN + 1) * 4);
  int* cursor = (int*)carve((size_t)NN * 4);
  int* elist  = (int*)carve((size_t)NE * 4);
  int* slist  = (int*)carve((size_t)NE * 4);
  float* bfac = (float*)carve((size_t)NN * 4);
  float* wT   = (float*)carve(16384 * 4);
  float* wkT  = (float*)carve(16384 * 4);
  u16* wB1t   = (u16*)carve(512 * 2);
  u16* wB2t   = (u16*)carve(4096 * 2);
  u16* wB3t   = (u16*)carve(4096 * 2);
  u16* Bt     = (u16*)carve((size_t)256 * 576 * 2);
  u16* Bt1    = (u16*)carve((size_t)128 * 256 * 2);
  u16* postg  = e3g;   // e3g dead after k_attn
  if (off > ws_size) return;

  k_prep<<<128, 256, 0, stream>>>(wedge, wk, wT, wkT);
  k_prep_w<<<34, 256, 0, stream>>>(we1, we2, we3, wB1t, wB2t, wB3t);
  k_prep_b<<<256, 576, 0, stream>>>(wedge, wv, wskip, Bt);
  k_prep_h<<<128, 256, 0, stream>>>(w1, Bt1);
  k_zero<<<(NN + 255) / 256, 256, 0, stream>>>(deg);
  k_hist<<<NE / 256, 256, 0, stream>>>(ei, deg);
  k_scan<<<1, 1024, 0, stream>>>(deg, rowptr, cursor);
  k_scatter<<<NE / 256, 256, 0, stream>>>(ei, cursor, elist, slist);
  k_node<<<NN / 8, 256, 0, stream>>>(x, w00, b00, wq, bq, x1g, qg);
  k_gmat<<<NN / 8, 256, 0, stream>>>(qg, wT, wkT, Gg, Qkg);
  k_edge_mlp<<<NE / EPB, 256, 0, stream>>>(ea, wB1t, wB2t, wB3t, be1, be2, be3, e3g);
  k_attn<<<NN / 4, 256, 0, stream>>>(rowptr, elist, slist, qg, x1g, Gg, Qkg, e3g, bk, bedge, bfac);
  k_post<<<(NN + PM - 1) / PM, 256, 0, stream>>>(Gg, qg, x1g, Bt, bfac, bedge, bv, bskip,
                                                 lng, lnb, postg);
  k_head<<<(NN + 63) / 64, 256, 0, stream>>>(postg, Bt1, b1, w2, b2, outg);
}

// Round 9
// 565.380 us; speedup vs baseline: 2.1069x; 1.1903x over previous
//
#include <hip/hip_runtime.h>
#include <hip/hip_bf16.h>

typedef unsigned short u16;
typedef __attribute__((ext_vector_type(8))) short bf16x8;
typedef __attribute__((ext_vector_type(4))) float f32x4;

#define NN 50000
#define NE 800000
#define SCAN_NB ((NN + 255) / 256)   // 196 chunk-blocks

__device__ __forceinline__ float bf2f(u16 u) { return __uint_as_float(((unsigned)u) << 16); }
__device__ __forceinline__ u16 f2bf(float f) {
  unsigned u = __float_as_uint(f);
  return (u16)((u + 0x7FFFu + ((u >> 16) & 1u)) >> 16);
}

// ---------------- CSR build ----------------
__global__ void k_zero(int* __restrict__ deg) {
  int i = blockIdx.x * 256 + threadIdx.x;
  if (i < NN) deg[i] = 0;
}

__global__ void k_hist(const int* __restrict__ ei, int* __restrict__ deg) {
  int i = blockIdx.x * 256 + threadIdx.x;
  if (i < NE) {
    int d = ei[NE + i];
    if (d >= 0 && d < NN) atomicAdd(&deg[d], 1);
  }
}

// phase A: per-chunk sums
__global__ __launch_bounds__(256) void k_scan_a(const int* __restrict__ deg,
                                                int* __restrict__ bsum) {
  __shared__ int red[256];
  const int t = threadIdx.x;
  const int i = blockIdx.x * 256 + t;
  red[t] = (i < NN) ? deg[i] : 0;
  __syncthreads();
  #pragma unroll
  for (int s = 128; s > 0; s >>= 1) {
    if (t < s) red[t] += red[t + s];
    __syncthreads();
  }
  if (t == 0) bsum[blockIdx.x] = red[0];
}

// phase B: exclusive scan of the block sums (1 block), writes rowptr[NN]=total
__global__ __launch_bounds__(256) void k_scan_b(const int* __restrict__ bsum,
                                                int* __restrict__ boff,
                                                int* __restrict__ rowptr) {
  __shared__ int s[256];
  const int t = threadIdx.x;
  int v = (t < SCAN_NB) ? bsum[t] : 0;
  s[t] = v;
  __syncthreads();
  #pragma unroll
  for (int o = 1; o < 256; o <<= 1) {
    int u = (t >= o) ? s[t - o] : 0;
    __syncthreads();
    s[t] += u;
    __syncthreads();
  }
  if (t < SCAN_NB) boff[t] = s[t] - v;   // exclusive
  if (t == 255) rowptr[NN] = s[255];
}

// phase C: in-chunk exclusive scan + block offset -> rowptr, cursor
__global__ __launch_bounds__(256) void k_scan_c(const int* __restrict__ deg,
                                                const int* __restrict__ boff,
                                                int* __restrict__ rowptr,
                                                int* __restrict__ cursor) {
  __shared__ int s[256];
  const int t = threadIdx.x;
  const int i = blockIdx.x * 256 + t;
  int v = (i < NN) ? deg[i] : 0;
  s[t] = v;
  __syncthreads();
  #pragma unroll
  for (int o = 1; o < 256; o <<= 1) {
    int u = (t >= o) ? s[t - o] : 0;
    __syncthreads();
    s[t] += u;
    __syncthreads();
  }
  if (i < NN) {
    int r = boff[blockIdx.x] + s[t] - v;   // exclusive
    rowptr[i] = r;
    cursor[i] = r;
  }
}

__global__ void k_scatter(const int* __restrict__ ei, int* __restrict__ cursor,
                          int* __restrict__ elist, int* __restrict__ slist) {
  int i = blockIdx.x * 256 + threadIdx.x;
  if (i < NE) {
    int d = ei[NE + i];
    if (d >= 0 && d < NN) {
      int pos = atomicAdd(&cursor[d], 1);
      if (pos >= 0 && pos < NE) {
        elist[pos] = i;
        int s = ei[i];
        slist[pos] = max(0, min(s, NN - 1));
      }
    }
  }
}

// ---------------- weight prep ----------------
__global__ void k_prep(const float* __restrict__ wedge, const float* __restrict__ wk,
                       float* __restrict__ wT, float* __restrict__ wkT) {
  int i = blockIdx.x * 256 + threadIdx.x;  // i = c*64 + j
  if (i < 16384) {
    int c = i >> 6, j = i & 63;
    wT[i] = wedge[j * 256 + c];
  } else if (i < 32768) {
    int i2 = i - 16384;
    int c = i2 >> 6, j = i2 & 63;
    wkT[i2] = wk[j * 256 + c];
  }
}

__global__ void k_prep_w(const float* __restrict__ we1, const float* __restrict__ we2,
                         const float* __restrict__ we3,
                         u16* __restrict__ wB1t, u16* __restrict__ wB2t, u16* __restrict__ wB3t) {
  int i = blockIdx.x * 256 + threadIdx.x;
  if (i < 512) {
    int n = i >> 3, k = i & 7;
    wB1t[i] = f2bf(we1[k * 64 + n]);
  } else if (i < 512 + 4096) {
    int i2 = i - 512;
    int n = i2 >> 6, k = i2 & 63;
    wB2t[i2] = f2bf(we2[k * 64 + n]);
  } else if (i < 512 + 8192) {
    int i2 = i - 512 - 4096;
    int n = i2 >> 6, k = i2 & 63;
    wB3t[i2] = f2bf(we3[k * 64 + n]);
  }
}

// Bt[col][k] bf16, K=576: [0,256) block-diag wedge | [256,512) block-diag wv | [512,576) wskip
__global__ void k_prep_b(const float* __restrict__ wedge, const float* __restrict__ wv,
                         const float* __restrict__ wskip, u16* __restrict__ Bt) {
  const int col = blockIdx.x;
  const int k = threadIdx.x;   // 576 threads
  float v;
  if (k < 256) v = ((k >> 6) == (col >> 6)) ? wedge[(k & 63) * 256 + col] : 0.f;
  else if (k < 512) { int k2 = k - 256; v = ((k2 >> 6) == (col >> 6)) ? wv[(k2 & 63) * 256 + col] : 0.f; }
  else v = wskip[(k - 512) * 256 + col];
  Bt[col * 576 + k] = f2bf(v);
}

__global__ void k_prep_h(const float* __restrict__ w1, u16* __restrict__ Bt1) {
  const int col = blockIdx.x;
  const int k = threadIdx.x;
  Bt1[col * 256 + k] = f2bf(w1[k * 128 + col]);
}

// ---------------- node: x1 = relu(x@w00+b00), q projection only ----------------
__global__ __launch_bounds__(256) void k_node(
    const float* __restrict__ x, const float* __restrict__ w00, const float* __restrict__ b00,
    const float* __restrict__ wq, const float* __restrict__ bq,
    u16* __restrict__ x1g, u16* __restrict__ qg) {
  __shared__ float xs[128];
  __shared__ float x1s[8 * 65];
  const int t = threadIdx.x;
  const int n0 = blockIdx.x * 8;
  if (t < 128) xs[t] = x[n0 * 16 + t];
  __syncthreads();
  #pragma unroll
  for (int it = 0; it < 2; ++it) {
    int nb = it * 4 + (t >> 6);
    int col = t & 63;
    float v = b00[col];
    #pragma unroll
    for (int i = 0; i < 16; ++i) v += xs[nb * 16 + i] * w00[i * 64 + col];
    v = fmaxf(v, 0.f);
    x1s[nb * 65 + col] = v;
    x1g[(n0 + nb) * 64 + col] = f2bf(v);
  }
  __syncthreads();
  float aq[8];
  const float bqv = bq[t];
  #pragma unroll
  for (int nb = 0; nb < 8; ++nb) aq[nb] = bqv;
  for (int j = 0; j < 64; ++j) {
    float wqv = wq[j * 256 + t];
    #pragma unroll
    for (int nb = 0; nb < 8; ++nb) aq[nb] += x1s[nb * 65 + j] * wqv;
  }
  #pragma unroll
  for (int nb = 0; nb < 8; ++nb) qg[(n0 + nb) * 256 + t] = f2bf(aq[nb]);
}

// ---------------- G[n,h,j] = q·wedge-block, Qk[n,h,j] = q·wk-block ----------------
__global__ __launch_bounds__(256) void k_gmat(const u16* __restrict__ qg,
                                              const float* __restrict__ wT,
                                              const float* __restrict__ wkT,
                                              u16* __restrict__ Gg, u16* __restrict__ Qkg) {
  __shared__ float qs[8 * 256];
  const int t = threadIdx.x;
  const int n0 = blockIdx.x * 8;
  #pragma unroll
  for (int i = 0; i < 8; ++i) qs[i * 256 + t] = bf2f(qg[(n0 + i) * 256 + t]);
  __syncthreads();
  const int h = t >> 6, j = t & 63;
  float accG[8] = {0, 0, 0, 0, 0, 0, 0, 0};
  float accK[8] = {0, 0, 0, 0, 0, 0, 0, 0};
  for (int c = 0; c < 64; ++c) {
    float wv = wT[(h * 64 + c) * 64 + j];
    float wk = wkT[(h * 64 + c) * 64 + j];
    #pragma unroll
    for (int nb = 0; nb < 8; ++nb) {
      float qv = qs[nb * 256 + h * 64 + c];
      accG[nb] += qv * wv;
      accK[nb] += qv * wk;
    }
  }
  #pragma unroll
  for (int nb = 0; nb < 8; ++nb) {
    Gg[(n0 + nb) * 256 + t] = f2bf(accG[nb]);
    Qkg[(n0 + nb) * 256 + t] = f2bf(accK[nb]);
  }
}

// ---------------- edge MLP via MFMA bf16 ----------------
#define EPB 128
#define APAD 72
__global__ __launch_bounds__(256) void k_edge_mlp(
    const float* __restrict__ ea,
    const u16* __restrict__ wB1t, const u16* __restrict__ wB2t, const u16* __restrict__ wB3t,
    const float* __restrict__ be1, const float* __restrict__ be2, const float* __restrict__ be3,
    u16* __restrict__ e3g) {
  __shared__ u16 actA[EPB * APAD];
  __shared__ u16 actB[EPB * APAD];
  const int t = threadIdx.x;
  const int w = t >> 6, l = t & 63;
  const int quad = l >> 4, li = l & 15;
  const int e0 = blockIdx.x * EPB;
  const f32x4 zc = {0.f, 0.f, 0.f, 0.f};

  float b1c[4], b2c[4], b3c[4];
  #pragma unroll
  for (int nt = 0; nt < 4; ++nt) {
    b1c[nt] = be1[nt * 16 + li];
    b2c[nt] = be2[nt * 16 + li];
    b3c[nt] = be3[nt * 16 + li];
  }

  bf16x8 b1f[4];
  #pragma unroll
  for (int nt = 0; nt < 4; ++nt) {
    bf16x8 z = {};
    if (quad == 0) z = *(const bf16x8*)(wB1t + (nt * 16 + li) * 8);
    b1f[nt] = z;
  }
  #pragma unroll
  for (int mi = 0; mi < 2; ++mi) {
    const int mt = w * 2 + mi;
    bf16x8 af = {};
    if (quad == 0) {
      const float4* pa = (const float4*)(ea + (size_t)(e0 + mt * 16 + li) * 8);
      float4 p0 = pa[0], p1 = pa[1];
      af[0] = (short)f2bf(p0.x); af[1] = (short)f2bf(p0.y);
      af[2] = (short)f2bf(p0.z); af[3] = (short)f2bf(p0.w);
      af[4] = (short)f2bf(p1.x); af[5] = (short)f2bf(p1.y);
      af[6] = (short)f2bf(p1.z); af[7] = (short)f2bf(p1.w);
    }
    #pragma unroll
    for (int nt = 0; nt < 4; ++nt) {
      f32x4 d = __builtin_amdgcn_mfma_f32_16x16x32_bf16(af, b1f[nt], zc, 0, 0, 0);
      #pragma unroll
      for (int r = 0; r < 4; ++r)
        actA[(mt * 16 + quad * 4 + r) * APAD + nt * 16 + li] = f2bf(fmaxf(d[r] + b1c[nt], 0.f));
    }
  }
  __syncthreads();

  {
    bf16x8 bf[4][2];
    #pragma unroll
    for (int nt = 0; nt < 4; ++nt)
      #pragma unroll
      for (int kk = 0; kk < 2; ++kk)
        bf[nt][kk] = *(const bf16x8*)(wB2t + (nt * 16 + li) * 64 + kk * 32 + quad * 8);
    #pragma unroll
    for (int mi = 0; mi < 2; ++mi) {
      const int mt = w * 2 + mi;
      bf16x8 a0 = *(const bf16x8*)(actA + (mt * 16 + li) * APAD + quad * 8);
      bf16x8 a1 = *(const bf16x8*)(actA + (mt * 16 + li) * APAD + 32 + quad * 8);
      #pragma unroll
      for (int nt = 0; nt < 4; ++nt) {
        f32x4 d = __builtin_amdgcn_mfma_f32_16x16x32_bf16(a0, bf[nt][0], zc, 0, 0, 0);
        d = __builtin_amdgcn_mfma_f32_16x16x32_bf16(a1, bf[nt][1], d, 0, 0, 0);
        #pragma unroll
        for (int r = 0; r < 4; ++r)
          actB[(mt * 16 + quad * 4 + r) * APAD + nt * 16 + li] = f2bf(fmaxf(d[r] + b2c[nt], 0.f));
      }
    }
  }
  __syncthreads();

  {
    bf16x8 bf[4][2];
    #pragma unroll
    for (int nt = 0; nt < 4; ++nt)
      #pragma unroll
      for (int kk = 0; kk < 2; ++kk)
        bf[nt][kk] = *(const bf16x8*)(wB3t + (nt * 16 + li) * 64 + kk * 32 + quad * 8);
    #pragma unroll
    for (int mi = 0; mi < 2; ++mi) {
      const int mt = w * 2 + mi;
      bf16x8 a0 = *(const bf16x8*)(actB + (mt * 16 + li) * APAD + quad * 8);
      bf16x8 a1 = *(const bf16x8*)(actB + (mt * 16 + li) * APAD + 32 + quad * 8);
      #pragma unroll
      for (int nt = 0; nt < 4; ++nt) {
        f32x4 d = __builtin_amdgcn_mfma_f32_16x16x32_bf16(a0, bf[nt][0], zc, 0, 0, 0);
        d = __builtin_amdgcn_mfma_f32_16x16x32_bf16(a1, bf[nt][1], d, 0, 0, 0);
        #pragma unroll
        for (int r = 0; r < 4; ++r)
          actA[(mt * 16 + quad * 4 + r) * APAD + nt * 16 + li] = f2bf(fmaxf(d[r] + b3c[nt], 0.f));
      }
    }
  }
  __syncthreads();

  #pragma unroll
  for (int it = 0; it < 4; ++it) {
    int flat = it * 2048 + t * 8;
    int el = flat >> 6, c = flat & 63;
    uint4 v = *(const uint4*)(actA + el * APAD + c);
    *(uint4*)(e3g + (size_t)(e0 + el) * 64 + c) = v;
  }
}

// ---------------- attention gather: x1/e3 only ----------------
__global__ __launch_bounds__(256) void k_attn(
    const int* __restrict__ rowptr, const int* __restrict__ elist, const int* __restrict__ slist,
    u16* qo, const u16* __restrict__ x1g, u16* gz, const u16* __restrict__ Qkg,
    const u16* __restrict__ e3g,
    const float* __restrict__ bk, const float* __restrict__ bedge,
    float* __restrict__ bfac) {
  const int t = threadIdx.x;
  const int w = t >> 6;
  const int l = t & 63;
  const int grp = l >> 4;
  const int li = l & 15;
  const int chb = grp * 64 + li * 4;
  const int n = blockIdx.x * 4 + w;
  int base = rowptr[n];
  int end  = rowptr[n + 1];
  base = max(0, min(base, NE));
  end  = max(base, min(end, NE));
  if (l == 0) bfac[n] = (end > base) ? 1.f : 0.f;

  float Qkf[4], Gf[4];
  {
    ushort4 kv = *(const ushort4*)(Qkg + (size_t)n * 256 + chb);
    Qkf[0] = bf2f(kv.x); Qkf[1] = bf2f(kv.y); Qkf[2] = bf2f(kv.z); Qkf[3] = bf2f(kv.w);
    ushort4 gv = *(const ushort4*)(gz + (size_t)n * 256 + chb);
    Gf[0] = bf2f(gv.x); Gf[1] = bf2f(gv.y); Gf[2] = bf2f(gv.z); Gf[3] = bf2f(gv.w);
  }
  float bqe;
  {
    ushort4 qv = *(const ushort4*)(qo + (size_t)n * 256 + chb);
    float4 bkv = *(const float4*)(bk + chb);
    float4 bev = *(const float4*)(bedge + chb);
    bqe = bf2f(qv.x) * (bkv.x + bev.x) + bf2f(qv.y) * (bkv.y + bev.y)
        + bf2f(qv.z) * (bkv.z + bev.z) + bf2f(qv.w) * (bkv.w + bev.w);
    #pragma unroll
    for (int mk = 1; mk < 16; mk <<= 1) bqe += __shfl_xor(bqe, mk);
  }

  float s_run = 0.f;
  float y[4] = {0, 0, 0, 0}, zz[4] = {0, 0, 0, 0};
  int d = base;
  for (; d + 1 < end; d += 2) {
    int eid0 = elist[d],     src0 = slist[d];
    int eid1 = elist[d + 1], src1 = slist[d + 1];
    eid0 = max(0, min(eid0, NE - 1)); eid1 = max(0, min(eid1, NE - 1));
    src0 = max(0, min(src0, NN - 1)); src1 = max(0, min(src1, NN - 1));
    ushort4 x0 = *(const ushort4*)(x1g + (size_t)src0 * 64 + li * 4);
    ushort4 e0 = *(const ushort4*)(e3g + (size_t)eid0 * 64 + li * 4);
    ushort4 x1v = *(const ushort4*)(x1g + (size_t)src1 * 64 + li * 4);
    ushort4 e1 = *(const ushort4*)(e3g + (size_t)eid1 * 64 + li * 4);
    float xf00 = bf2f(x0.x), xf01 = bf2f(x0.y), xf02 = bf2f(x0.z), xf03 = bf2f(x0.w);
    float ef00 = bf2f(e0.x), ef01 = bf2f(e0.y), ef02 = bf2f(e0.z), ef03 = bf2f(e0.w);
    float xf10 = bf2f(x1v.x), xf11 = bf2f(x1v.y), xf12 = bf2f(x1v.z), xf13 = bf2f(x1v.w);
    float ef10 = bf2f(e1.x), ef11 = bf2f(e1.y), ef12 = bf2f(e1.z), ef13 = bf2f(e1.w);
    float p0 = Qkf[0]*xf00 + Qkf[1]*xf01 + Qkf[2]*xf02 + Qkf[3]*xf03
             + Gf[0]*ef00 + Gf[1]*ef01 + Gf[2]*ef02 + Gf[3]*ef03;
    float p1 = Qkf[0]*xf10 + Qkf[1]*xf11 + Qkf[2]*xf12 + Qkf[3]*xf13
             + Gf[0]*ef10 + Gf[1]*ef11 + Gf[2]*ef12 + Gf[3]*ef13;
    #pragma unroll
    for (int mk = 1; mk < 16; mk <<= 1) { p0 += __shfl_xor(p0, mk); p1 += __shfl_xor(p1, mk); }
    float w0 = __expf(fminf((p0 + bqe) * 0.125f, 60.f));
    float w1 = __expf(fminf((p1 + bqe) * 0.125f, 60.f));
    s_run += w0 + w1;
    y[0] += w0*xf00 + w1*xf10; y[1] += w0*xf01 + w1*xf11;
    y[2] += w0*xf02 + w1*xf12; y[3] += w0*xf03 + w1*xf13;
    zz[0] += w0*ef00 + w1*ef10; zz[1] += w0*ef01 + w1*ef11;
    zz[2] += w0*ef02 + w1*ef12; zz[3] += w0*ef03 + w1*ef13;
  }
  if (d < end) {
    int eid0 = elist[d], src0 = slist[d];
    eid0 = max(0, min(eid0, NE - 1));
    src0 = max(0, min(src0, NN - 1));
    ushort4 x0 = *(const ushort4*)(x1g + (size_t)src0 * 64 + li * 4);
    ushort4 e0 = *(const ushort4*)(e3g + (size_t)eid0 * 64 + li * 4);
    float xf00 = bf2f(x0.x), xf01 = bf2f(x0.y), xf02 = bf2f(x0.z), xf03 = bf2f(x0.w);
    float ef00 = bf2f(e0.x), ef01 = bf2f(e0.y), ef02 = bf2f(e0.z), ef03 = bf2f(e0.w);
    float p0 = Qkf[0]*xf00 + Qkf[1]*xf01 + Qkf[2]*xf02 + Qkf[3]*xf03
             + Gf[0]*ef00 + Gf[1]*ef01 + Gf[2]*ef02 + Gf[3]*ef03;
    #pragma unroll
    for (int mk = 1; mk < 16; mk <<= 1) p0 += __shfl_xor(p0, mk);
    float w0 = __expf(fminf((p0 + bqe) * 0.125f, 60.f));
    s_run += w0;
    y[0] += w0*xf00; y[1] += w0*xf01; y[2] += w0*xf02; y[3] += w0*xf03;
    zz[0] += w0*ef00; zz[1] += w0*ef01; zz[2] += w0*ef02; zz[3] += w0*ef03;
  }
  const float inv_s = 1.0f / (s_run + 1e-16f);
  ushort4 ynv, znv;
  ynv.x = f2bf(y[0] * inv_s); ynv.y = f2bf(y[1] * inv_s);
  ynv.z = f2bf(y[2] * inv_s); ynv.w = f2bf(y[3] * inv_s);
  znv.x = f2bf(zz[0] * inv_s); znv.y = f2bf(zz[1] * inv_s);
  znv.z = f2bf(zz[2] * inv_s); znv.w = f2bf(zz[3] * inv_s);
  *(ushort4*)(qo + (size_t)n * 256 + chb) = ynv;
  *(ushort4*)(gz + (size_t)n * 256 + chb) = znv;
}

// ---------------- post via MFMA: out = [zn|yn|x1]@Bt^T + hasE*(bedge+bv) + bskip -> LN -> relu ----------------
#define PM 64
#define PK 576
#define PAPAD 584
__global__ __launch_bounds__(256) void k_post(
    const u16* __restrict__ zng, const u16* __restrict__ yng, const u16* __restrict__ x1g,
    const u16* __restrict__ Bt, const float* __restrict__ bfac,
    const float* __restrict__ bedge, const float* __restrict__ bv, const float* __restrict__ bskip,
    const float* __restrict__ lng, const float* __restrict__ lnb,
    u16* __restrict__ postg) {
  __shared__ u16 As[PM * PAPAD];
  __shared__ float ps1[PM * 4];
  __shared__ float ps2[PM * 4];
  const int t = threadIdx.x;
  const int w = t >> 6, l = t & 63;
  const int quad = l >> 4, li = l & 15;
  const int n0 = blockIdx.x * PM;

  for (int q = t; q < 2048; q += 256) {
    int row = q >> 5, off = (q & 31) * 8;
    uint4 vz = make_uint4(0, 0, 0, 0), vy = make_uint4(0, 0, 0, 0);
    if (n0 + row < NN) {
      vz = *(const uint4*)(zng + (size_t)(n0 + row) * 256 + off);
      vy = *(const uint4*)(yng + (size_t)(n0 + row) * 256 + off);
    }
    *(uint4*)(As + row * PAPAD + off) = vz;
    *(uint4*)(As + row * PAPAD + 256 + off) = vy;
  }
  for (int q = t; q < 512; q += 256) {
    int row = q >> 3, off = (q & 7) * 8;
    uint4 v = make_uint4(0, 0, 0, 0);
    if (n0 + row < NN) v = *(const uint4*)(x1g + (size_t)(n0 + row) * 64 + off);
    *(uint4*)(As + row * PAPAD + 512 + off) = v;
  }
  __syncthreads();

  f32x4 acc[4][4];
  #pragma unroll
  for (int mt = 0; mt < 4; ++mt)
    #pragma unroll
    for (int nt = 0; nt < 4; ++nt) acc[mt][nt] = (f32x4){0.f, 0.f, 0.f, 0.f};

  const int colbase = w * 64;
  #pragma unroll
  for (int s = 0; s < 18; ++s) {
    bf16x8 bf[4];
    #pragma unroll
    for (int nt = 0; nt < 4; ++nt)
      bf[nt] = *(const bf16x8*)(Bt + (size_t)(colbase + nt * 16 + li) * PK + s * 32 + quad * 8);
    #pragma unroll
    for (int mt = 0; mt < 4; ++mt) {
      bf16x8 af = *(const bf16x8*)(As + (mt * 16 + li) * PAPAD + s * 32 + quad * 8);
      #pragma unroll
      for (int nt = 0; nt < 4; ++nt)
        acc[mt][nt] = __builtin_amdgcn_mfma_f32_16x16x32_bf16(af, bf[nt], acc[mt][nt], 0, 0, 0);
    }
  }

  float beb[4], bs4[4], g4[4], lb4[4];
  #pragma unroll
  for (int nt = 0; nt < 4; ++nt) {
    int col = colbase + nt * 16 + li;
    beb[nt] = bedge[col] + bv[col];
    bs4[nt] = bskip[col]; g4[nt] = lng[col]; lb4[nt] = lnb[col];
  }
  #pragma unroll
  for (int mt = 0; mt < 4; ++mt) {
    #pragma unroll
    for (int r = 0; r < 4; ++r) {
      int node = n0 + mt * 16 + quad * 4 + r;
      float hasE = bfac[min(node, NN - 1)];
      #pragma unroll
      for (int nt = 0; nt < 4; ++nt)
        acc[mt][nt][r] += hasE * beb[nt] + bs4[nt];
    }
  }
  #pragma unroll
  for (int mt = 0; mt < 4; ++mt)
    #pragma unroll
    for (int r = 0; r < 4; ++r) {
      float s = acc[mt][0][r] + acc[mt][1][r] + acc[mt][2][r] + acc[mt][3][r];
      #pragma unroll
      for (int mk = 1; mk < 16; mk <<= 1) s += __shfl_xor(s, mk);
      if (li == 0) ps1[(mt * 16 + quad * 4 + r) * 4 + w] = s;
    }
  __syncthreads();
  float mu[4][4];
  #pragma unroll
  for (int mt = 0; mt < 4; ++mt)
    #pragma unroll
    for (int r = 0; r < 4; ++r) {
      float4 p = *(const float4*)(ps1 + (mt * 16 + quad * 4 + r) * 4);
      mu[mt][r] = (p.x + p.y + p.z + p.w) * (1.0f / 256.0f);
    }
  #pragma unroll
  for (int mt = 0; mt < 4; ++mt)
    #pragma unroll
    for (int r = 0; r < 4; ++r) {
      float m = mu[mt][r];
      float s = 0.f;
      #pragma unroll
      for (int nt = 0; nt < 4; ++nt) { float dd = acc[mt][nt][r] - m; s += dd * dd; }
      #pragma unroll
      for (int mk = 1; mk < 16; mk <<= 1) s += __shfl_xor(s, mk);
      if (li == 0) ps2[(mt * 16 + quad * 4 + r) * 4 + w] = s;
    }
  __syncthreads();
  #pragma unroll
  for (int mt = 0; mt < 4; ++mt)
    #pragma unroll
    for (int r = 0; r < 4; ++r) {
      float4 p = *(const float4*)(ps2 + (mt * 16 + quad * 4 + r) * 4);
      float rstd = rsqrtf((p.x + p.y + p.z + p.w) * (1.0f / 256.0f) + 1e-5f);
      int node = n0 + mt * 16 + quad * 4 + r;
      if (node < NN) {
        float m = mu[mt][r];
        #pragma unroll
        for (int nt = 0; nt < 4; ++nt) {
          int col = colbase + nt * 16 + li;
          postg[(size_t)node * 256 + col] =
              f2bf(fmaxf((acc[mt][nt][r] - m) * rstd * g4[nt] + lb4[nt], 0.f));
        }
      }
    }
}

// ---------------- head via MFMA ----------------
#define HAPAD 264
#define H1PAD 136
__global__ __launch_bounds__(256) void k_head(
    const u16* __restrict__ postg, const u16* __restrict__ Bt1,
    const float* __restrict__ b1, const float* __restrict__ w2, const float* __restrict__ b2,
    float* __restrict__ outg) {
  __shared__ u16 As[64 * HAPAD];
  __shared__ u16 h1s[64 * H1PAD];
  const int t = threadIdx.x;
  const int w = t >> 6, l = t & 63;
  const int quad = l >> 4, li = l & 15;
  const int n0 = blockIdx.x * 64;

  for (int q = t; q < 2048; q += 256) {
    int row = q >> 5, off = (q & 31) * 8;
    uint4 v = make_uint4(0, 0, 0, 0);
    if (n0 + row < NN) v = *(const uint4*)(postg + (size_t)(n0 + row) * 256 + off);
    *(uint4*)(As + row * HAPAD + off) = v;
  }
  __syncthreads();

  f32x4 acc[4][2];
  #pragma unroll
  for (int mt = 0; mt < 4; ++mt)
    #pragma unroll
    for (int nt = 0; nt < 2; ++nt) acc[mt][nt] = (f32x4){0.f, 0.f, 0.f, 0.f};
  const int colbase = w * 32;
  #pragma unroll
  for (int s = 0; s < 8; ++s) {
    bf16x8 bf[2];
    #pragma unroll
    for (int nt = 0; nt < 2; ++nt)
      bf[nt] = *(const bf16x8*)(Bt1 + (size_t)(colbase + nt * 16 + li) * 256 + s * 32 + quad * 8);
    #pragma unroll
    for (int mt = 0; mt < 4; ++mt) {
      bf16x8 af = *(const bf16x8*)(As + (mt * 16 + li) * HAPAD + s * 32 + quad * 8);
      #pragma unroll
      for (int nt = 0; nt < 2; ++nt)
        acc[mt][nt] = __builtin_amdgcn_mfma_f32_16x16x32_bf16(af, bf[nt], acc[mt][nt], 0, 0, 0);
    }
  }
  float b1c[2];
  #pragma unroll
  for (int nt = 0; nt < 2; ++nt) b1c[nt] = b1[colbase + nt * 16 + li];
  #pragma unroll
  for (int mt = 0; mt < 4; ++mt)
    #pragma unroll
    for (int nt = 0; nt < 2; ++nt)
      #pragma unroll
      for (int r = 0; r < 4; ++r)
        h1s[(mt * 16 + quad * 4 + r) * H1PAD + colbase + nt * 16 + li] =
            f2bf(fmaxf(acc[mt][nt][r] + b1c[nt], 0.f));
  __syncthreads();

  const int node = t >> 2, c = t & 3;
  float lg = b2[c];
  const u16* hrow = h1s + node * H1PAD;
  #pragma unroll 4
  for (int j = 0; j < 128; ++j) lg += bf2f(hrow[j]) * w2[j * 4 + c];
  float mx = lg;
  #pragma unroll
  for (int mk = 1; mk < 4; mk <<= 1) mx = fmaxf(mx, __shfl_xor(mx, mk));
  float ex = __expf(lg - mx);
  float se = ex;
  #pragma unroll
  for (int mk = 1; mk < 4; mk <<= 1) se += __shfl_xor(se, mk);
  float res = lg - (mx + __logf(se));
  if (n0 + node < NN) outg[(size_t)(n0 + node) * 4 + c] = res;
}

extern "C" void kernel_launch(void* const* d_in, const int* in_sizes, int n_in,
                              void* d_out, int out_size, void* d_ws, size_t ws_size,
                              hipStream_t stream) {
  const float* x     = (const float*)d_in[0];
  const int*   ei    = (const int*)d_in[1];
  const float* ea    = (const float*)d_in[2];
  const float* w00   = (const float*)d_in[3];
  const float* b00   = (const float*)d_in[4];
  const float* we1   = (const float*)d_in[5];
  const float* be1   = (const float*)d_in[6];
  const float* we2   = (const float*)d_in[7];
  const float* be2   = (const float*)d_in[8];
  const float* we3   = (const float*)d_in[9];
  const float* be3   = (const float*)d_in[10];
  const float* wq    = (const float*)d_in[11];
  const float* bq    = (const float*)d_in[12];
  const float* wk    = (const float*)d_in[13];
  const float* bk    = (const float*)d_in[14];
  const float* wv    = (const float*)d_in[15];
  const float* bv    = (const float*)d_in[16];
  const float* wedge = (const float*)d_in[17];
  const float* bedge = (const float*)d_in[18];
  const float* wskip = (const float*)d_in[19];
  const float* bskip = (const float*)d_in[20];
  const float* lng   = (const float*)d_in[21];
  const float* lnb   = (const float*)d_in[22];
  const float* w1    = (const float*)d_in[23];
  const float* b1    = (const float*)d_in[24];
  const float* w2    = (const float*)d_in[25];
  const float* b2    = (const float*)d_in[26];
  float* outg = (float*)d_out;

  size_t off = 0;
  char* wsb = (char*)d_ws;
  auto carve = [&](size_t bytes) -> char* {
    char* r = wsb + off;
    off += (bytes + 255) & ~(size_t)255;
    return r;
  };
  u16* qg     = (u16*)carve((size_t)NN * 256 * 2);  // q -> yn
  u16* Gg     = (u16*)carve((size_t)NN * 256 * 2);  // G -> zn
  u16* Qkg    = (u16*)carve((size_t)NN * 256 * 2);  // Qk
  u16* x1g    = (u16*)carve((size_t)NN * 64 * 2);
  u16* e3g    = (u16*)carve((size_t)NE * 64 * 2);   // e3; front reused as postg after k_attn
  int* deg    = (int*)carve((size_t)NN * 4);
  int* rowptr = (int*)carve((size_t)(NN + 1) * 4);
  int* cursor = (int*)carve((size_t)NN * 4);
  int* elist  = (int*)carve((size_t)NE * 4);
  int* slist  = (int*)carve((size_t)NE * 4);
  float* bfac = (float*)carve((size_t)NN * 4);
  int* bsum   = (int*)carve((size_t)SCAN_NB * 4);
  int* boff   = (int*)carve((size_t)SCAN_NB * 4);
  float* wT   = (float*)carve(16384 * 4);
  float* wkT  = (float*)carve(16384 * 4);
  u16* wB1t   = (u16*)carve(512 * 2);
  u16* wB2t   = (u16*)carve(4096 * 2);
  u16* wB3t   = (u16*)carve(4096 * 2);
  u16* Bt     = (u16*)carve((size_t)256 * 576 * 2);
  u16* Bt1    = (u16*)carve((size_t)128 * 256 * 2);
  u16* postg  = e3g;   // e3g dead after k_attn
  if (off > ws_size) return;

  k_prep<<<128, 256, 0, stream>>>(wedge, wk, wT, wkT);
  k_prep_w<<<34, 256, 0, stream>>>(we1, we2, we3, wB1t, wB2t, wB3t);
  k_prep_b<<<256, 576, 0, stream>>>(wedge, wv, wskip, Bt);
  k_prep_h<<<128, 256, 0, stream>>>(w1, Bt1);
  k_zero<<<SCAN_NB, 256, 0, stream>>>(deg);
  k_hist<<<NE / 256, 256, 0, stream>>>(ei, deg);
  k_scan_a<<<SCAN_NB, 256, 0, stream>>>(deg, bsum);
  k_scan_b<<<1, 256, 0, stream>>>(bsum, boff, rowptr);
  k_scan_c<<<SCAN_NB, 256, 0, stream>>>(deg, boff, rowptr, cursor);
  k_scatter<<<NE / 256, 256, 0, stream>>>(ei, cursor, elist, slist);
  k_node<<<NN / 8, 256, 0, stream>>>(x, w00, b00, wq, bq, x1g, qg);
  k_gmat<<<NN / 8, 256, 0, stream>>>(qg, wT, wkT, Gg, Qkg);
  k_edge_mlp<<<NE / EPB, 256, 0, stream>>>(ea, wB1t, wB2t, wB3t, be1, be2, be3, e3g);
  k_attn<<<NN / 4, 256, 0, stream>>>(rowptr, elist, slist, qg, x1g, Gg, Qkg, e3g, bk, bedge, bfac);
  k_post<<<(NN + PM - 1) / PM, 256, 0, stream>>>(Gg, qg, x1g, Bt, bfac, bedge, bv, bskip,
                                                 lng, lnb, postg);
  k_head<<<(NN + 63) / 64, 256, 0, stream>>>(postg, Bt1, b1, w2, b2, outg);
}

// Round 10
// 550.846 us; speedup vs baseline: 2.1624x; 1.0264x over previous
//
#include <hip/hip_runtime.h>
#include <hip/hip_bf16.h>

typedef unsigned short u16;
typedef __attribute__((ext_vector_type(8))) short bf16x8;
typedef __attribute__((ext_vector_type(4))) float f32x4;

#define NN 50000
#define NE 800000
#define SCAN_NB ((NN + 255) / 256)

__device__ __forceinline__ float bf2f(u16 u) { return __uint_as_float(((unsigned)u) << 16); }
__device__ __forceinline__ u16 f2bf(float f) {
  unsigned u = __float_as_uint(f);
  return (u16)((u + 0x7FFFu + ((u >> 16) & 1u)) >> 16);
}

// ---------------- CSR build ----------------
__global__ void k_zero(int* __restrict__ deg) {
  int i = blockIdx.x * 256 + threadIdx.x;
  if (i < NN) deg[i] = 0;
}

__global__ void k_hist(const int* __restrict__ ei, int* __restrict__ deg) {
  int i = blockIdx.x * 256 + threadIdx.x;
  if (i < NE) {
    int d = ei[NE + i];
    if (d >= 0 && d < NN) atomicAdd(&deg[d], 1);
  }
}

__global__ __launch_bounds__(256) void k_scan_a(const int* __restrict__ deg,
                                                int* __restrict__ bsum) {
  __shared__ int red[256];
  const int t = threadIdx.x;
  const int i = blockIdx.x * 256 + t;
  red[t] = (i < NN) ? deg[i] : 0;
  __syncthreads();
  #pragma unroll
  for (int s = 128; s > 0; s >>= 1) {
    if (t < s) red[t] += red[t + s];
    __syncthreads();
  }
  if (t == 0) bsum[blockIdx.x] = red[0];
}

__global__ __launch_bounds__(256) void k_scan_b(const int* __restrict__ bsum,
                                                int* __restrict__ boff,
                                                int* __restrict__ rowptr) {
  __shared__ int s[256];
  const int t = threadIdx.x;
  int v = (t < SCAN_NB) ? bsum[t] : 0;
  s[t] = v;
  __syncthreads();
  #pragma unroll
  for (int o = 1; o < 256; o <<= 1) {
    int u = (t >= o) ? s[t - o] : 0;
    __syncthreads();
    s[t] += u;
    __syncthreads();
  }
  if (t < SCAN_NB) boff[t] = s[t] - v;
  if (t == 255) rowptr[NN] = s[255];
}

__global__ __launch_bounds__(256) void k_scan_c(const int* __restrict__ deg,
                                                const int* __restrict__ boff,
                                                int* __restrict__ rowptr,
                                                int* __restrict__ cursor) {
  __shared__ int s[256];
  const int t = threadIdx.x;
  const int i = blockIdx.x * 256 + t;
  int v = (i < NN) ? deg[i] : 0;
  s[t] = v;
  __syncthreads();
  #pragma unroll
  for (int o = 1; o < 256; o <<= 1) {
    int u = (t >= o) ? s[t - o] : 0;
    __syncthreads();
    s[t] += u;
    __syncthreads();
  }
  if (i < NN) {
    int r = boff[blockIdx.x] + s[t] - v;
    rowptr[i] = r;
    cursor[i] = r;
  }
}

// emits slist[pos]=src and e2p[eid]=pos (CSR position of each edge)
__global__ void k_scatter(const int* __restrict__ ei, int* __restrict__ cursor,
                          int* __restrict__ slist, int* __restrict__ e2p) {
  int i = blockIdx.x * 256 + threadIdx.x;
  if (i < NE) {
    int d = ei[NE + i];
    if (d >= 0 && d < NN) {
      int pos = atomicAdd(&cursor[d], 1);
      if (pos >= 0 && pos < NE) {
        e2p[i] = pos;
        int s = ei[i];
        slist[pos] = max(0, min(s, NN - 1));
      }
    }
  }
}

// ---------------- weight prep ----------------
__global__ void k_prep(const float* __restrict__ wedge, const float* __restrict__ wk,
                       float* __restrict__ wT, float* __restrict__ wkT) {
  int i = blockIdx.x * 256 + threadIdx.x;  // i = c*64 + j
  if (i < 16384) {
    int c = i >> 6, j = i & 63;
    wT[i] = wedge[j * 256 + c];
  } else if (i < 32768) {
    int i2 = i - 16384;
    int c = i2 >> 6, j = i2 & 63;
    wkT[i2] = wk[j * 256 + c];
  }
}

__global__ void k_prep_w(const float* __restrict__ we1, const float* __restrict__ we2,
                         const float* __restrict__ we3,
                         u16* __restrict__ wB1t, u16* __restrict__ wB2t, u16* __restrict__ wB3t) {
  int i = blockIdx.x * 256 + threadIdx.x;
  if (i < 512) {
    int n = i >> 3, k = i & 7;
    wB1t[i] = f2bf(we1[k * 64 + n]);
  } else if (i < 512 + 4096) {
    int i2 = i - 512;
    int n = i2 >> 6, k = i2 & 63;
    wB2t[i2] = f2bf(we2[k * 64 + n]);
  } else if (i < 512 + 8192) {
    int i2 = i - 512 - 4096;
    int n = i2 >> 6, k = i2 & 63;
    wB3t[i2] = f2bf(we3[k * 64 + n]);
  }
}

// Bt[col][k] bf16, K=576: [0,256) blk-diag wedge | [256,512) blk-diag wv | [512,576) wskip
__global__ void k_prep_b(const float* __restrict__ wedge, const float* __restrict__ wv,
                         const float* __restrict__ wskip, u16* __restrict__ Bt) {
  const int col = blockIdx.x;
  const int k = threadIdx.x;
  float v;
  if (k < 256) v = ((k >> 6) == (col >> 6)) ? wedge[(k & 63) * 256 + col] : 0.f;
  else if (k < 512) { int k2 = k - 256; v = ((k2 >> 6) == (col >> 6)) ? wv[(k2 & 63) * 256 + col] : 0.f; }
  else v = wskip[(k - 512) * 256 + col];
  Bt[col * 576 + k] = f2bf(v);
}

__global__ void k_prep_h(const float* __restrict__ w1, u16* __restrict__ Bt1) {
  const int col = blockIdx.x;
  const int k = threadIdx.x;
  Bt1[col * 256 + k] = f2bf(w1[k * 128 + col]);
}

// ---------------- merged node: x1 -> q (LDS only) -> G, Qk ----------------
__global__ __launch_bounds__(256) void k_ng(
    const float* __restrict__ x, const float* __restrict__ w00, const float* __restrict__ b00,
    const float* __restrict__ wq, const float* __restrict__ bq,
    const float* __restrict__ wT, const float* __restrict__ wkT,
    u16* __restrict__ x1g, u16* __restrict__ Gg, u16* __restrict__ Qkg) {
  __shared__ float xs[128];
  __shared__ float x1s[8 * 65];
  __shared__ float qs[8 * 256];
  const int t = threadIdx.x;
  const int n0 = blockIdx.x * 8;
  if (t < 128) xs[t] = x[n0 * 16 + t];
  __syncthreads();
  #pragma unroll
  for (int it = 0; it < 2; ++it) {
    int nb = it * 4 + (t >> 6);
    int col = t & 63;
    float v = b00[col];
    #pragma unroll
    for (int i = 0; i < 16; ++i) v += xs[nb * 16 + i] * w00[i * 64 + col];
    v = fmaxf(v, 0.f);
    x1s[nb * 65 + col] = v;
    x1g[(n0 + nb) * 64 + col] = f2bf(v);
  }
  __syncthreads();
  {
    float aq[8];
    const float bqv = bq[t];
    #pragma unroll
    for (int nb = 0; nb < 8; ++nb) aq[nb] = bqv;
    for (int j = 0; j < 64; ++j) {
      float wqv = wq[j * 256 + t];
      #pragma unroll
      for (int nb = 0; nb < 8; ++nb) aq[nb] += x1s[nb * 65 + j] * wqv;
    }
    #pragma unroll
    for (int nb = 0; nb < 8; ++nb) qs[nb * 256 + t] = aq[nb];
  }
  __syncthreads();
  const int h = t >> 6, j = t & 63;
  float accG[8] = {0, 0, 0, 0, 0, 0, 0, 0};
  float accK[8] = {0, 0, 0, 0, 0, 0, 0, 0};
  for (int c = 0; c < 64; ++c) {
    float wv = wT[(h * 64 + c) * 64 + j];
    float wk = wkT[(h * 64 + c) * 64 + j];
    #pragma unroll
    for (int nb = 0; nb < 8; ++nb) {
      float qv = qs[nb * 256 + h * 64 + c];
      accG[nb] += qv * wv;
      accK[nb] += qv * wk;
    }
  }
  #pragma unroll
  for (int nb = 0; nb < 8; ++nb) {
    Gg[(n0 + nb) * 256 + t] = f2bf(accG[nb]);
    Qkg[(n0 + nb) * 256 + t] = f2bf(accK[nb]);
  }
}

// ---------------- edge MLP via MFMA bf16, output scattered to CSR order ----------------
#define EPB 128
#define APAD 72
__global__ __launch_bounds__(256) void k_edge_mlp(
    const float* __restrict__ ea,
    const u16* __restrict__ wB1t, const u16* __restrict__ wB2t, const u16* __restrict__ wB3t,
    const float* __restrict__ be1, const float* __restrict__ be2, const float* __restrict__ be3,
    const int* __restrict__ e2p, u16* __restrict__ e3g) {
  __shared__ u16 actA[EPB * APAD];
  __shared__ u16 actB[EPB * APAD];
  const int t = threadIdx.x;
  const int w = t >> 6, l = t & 63;
  const int quad = l >> 4, li = l & 15;
  const int e0 = blockIdx.x * EPB;
  const f32x4 zc = {0.f, 0.f, 0.f, 0.f};

  float b1c[4], b2c[4], b3c[4];
  #pragma unroll
  for (int nt = 0; nt < 4; ++nt) {
    b1c[nt] = be1[nt * 16 + li];
    b2c[nt] = be2[nt * 16 + li];
    b3c[nt] = be3[nt * 16 + li];
  }

  bf16x8 b1f[4];
  #pragma unroll
  for (int nt = 0; nt < 4; ++nt) {
    bf16x8 z = {};
    if (quad == 0) z = *(const bf16x8*)(wB1t + (nt * 16 + li) * 8);
    b1f[nt] = z;
  }
  #pragma unroll
  for (int mi = 0; mi < 2; ++mi) {
    const int mt = w * 2 + mi;
    bf16x8 af = {};
    if (quad == 0) {
      const float4* pa = (const float4*)(ea + (size_t)(e0 + mt * 16 + li) * 8);
      float4 p0 = pa[0], p1 = pa[1];
      af[0] = (short)f2bf(p0.x); af[1] = (short)f2bf(p0.y);
      af[2] = (short)f2bf(p0.z); af[3] = (short)f2bf(p0.w);
      af[4] = (short)f2bf(p1.x); af[5] = (short)f2bf(p1.y);
      af[6] = (short)f2bf(p1.z); af[7] = (short)f2bf(p1.w);
    }
    #pragma unroll
    for (int nt = 0; nt < 4; ++nt) {
      f32x4 d = __builtin_amdgcn_mfma_f32_16x16x32_bf16(af, b1f[nt], zc, 0, 0, 0);
      #pragma unroll
      for (int r = 0; r < 4; ++r)
        actA[(mt * 16 + quad * 4 + r) * APAD + nt * 16 + li] = f2bf(fmaxf(d[r] + b1c[nt], 0.f));
    }
  }
  __syncthreads();

  {
    bf16x8 bf[4][2];
    #pragma unroll
    for (int nt = 0; nt < 4; ++nt)
      #pragma unroll
      for (int kk = 0; kk < 2; ++kk)
        bf[nt][kk] = *(const bf16x8*)(wB2t + (nt * 16 + li) * 64 + kk * 32 + quad * 8);
    #pragma unroll
    for (int mi = 0; mi < 2; ++mi) {
      const int mt = w * 2 + mi;
      bf16x8 a0 = *(const bf16x8*)(actA + (mt * 16 + li) * APAD + quad * 8);
      bf16x8 a1 = *(const bf16x8*)(actA + (mt * 16 + li) * APAD + 32 + quad * 8);
      #pragma unroll
      for (int nt = 0; nt < 4; ++nt) {
        f32x4 d = __builtin_amdgcn_mfma_f32_16x16x32_bf16(a0, bf[nt][0], zc, 0, 0, 0);
        d = __builtin_amdgcn_mfma_f32_16x16x32_bf16(a1, bf[nt][1], d, 0, 0, 0);
        #pragma unroll
        for (int r = 0; r < 4; ++r)
          actB[(mt * 16 + quad * 4 + r) * APAD + nt * 16 + li] = f2bf(fmaxf(d[r] + b2c[nt], 0.f));
      }
    }
  }
  __syncthreads();

  {
    bf16x8 bf[4][2];
    #pragma unroll
    for (int nt = 0; nt < 4; ++nt)
      #pragma unroll
      for (int kk = 0; kk < 2; ++kk)
        bf[nt][kk] = *(const bf16x8*)(wB3t + (nt * 16 + li) * 64 + kk * 32 + quad * 8);
    #pragma unroll
    for (int mi = 0; mi < 2; ++mi) {
      const int mt = w * 2 + mi;
      bf16x8 a0 = *(const bf16x8*)(actB + (mt * 16 + li) * APAD + quad * 8);
      bf16x8 a1 = *(const bf16x8*)(actB + (mt * 16 + li) * APAD + 32 + quad * 8);
      #pragma unroll
      for (int nt = 0; nt < 4; ++nt) {
        f32x4 d = __builtin_amdgcn_mfma_f32_16x16x32_bf16(a0, bf[nt][0], zc, 0, 0, 0);
        d = __builtin_amdgcn_mfma_f32_16x16x32_bf16(a1, bf[nt][1], d, 0, 0, 0);
        #pragma unroll
        for (int r = 0; r < 4; ++r)
          actA[(mt * 16 + quad * 4 + r) * APAD + nt * 16 + li] = f2bf(fmaxf(d[r] + b3c[nt], 0.f));
      }
    }
  }
  __syncthreads();

  // scatter rows to CSR positions (e2p); invalid -> scratch row NE
  #pragma unroll
  for (int it = 0; it < 4; ++it) {
    int flat = it * 2048 + t * 8;
    int el = flat >> 6, c = flat & 63;
    int pos = e2p[e0 + el];
    pos = ((unsigned)pos <= (unsigned)(NE - 1)) ? pos : NE;
    uint4 v = *(const uint4*)(actA + el * APAD + c);
    *(uint4*)(e3g + (size_t)pos * 64 + c) = v;
  }
}

// ---------------- attention gather: sequential e3 (CSR order), x1 via L2 table ----------------
// alpha' = (Qk·x1[src] + G·e3[pos]) / 8   (the q·(bk+bedge) constant cancels in softmax)
__global__ __launch_bounds__(256) void k_attn(
    const int* __restrict__ rowptr, const int* __restrict__ slist,
    u16* yo, const u16* __restrict__ x1g, u16* gz, const u16* __restrict__ Qkg,
    const u16* __restrict__ e3g, float* __restrict__ bfac) {
  const int t = threadIdx.x;
  const int w = t >> 6;
  const int l = t & 63;
  const int grp = l >> 4;
  const int li = l & 15;
  const int chb = grp * 64 + li * 4;
  const int n = blockIdx.x * 4 + w;
  int base = rowptr[n];
  int end  = rowptr[n + 1];
  base = max(0, min(base, NE));
  end  = max(base, min(end, NE));
  if (l == 0) bfac[n] = (end > base) ? 1.f : 0.f;

  float Qkf[4], Gf[4];
  {
    ushort4 kv = *(const ushort4*)(Qkg + (size_t)n * 256 + chb);
    Qkf[0] = bf2f(kv.x); Qkf[1] = bf2f(kv.y); Qkf[2] = bf2f(kv.z); Qkf[3] = bf2f(kv.w);
    ushort4 gv = *(const ushort4*)(gz + (size_t)n * 256 + chb);
    Gf[0] = bf2f(gv.x); Gf[1] = bf2f(gv.y); Gf[2] = bf2f(gv.z); Gf[3] = bf2f(gv.w);
  }

  float s_run = 0.f;
  float y[4] = {0, 0, 0, 0}, zz[4] = {0, 0, 0, 0};
  int d = base;
  for (; d + 1 < end; d += 2) {
    int src0 = slist[d], src1 = slist[d + 1];
    src0 = max(0, min(src0, NN - 1)); src1 = max(0, min(src1, NN - 1));
    ushort4 x0 = *(const ushort4*)(x1g + (size_t)src0 * 64 + li * 4);
    ushort4 e0 = *(const ushort4*)(e3g + (size_t)d * 64 + li * 4);
    ushort4 x1v = *(const ushort4*)(x1g + (size_t)src1 * 64 + li * 4);
    ushort4 e1 = *(const ushort4*)(e3g + (size_t)(d + 1) * 64 + li * 4);
    float xf00 = bf2f(x0.x), xf01 = bf2f(x0.y), xf02 = bf2f(x0.z), xf03 = bf2f(x0.w);
    float ef00 = bf2f(e0.x), ef01 = bf2f(e0.y), ef02 = bf2f(e0.z), ef03 = bf2f(e0.w);
    float xf10 = bf2f(x1v.x), xf11 = bf2f(x1v.y), xf12 = bf2f(x1v.z), xf13 = bf2f(x1v.w);
    float ef10 = bf2f(e1.x), ef11 = bf2f(e1.y), ef12 = bf2f(e1.z), ef13 = bf2f(e1.w);
    float p0 = Qkf[0]*xf00 + Qkf[1]*xf01 + Qkf[2]*xf02 + Qkf[3]*xf03
             + Gf[0]*ef00 + Gf[1]*ef01 + Gf[2]*ef02 + Gf[3]*ef03;
    float p1 = Qkf[0]*xf10 + Qkf[1]*xf11 + Qkf[2]*xf12 + Qkf[3]*xf13
             + Gf[0]*ef10 + Gf[1]*ef11 + Gf[2]*ef12 + Gf[3]*ef13;
    #pragma unroll
    for (int mk = 1; mk < 16; mk <<= 1) { p0 += __shfl_xor(p0, mk); p1 += __shfl_xor(p1, mk); }
    float w0 = __expf(fminf(p0 * 0.125f, 60.f));
    float w1 = __expf(fminf(p1 * 0.125f, 60.f));
    s_run += w0 + w1;
    y[0] += w0*xf00 + w1*xf10; y[1] += w0*xf01 + w1*xf11;
    y[2] += w0*xf02 + w1*xf12; y[3] += w0*xf03 + w1*xf13;
    zz[0] += w0*ef00 + w1*ef10; zz[1] += w0*ef01 + w1*ef11;
    zz[2] += w0*ef02 + w1*ef12; zz[3] += w0*ef03 + w1*ef13;
  }
  if (d < end) {
    int src0 = slist[d];
    src0 = max(0, min(src0, NN - 1));
    ushort4 x0 = *(const ushort4*)(x1g + (size_t)src0 * 64 + li * 4);
    ushort4 e0 = *(const ushort4*)(e3g + (size_t)d * 64 + li * 4);
    float xf00 = bf2f(x0.x), xf01 = bf2f(x0.y), xf02 = bf2f(x0.z), xf03 = bf2f(x0.w);
    float ef00 = bf2f(e0.x), ef01 = bf2f(e0.y), ef02 = bf2f(e0.z), ef03 = bf2f(e0.w);
    float p0 = Qkf[0]*xf00 + Qkf[1]*xf01 + Qkf[2]*xf02 + Qkf[3]*xf03
             + Gf[0]*ef00 + Gf[1]*ef01 + Gf[2]*ef02 + Gf[3]*ef03;
    #pragma unroll
    for (int mk = 1; mk < 16; mk <<= 1) p0 += __shfl_xor(p0, mk);
    float w0 = __expf(fminf(p0 * 0.125f, 60.f));
    s_run += w0;
    y[0] += w0*xf00; y[1] += w0*xf01; y[2] += w0*xf02; y[3] += w0*xf03;
    zz[0] += w0*ef00; zz[1] += w0*ef01; zz[2] += w0*ef02; zz[3] += w0*ef03;
  }
  const float inv_s = 1.0f / (s_run + 1e-16f);
  ushort4 ynv, znv;
  ynv.x = f2bf(y[0] * inv_s); ynv.y = f2bf(y[1] * inv_s);
  ynv.z = f2bf(y[2] * inv_s); ynv.w = f2bf(y[3] * inv_s);
  znv.x = f2bf(zz[0] * inv_s); znv.y = f2bf(zz[1] * inv_s);
  znv.z = f2bf(zz[2] * inv_s); znv.w = f2bf(zz[3] * inv_s);
  *(ushort4*)(yo + (size_t)n * 256 + chb) = ynv;
  *(ushort4*)(gz + (size_t)n * 256 + chb) = znv;
}

// ---------------- post via MFMA ----------------
#define PM 64
#define PK 576
#define PAPAD 584
__global__ __launch_bounds__(256) void k_post(
    const u16* __restrict__ zng, const u16* __restrict__ yng, const u16* __restrict__ x1g,
    const u16* __restrict__ Bt, const float* __restrict__ bfac,
    const float* __restrict__ bedge, const float* __restrict__ bv, const float* __restrict__ bskip,
    const float* __restrict__ lng, const float* __restrict__ lnb,
    u16* __restrict__ postg) {
  __shared__ u16 As[PM * PAPAD];
  __shared__ float ps1[PM * 4];
  __shared__ float ps2[PM * 4];
  const int t = threadIdx.x;
  const int w = t >> 6, l = t & 63;
  const int quad = l >> 4, li = l & 15;
  const int n0 = blockIdx.x * PM;

  for (int q = t; q < 2048; q += 256) {
    int row = q >> 5, off = (q & 31) * 8;
    uint4 vz = make_uint4(0, 0, 0, 0), vy = make_uint4(0, 0, 0, 0);
    if (n0 + row < NN) {
      vz = *(const uint4*)(zng + (size_t)(n0 + row) * 256 + off);
      vy = *(const uint4*)(yng + (size_t)(n0 + row) * 256 + off);
    }
    *(uint4*)(As + row * PAPAD + off) = vz;
    *(uint4*)(As + row * PAPAD + 256 + off) = vy;
  }
  for (int q = t; q < 512; q += 256) {
    int row = q >> 3, off = (q & 7) * 8;
    uint4 v = make_uint4(0, 0, 0, 0);
    if (n0 + row < NN) v = *(const uint4*)(x1g + (size_t)(n0 + row) * 64 + off);
    *(uint4*)(As + row * PAPAD + 512 + off) = v;
  }
  __syncthreads();

  f32x4 acc[4][4];
  #pragma unroll
  for (int mt = 0; mt < 4; ++mt)
    #pragma unroll
    for (int nt = 0; nt < 4; ++nt) acc[mt][nt] = (f32x4){0.f, 0.f, 0.f, 0.f};

  const int colbase = w * 64;
  #pragma unroll
  for (int s = 0; s < 18; ++s) {
    bf16x8 bf[4];
    #pragma unroll
    for (int nt = 0; nt < 4; ++nt)
      bf[nt] = *(const bf16x8*)(Bt + (size_t)(colbase + nt * 16 + li) * PK + s * 32 + quad * 8);
    #pragma unroll
    for (int mt = 0; mt < 4; ++mt) {
      bf16x8 af = *(const bf16x8*)(As + (mt * 16 + li) * PAPAD + s * 32 + quad * 8);
      #pragma unroll
      for (int nt = 0; nt < 4; ++nt)
        acc[mt][nt] = __builtin_amdgcn_mfma_f32_16x16x32_bf16(af, bf[nt], acc[mt][nt], 0, 0, 0);
    }
  }

  float beb[4], bs4[4], g4[4], lb4[4];
  #pragma unroll
  for (int nt = 0; nt < 4; ++nt) {
    int col = colbase + nt * 16 + li;
    beb[nt] = bedge[col] + bv[col];
    bs4[nt] = bskip[col]; g4[nt] = lng[col]; lb4[nt] = lnb[col];
  }
  #pragma unroll
  for (int mt = 0; mt < 4; ++mt) {
    #pragma unroll
    for (int r = 0; r < 4; ++r) {
      int node = n0 + mt * 16 + quad * 4 + r;
      float hasE = bfac[min(node, NN - 1)];
      #pragma unroll
      for (int nt = 0; nt < 4; ++nt)
        acc[mt][nt][r] += hasE * beb[nt] + bs4[nt];
    }
  }
  #pragma unroll
  for (int mt = 0; mt < 4; ++mt)
    #pragma unroll
    for (int r = 0; r < 4; ++r) {
      float s = acc[mt][0][r] + acc[mt][1][r] + acc[mt][2][r] + acc[mt][3][r];
      #pragma unroll
      for (int mk = 1; mk < 16; mk <<= 1) s += __shfl_xor(s, mk);
      if (li == 0) ps1[(mt * 16 + quad * 4 + r) * 4 + w] = s;
    }
  __syncthreads();
  float mu[4][4];
  #pragma unroll
  for (int mt = 0; mt < 4; ++mt)
    #pragma unroll
    for (int r = 0; r < 4; ++r) {
      float4 p = *(const float4*)(ps1 + (mt * 16 + quad * 4 + r) * 4);
      mu[mt][r] = (p.x + p.y + p.z + p.w) * (1.0f / 256.0f);
    }
  #pragma unroll
  for (int mt = 0; mt < 4; ++mt)
    #pragma unroll
    for (int r = 0; r < 4; ++r) {
      float m = mu[mt][r];
      float s = 0.f;
      #pragma unroll
      for (int nt = 0; nt < 4; ++nt) { float dd = acc[mt][nt][r] - m; s += dd * dd; }
      #pragma unroll
      for (int mk = 1; mk < 16; mk <<= 1) s += __shfl_xor(s, mk);
      if (li == 0) ps2[(mt * 16 + quad * 4 + r) * 4 + w] = s;
    }
  __syncthreads();
  #pragma unroll
  for (int mt = 0; mt < 4; ++mt)
    #pragma unroll
    for (int r = 0; r < 4; ++r) {
      float4 p = *(const float4*)(ps2 + (mt * 16 + quad * 4 + r) * 4);
      float rstd = rsqrtf((p.x + p.y + p.z + p.w) * (1.0f / 256.0f) + 1e-5f);
      int node = n0 + mt * 16 + quad * 4 + r;
      if (node < NN) {
        float m = mu[mt][r];
        #pragma unroll
        for (int nt = 0; nt < 4; ++nt) {
          int col = colbase + nt * 16 + li;
          postg[(size_t)node * 256 + col] =
              f2bf(fmaxf((acc[mt][nt][r] - m) * rstd * g4[nt] + lb4[nt], 0.f));
        }
      }
    }
}

// ---------------- head via MFMA ----------------
#define HAPAD 264
#define H1PAD 136
__global__ __launch_bounds__(256) void k_head(
    const u16* __restrict__ postg, const u16* __restrict__ Bt1,
    const float* __restrict__ b1, const float* __restrict__ w2, const float* __restrict__ b2,
    float* __restrict__ outg) {
  __shared__ u16 As[64 * HAPAD];
  __shared__ u16 h1s[64 * H1PAD];
  const int t = threadIdx.x;
  const int w = t >> 6, l = t & 63;
  const int quad = l >> 4, li = l & 15;
  const int n0 = blockIdx.x * 64;

  for (int q = t; q < 2048; q += 256) {
    int row = q >> 5, off = (q & 31) * 8;
    uint4 v = make_uint4(0, 0, 0, 0);
    if (n0 + row < NN) v = *(const uint4*)(postg + (size_t)(n0 + row) * 256 + off);
    *(uint4*)(As + row * HAPAD + off) = v;
  }
  __syncthreads();

  f32x4 acc[4][2];
  #pragma unroll
  for (int mt = 0; mt < 4; ++mt)
    #pragma unroll
    for (int nt = 0; nt < 2; ++nt) acc[mt][nt] = (f32x4){0.f, 0.f, 0.f, 0.f};
  const int colbase = w * 32;
  #pragma unroll
  for (int s = 0; s < 8; ++s) {
    bf16x8 bf[2];
    #pragma unroll
    for (int nt = 0; nt < 2; ++nt)
      bf[nt] = *(const bf16x8*)(Bt1 + (size_t)(colbase + nt * 16 + li) * 256 + s * 32 + quad * 8);
    #pragma unroll
    for (int mt = 0; mt < 4; ++mt) {
      bf16x8 af = *(const bf16x8*)(As + (mt * 16 + li) * HAPAD + s * 32 + quad * 8);
      #pragma unroll
      for (int nt = 0; nt < 2; ++nt)
        acc[mt][nt] = __builtin_amdgcn_mfma_f32_16x16x32_bf16(af, bf[nt], acc[mt][nt], 0, 0, 0);
    }
  }
  float b1c[2];
  #pragma unroll
  for (int nt = 0; nt < 2; ++nt) b1c[nt] = b1[colbase + nt * 16 + li];
  #pragma unroll
  for (int mt = 0; mt < 4; ++mt)
    #pragma unroll
    for (int nt = 0; nt < 2; ++nt)
      #pragma unroll
      for (int r = 0; r < 4; ++r)
        h1s[(mt * 16 + quad * 4 + r) * H1PAD + colbase + nt * 16 + li] =
            f2bf(fmaxf(acc[mt][nt][r] + b1c[nt], 0.f));
  __syncthreads();

  const int node = t >> 2, c = t & 3;
  float lg = b2[c];
  const u16* hrow = h1s + node * H1PAD;
  #pragma unroll 4
  for (int j = 0; j < 128; ++j) lg += bf2f(hrow[j]) * w2[j * 4 + c];
  float mx = lg;
  #pragma unroll
  for (int mk = 1; mk < 4; mk <<= 1) mx = fmaxf(mx, __shfl_xor(mx, mk));
  float ex = __expf(lg - mx);
  float se = ex;
  #pragma unroll
  for (int mk = 1; mk < 4; mk <<= 1) se += __shfl_xor(se, mk);
  float res = lg - (mx + __logf(se));
  if (n0 + node < NN) outg[(size_t)(n0 + node) * 4 + c] = res;
}

extern "C" void kernel_launch(void* const* d_in, const int* in_sizes, int n_in,
                              void* d_out, int out_size, void* d_ws, size_t ws_size,
                              hipStream_t stream) {
  const float* x     = (const float*)d_in[0];
  const int*   ei    = (const int*)d_in[1];
  const float* ea    = (const float*)d_in[2];
  const float* w00   = (const float*)d_in[3];
  const float* b00   = (const float*)d_in[4];
  const float* we1   = (const float*)d_in[5];
  const float* be1   = (const float*)d_in[6];
  const float* we2   = (const float*)d_in[7];
  const float* be2   = (const float*)d_in[8];
  const float* we3   = (const float*)d_in[9];
  const float* be3   = (const float*)d_in[10];
  const float* wq    = (const float*)d_in[11];
  const float* bq    = (const float*)d_in[12];
  const float* wk    = (const float*)d_in[13];
  const float* bk    = (const float*)d_in[14];
  const float* wv    = (const float*)d_in[15];
  const float* bv    = (const float*)d_in[16];
  const float* wedge = (const float*)d_in[17];
  const float* bedge = (const float*)d_in[18];
  const float* wskip = (const float*)d_in[19];
  const float* bskip = (const float*)d_in[20];
  const float* lng   = (const float*)d_in[21];
  const float* lnb   = (const float*)d_in[22];
  const float* w1    = (const float*)d_in[23];
  const float* b1    = (const float*)d_in[24];
  const float* w2    = (const float*)d_in[25];
  const float* b2    = (const float*)d_in[26];
  float* outg = (float*)d_out;
  (void)bk;

  size_t off = 0;
  char* wsb = (char*)d_ws;
  auto carve = [&](size_t bytes) -> char* {
    char* r = wsb + off;
    off += (bytes + 255) & ~(size_t)255;
    return r;
  };
  u16* yg     = (u16*)carve((size_t)NN * 256 * 2);      // yn
  u16* Gg     = (u16*)carve((size_t)NN * 256 * 2);      // G -> zn
  u16* Qkg    = (u16*)carve((size_t)NN * 256 * 2);      // Qk
  u16* x1g    = (u16*)carve((size_t)NN * 64 * 2);
  u16* e3g    = (u16*)carve((size_t)(NE + 1) * 64 * 2); // e3 in CSR order (+1 scratch row)
  int* deg    = (int*)carve((size_t)NN * 4);
  int* rowptr = (int*)carve((size_t)(NN + 1) * 4);
  int* cursor = (int*)carve((size_t)NN * 4);
  int* slist  = (int*)carve((size_t)NE * 4);
  int* e2p    = (int*)carve((size_t)NE * 4);
  float* bfac = (float*)carve((size_t)NN * 4);
  int* bsum   = (int*)carve((size_t)SCAN_NB * 4);
  int* boff   = (int*)carve((size_t)SCAN_NB * 4);
  float* wT   = (float*)carve(16384 * 4);
  float* wkT  = (float*)carve(16384 * 4);
  u16* wB1t   = (u16*)carve(512 * 2);
  u16* wB2t   = (u16*)carve(4096 * 2);
  u16* wB3t   = (u16*)carve(4096 * 2);
  u16* Bt     = (u16*)carve((size_t)256 * 576 * 2);
  u16* Bt1    = (u16*)carve((size_t)128 * 256 * 2);
  u16* postg  = e3g;   // e3g dead after k_attn
  if (off > ws_size) return;

  k_prep<<<128, 256, 0, stream>>>(wedge, wk, wT, wkT);
  k_prep_w<<<34, 256, 0, stream>>>(we1, we2, we3, wB1t, wB2t, wB3t);
  k_prep_b<<<256, 576, 0, stream>>>(wedge, wv, wskip, Bt);
  k_prep_h<<<128, 256, 0, stream>>>(w1, Bt1);
  k_zero<<<SCAN_NB, 256, 0, stream>>>(deg);
  k_hist<<<NE / 256, 256, 0, stream>>>(ei, deg);
  k_scan_a<<<SCAN_NB, 256, 0, stream>>>(deg, bsum);
  k_scan_b<<<1, 256, 0, stream>>>(bsum, boff, rowptr);
  k_scan_c<<<SCAN_NB, 256, 0, stream>>>(deg, boff, rowptr, cursor);
  k_scatter<<<NE / 256, 256, 0, stream>>>(ei, cursor, slist, e2p);
  k_ng<<<NN / 8, 256, 0, stream>>>(x, w00, b00, wq, bq, wT, wkT, x1g, Gg, Qkg);
  k_edge_mlp<<<NE / EPB, 256, 0, stream>>>(ea, wB1t, wB2t, wB3t, be1, be2, be3, e2p, e3g);
  k_attn<<<NN / 4, 256, 0, stream>>>(rowptr, slist, yg, x1g, Gg, Qkg, e3g, bfac);
  k_post<<<(NN + PM - 1) / PM, 256, 0, stream>>>(Gg, yg, x1g, Bt, bfac, bedge, bv, bskip,
                                                 lng, lnb, postg);
  k_head<<<(NN + 63) / 64, 256, 0, stream>>>(postg, Bt1, b1, w2, b2, outg);
}

// Round 11
// 498.987 us; speedup vs baseline: 2.3872x; 1.1039x over previous
//
#include <hip/hip_runtime.h>
#include <hip/hip_bf16.h>

typedef unsigned short u16;
typedef __attribute__((ext_vector_type(8))) short bf16x8;
typedef __attribute__((ext_vector_type(4))) float f32x4;

#define NN 50000
#define NE 800000
#define SCAN_NB ((NN + 255) / 256)

__device__ __forceinline__ float bf2f(u16 u) { return __uint_as_float(((unsigned)u) << 16); }
__device__ __forceinline__ u16 f2bf(float f) {
  unsigned u = __float_as_uint(f);
  return (u16)((u + 0x7FFFu + ((u >> 16) & 1u)) >> 16);
}

// ---------------- CSR build ----------------
__global__ void k_zero(int* __restrict__ deg) {
  int i = blockIdx.x * 256 + threadIdx.x;
  if (i < NN) deg[i] = 0;
}

__global__ void k_hist(const int* __restrict__ ei, int* __restrict__ deg) {
  int i = blockIdx.x * 256 + threadIdx.x;
  if (i < NE) {
    int d = ei[NE + i];
    if (d >= 0 && d < NN) atomicAdd(&deg[d], 1);
  }
}

__global__ __launch_bounds__(256) void k_scan_a(const int* __restrict__ deg,
                                                int* __restrict__ bsum) {
  __shared__ int red[256];
  const int t = threadIdx.x;
  const int i = blockIdx.x * 256 + t;
  red[t] = (i < NN) ? deg[i] : 0;
  __syncthreads();
  #pragma unroll
  for (int s = 128; s > 0; s >>= 1) {
    if (t < s) red[t] += red[t + s];
    __syncthreads();
  }
  if (t == 0) bsum[blockIdx.x] = red[0];
}

__global__ __launch_bounds__(256) void k_scan_b(const int* __restrict__ bsum,
                                                int* __restrict__ boff,
                                                int* __restrict__ rowptr) {
  __shared__ int s[256];
  const int t = threadIdx.x;
  int v = (t < SCAN_NB) ? bsum[t] : 0;
  s[t] = v;
  __syncthreads();
  #pragma unroll
  for (int o = 1; o < 256; o <<= 1) {
    int u = (t >= o) ? s[t - o] : 0;
    __syncthreads();
    s[t] += u;
    __syncthreads();
  }
  if (t < SCAN_NB) boff[t] = s[t] - v;
  if (t == 255) rowptr[NN] = s[255];
}

__global__ __launch_bounds__(256) void k_scan_c(const int* __restrict__ deg,
                                                const int* __restrict__ boff,
                                                int* __restrict__ rowptr,
                                                int* __restrict__ cursor) {
  __shared__ int s[256];
  const int t = threadIdx.x;
  const int i = blockIdx.x * 256 + t;
  int v = (i < NN) ? deg[i] : 0;
  s[t] = v;
  __syncthreads();
  #pragma unroll
  for (int o = 1; o < 256; o <<= 1) {
    int u = (t >= o) ? s[t - o] : 0;
    __syncthreads();
    s[t] += u;
    __syncthreads();
  }
  if (i < NN) {
    int r = boff[blockIdx.x] + s[t] - v;
    rowptr[i] = r;
    cursor[i] = r;
  }
}

__global__ void k_scatter(const int* __restrict__ ei, int* __restrict__ cursor,
                          int* __restrict__ slist, int* __restrict__ e2p) {
  int i = blockIdx.x * 256 + threadIdx.x;
  if (i < NE) {
    int d = ei[NE + i];
    if (d >= 0 && d < NN) {
      int pos = atomicAdd(&cursor[d], 1);
      if (pos >= 0 && pos < NE) {
        e2p[i] = pos;
        int s = ei[i];
        slist[pos] = max(0, min(s, NN - 1));
      }
    }
  }
}

// ---------------- weight prep ----------------
// wB00t[n*32+k] = k<16 ? w00[k*64+n] : 0          (2048)
// wqt[n*64+k]   = wq[k*256+n]                      (16384)
// BGQ[col*256+k]: col<256 -> blkdiag wedge; col in [256,512) -> blkdiag wk   (131072)
__global__ void k_prep_ng(const float* __restrict__ w00, const float* __restrict__ wq,
                          const float* __restrict__ wedge, const float* __restrict__ wk,
                          u16* __restrict__ wB00t, u16* __restrict__ wqt, u16* __restrict__ BGQ) {
  int i = blockIdx.x * 256 + threadIdx.x;
  if (i < 2048) {
    int n = i >> 5, k = i & 31;
    wB00t[i] = (k < 16) ? f2bf(w00[k * 64 + n]) : (u16)0;
  } else if (i < 2048 + 16384) {
    int i2 = i - 2048;
    int n = i2 >> 6, k = i2 & 63;
    wqt[i2] = f2bf(wq[k * 256 + n]);
  } else if (i < 2048 + 16384 + 131072) {
    int i2 = i - 2048 - 16384;
    int col = i2 >> 8, k = i2 & 255;
    float v;
    if (col < 256) v = ((k >> 6) == (col >> 6)) ? wedge[(col & 63) * 256 + k] : 0.f;
    else { int c = col - 256; v = ((k >> 6) == (c >> 6)) ? wk[(c & 63) * 256 + k] : 0.f; }
    BGQ[i2] = f2bf(v);
  }
}

__global__ void k_prep_w(const float* __restrict__ we1, const float* __restrict__ we2,
                         const float* __restrict__ we3,
                         u16* __restrict__ wB1t, u16* __restrict__ wB2t, u16* __restrict__ wB3t) {
  int i = blockIdx.x * 256 + threadIdx.x;
  if (i < 512) {
    int n = i >> 3, k = i & 7;
    wB1t[i] = f2bf(we1[k * 64 + n]);
  } else if (i < 512 + 4096) {
    int i2 = i - 512;
    int n = i2 >> 6, k = i2 & 63;
    wB2t[i2] = f2bf(we2[k * 64 + n]);
  } else if (i < 512 + 8192) {
    int i2 = i - 512 - 4096;
    int n = i2 >> 6, k = i2 & 63;
    wB3t[i2] = f2bf(we3[k * 64 + n]);
  }
}

// Bt[col][k] bf16, K=576: [0,256) blk-diag wedge | [256,512) blk-diag wv | [512,576) wskip
__global__ void k_prep_b(const float* __restrict__ wedge, const float* __restrict__ wv,
                         const float* __restrict__ wskip, u16* __restrict__ Bt) {
  const int col = blockIdx.x;
  const int k = threadIdx.x;
  float v;
  if (k < 256) v = ((k >> 6) == (col >> 6)) ? wedge[(k & 63) * 256 + col] : 0.f;
  else if (k < 512) { int k2 = k - 256; v = ((k2 >> 6) == (col >> 6)) ? wv[(k2 & 63) * 256 + col] : 0.f; }
  else v = wskip[(k - 512) * 256 + col];
  Bt[col * 576 + k] = f2bf(v);
}

__global__ void k_prep_h(const float* __restrict__ w1, u16* __restrict__ Bt1) {
  const int col = blockIdx.x;
  const int k = threadIdx.x;
  Bt1[col * 256 + k] = f2bf(w1[k * 128 + col]);
}

// ---------------- node chain via MFMA: x -> x1 -> q -> {G, Qk} ----------------
// 64 nodes/block. A-frag A[m=li][k=quad*8+j], B-frag B[k=quad*8+j][n=li],
// C/D col=lane&15, row=quad*4+reg (m89/m91-verified).
__global__ __launch_bounds__(256) void k_ng(
    const float* __restrict__ x, const u16* __restrict__ wB00t, const float* __restrict__ b00,
    const u16* __restrict__ wqt, const float* __restrict__ bq,
    const u16* __restrict__ BGQ,
    u16* __restrict__ x1g, u16* __restrict__ Gg, u16* __restrict__ Qkg) {
  __shared__ u16 xs[64 * 32];     // x staged, K padded 16->32
  __shared__ u16 x1s[64 * 72];
  __shared__ u16 qs[64 * 264];
  const int t = threadIdx.x;
  const int w = t >> 6, l = t & 63;
  const int quad = l >> 4, li = l & 15;
  const int n0 = blockIdx.x * 64;
  const f32x4 zc = {0.f, 0.f, 0.f, 0.f};

  // stage x (fp32 -> bf16, zero-pad k>=16 and rows >= NN)
  for (int q = t; q < 2048; q += 256) {
    int row = q >> 5, k = q & 31;
    float v = (k < 16 && n0 + row < NN) ? x[(size_t)(n0 + row) * 16 + k] : 0.f;
    xs[row * 32 + k] = f2bf(v);
  }
  __syncthreads();

  // ---- layer 1: x1 = relu(x @ w00 + b00); wave w -> n-tile w ----
  {
    bf16x8 bf = *(const bf16x8*)(wB00t + (w * 16 + li) * 32 + quad * 8);
    float bc = b00[w * 16 + li];
    #pragma unroll
    for (int mt = 0; mt < 4; ++mt) {
      bf16x8 af = *(const bf16x8*)(xs + (mt * 16 + li) * 32 + quad * 8);
      f32x4 d = __builtin_amdgcn_mfma_f32_16x16x32_bf16(af, bf, zc, 0, 0, 0);
      #pragma unroll
      for (int r = 0; r < 4; ++r)
        x1s[(mt * 16 + quad * 4 + r) * 72 + w * 16 + li] = f2bf(fmaxf(d[r] + bc, 0.f));
    }
  }
  __syncthreads();

  // coalesced x1 write-out
  #pragma unroll
  for (int it = 0; it < 2; ++it) {
    int i = (it * 256 + t) * 8;
    int row = i >> 6, col = i & 63;
    if (n0 + row < NN)
      *(uint4*)(x1g + (size_t)(n0 + row) * 64 + col) = *(const uint4*)(x1s + row * 72 + col);
  }

  // ---- layer 2: q = x1 @ wq + bq; wave w -> cols [w*64, w*64+64) ----
  {
    f32x4 acc[4][4];
    #pragma unroll
    for (int mt = 0; mt < 4; ++mt)
      #pragma unroll
      for (int nt = 0; nt < 4; ++nt) acc[mt][nt] = zc;
    const int colbase = w * 64;
    #pragma unroll
    for (int s = 0; s < 2; ++s) {
      bf16x8 bf[4];
      #pragma unroll
      for (int nt = 0; nt < 4; ++nt)
        bf[nt] = *(const bf16x8*)(wqt + (size_t)(colbase + nt * 16 + li) * 64 + s * 32 + quad * 8);
      #pragma unroll
      for (int mt = 0; mt < 4; ++mt) {
        bf16x8 af = *(const bf16x8*)(x1s + (mt * 16 + li) * 72 + s * 32 + quad * 8);
        #pragma unroll
        for (int nt = 0; nt < 4; ++nt)
          acc[mt][nt] = __builtin_amdgcn_mfma_f32_16x16x32_bf16(af, bf[nt], acc[mt][nt], 0, 0, 0);
      }
    }
    float bqc[4];
    #pragma unroll
    for (int nt = 0; nt < 4; ++nt) bqc[nt] = bq[colbase + nt * 16 + li];
    #pragma unroll
    for (int mt = 0; mt < 4; ++mt)
      #pragma unroll
      for (int nt = 0; nt < 4; ++nt)
        #pragma unroll
        for (int r = 0; r < 4; ++r)
          qs[(mt * 16 + quad * 4 + r) * 264 + colbase + nt * 16 + li] = f2bf(acc[mt][nt][r] + bqc[nt]);
  }
  __syncthreads();

  // ---- layer 3a/3b: G = q @ BGQ[:,0:256), Qk = q @ BGQ[:,256:512) ----
  #pragma unroll
  for (int half = 0; half < 2; ++half) {
    f32x4 acc[4][4];
    #pragma unroll
    for (int mt = 0; mt < 4; ++mt)
      #pragma unroll
      for (int nt = 0; nt < 4; ++nt) acc[mt][nt] = zc;
    const int colbase = w * 64;
    const size_t bofs = (size_t)(half * 256) * 256;
    #pragma unroll
    for (int s = 0; s < 8; ++s) {
      bf16x8 bf[4];
      #pragma unroll
      for (int nt = 0; nt < 4; ++nt)
        bf[nt] = *(const bf16x8*)(BGQ + bofs + (size_t)(colbase + nt * 16 + li) * 256 + s * 32 + quad * 8);
      #pragma unroll
      for (int mt = 0; mt < 4; ++mt) {
        bf16x8 af = *(const bf16x8*)(qs + (mt * 16 + li) * 264 + s * 32 + quad * 8);
        #pragma unroll
        for (int nt = 0; nt < 4; ++nt)
          acc[mt][nt] = __builtin_amdgcn_mfma_f32_16x16x32_bf16(af, bf[nt], acc[mt][nt], 0, 0, 0);
      }
    }
    u16* dst = half ? Qkg : Gg;
    #pragma unroll
    for (int mt = 0; mt < 4; ++mt)
      #pragma unroll
      for (int r = 0; r < 4; ++r) {
        int node = n0 + mt * 16 + quad * 4 + r;
        if (node < NN) {
          #pragma unroll
          for (int nt = 0; nt < 4; ++nt)
            dst[(size_t)node * 256 + colbase + nt * 16 + li] = f2bf(acc[mt][nt][r]);
        }
      }
  }
}

// ---------------- edge MLP via MFMA bf16, output scattered to CSR order ----------------
#define EPB 128
#define APAD 72
__global__ __launch_bounds__(256) void k_edge_mlp(
    const float* __restrict__ ea,
    const u16* __restrict__ wB1t, const u16* __restrict__ wB2t, const u16* __restrict__ wB3t,
    const float* __restrict__ be1, const float* __restrict__ be2, const float* __restrict__ be3,
    const int* __restrict__ e2p, u16* __restrict__ e3g) {
  __shared__ u16 actA[EPB * APAD];
  __shared__ u16 actB[EPB * APAD];
  const int t = threadIdx.x;
  const int w = t >> 6, l = t & 63;
  const int quad = l >> 4, li = l & 15;
  const int e0 = blockIdx.x * EPB;
  const f32x4 zc = {0.f, 0.f, 0.f, 0.f};

  float b1c[4], b2c[4], b3c[4];
  #pragma unroll
  for (int nt = 0; nt < 4; ++nt) {
    b1c[nt] = be1[nt * 16 + li];
    b2c[nt] = be2[nt * 16 + li];
    b3c[nt] = be3[nt * 16 + li];
  }

  bf16x8 b1f[4];
  #pragma unroll
  for (int nt = 0; nt < 4; ++nt) {
    bf16x8 z = {};
    if (quad == 0) z = *(const bf16x8*)(wB1t + (nt * 16 + li) * 8);
    b1f[nt] = z;
  }
  #pragma unroll
  for (int mi = 0; mi < 2; ++mi) {
    const int mt = w * 2 + mi;
    bf16x8 af = {};
    if (quad == 0) {
      const float4* pa = (const float4*)(ea + (size_t)(e0 + mt * 16 + li) * 8);
      float4 p0 = pa[0], p1 = pa[1];
      af[0] = (short)f2bf(p0.x); af[1] = (short)f2bf(p0.y);
      af[2] = (short)f2bf(p0.z); af[3] = (short)f2bf(p0.w);
      af[4] = (short)f2bf(p1.x); af[5] = (short)f2bf(p1.y);
      af[6] = (short)f2bf(p1.z); af[7] = (short)f2bf(p1.w);
    }
    #pragma unroll
    for (int nt = 0; nt < 4; ++nt) {
      f32x4 d = __builtin_amdgcn_mfma_f32_16x16x32_bf16(af, b1f[nt], zc, 0, 0, 0);
      #pragma unroll
      for (int r = 0; r < 4; ++r)
        actA[(mt * 16 + quad * 4 + r) * APAD + nt * 16 + li] = f2bf(fmaxf(d[r] + b1c[nt], 0.f));
    }
  }
  __syncthreads();

  {
    bf16x8 bf[4][2];
    #pragma unroll
    for (int nt = 0; nt < 4; ++nt)
      #pragma unroll
      for (int kk = 0; kk < 2; ++kk)
        bf[nt][kk] = *(const bf16x8*)(wB2t + (nt * 16 + li) * 64 + kk * 32 + quad * 8);
    #pragma unroll
    for (int mi = 0; mi < 2; ++mi) {
      const int mt = w * 2 + mi;
      bf16x8 a0 = *(const bf16x8*)(actA + (mt * 16 + li) * APAD + quad * 8);
      bf16x8 a1 = *(const bf16x8*)(actA + (mt * 16 + li) * APAD + 32 + quad * 8);
      #pragma unroll
      for (int nt = 0; nt < 4; ++nt) {
        f32x4 d = __builtin_amdgcn_mfma_f32_16x16x32_bf16(a0, bf[nt][0], zc, 0, 0, 0);
        d = __builtin_amdgcn_mfma_f32_16x16x32_bf16(a1, bf[nt][1], d, 0, 0, 0);
        #pragma unroll
        for (int r = 0; r < 4; ++r)
          actB[(mt * 16 + quad * 4 + r) * APAD + nt * 16 + li] = f2bf(fmaxf(d[r] + b2c[nt], 0.f));
      }
    }
  }
  __syncthreads();

  {
    bf16x8 bf[4][2];
    #pragma unroll
    for (int nt = 0; nt < 4; ++nt)
      #pragma unroll
      for (int kk = 0; kk < 2; ++kk)
        bf[nt][kk] = *(const bf16x8*)(wB3t + (nt * 16 + li) * 64 + kk * 32 + quad * 8);
    #pragma unroll
    for (int mi = 0; mi < 2; ++mi) {
      const int mt = w * 2 + mi;
      bf16x8 a0 = *(const bf16x8*)(actB + (mt * 16 + li) * APAD + quad * 8);
      bf16x8 a1 = *(const bf16x8*)(actB + (mt * 16 + li) * APAD + 32 + quad * 8);
      #pragma unroll
      for (int nt = 0; nt < 4; ++nt) {
        f32x4 d = __builtin_amdgcn_mfma_f32_16x16x32_bf16(a0, bf[nt][0], zc, 0, 0, 0);
        d = __builtin_amdgcn_mfma_f32_16x16x32_bf16(a1, bf[nt][1], d, 0, 0, 0);
        #pragma unroll
        for (int r = 0; r < 4; ++r)
          actA[(mt * 16 + quad * 4 + r) * APAD + nt * 16 + li] = f2bf(fmaxf(d[r] + b3c[nt], 0.f));
      }
    }
  }
  __syncthreads();

  #pragma unroll
  for (int it = 0; it < 4; ++it) {
    int flat = it * 2048 + t * 8;
    int el = flat >> 6, c = flat & 63;
    int pos = e2p[e0 + el];
    pos = ((unsigned)pos <= (unsigned)(NE - 1)) ? pos : NE;
    uint4 v = *(const uint4*)(actA + el * APAD + c);
    *(uint4*)(e3g + (size_t)pos * 64 + c) = v;
  }
}

// ---------------- attention gather: sequential e3 (CSR order) ----------------
__global__ __launch_bounds__(256) void k_attn(
    const int* __restrict__ rowptr, const int* __restrict__ slist,
    u16* yo, const u16* __restrict__ x1g, u16* gz, const u16* __restrict__ Qkg,
    const u16* __restrict__ e3g, float* __restrict__ bfac) {
  const int t = threadIdx.x;
  const int w = t >> 6;
  const int l = t & 63;
  const int grp = l >> 4;
  const int li = l & 15;
  const int chb = grp * 64 + li * 4;
  const int n = blockIdx.x * 4 + w;
  int base = rowptr[n];
  int end  = rowptr[n + 1];
  base = max(0, min(base, NE));
  end  = max(base, min(end, NE));
  if (l == 0) bfac[n] = (end > base) ? 1.f : 0.f;

  float Qkf[4], Gf[4];
  {
    ushort4 kv = *(const ushort4*)(Qkg + (size_t)n * 256 + chb);
    Qkf[0] = bf2f(kv.x); Qkf[1] = bf2f(kv.y); Qkf[2] = bf2f(kv.z); Qkf[3] = bf2f(kv.w);
    ushort4 gv = *(const ushort4*)(gz + (size_t)n * 256 + chb);
    Gf[0] = bf2f(gv.x); Gf[1] = bf2f(gv.y); Gf[2] = bf2f(gv.z); Gf[3] = bf2f(gv.w);
  }

  float s_run = 0.f;
  float y[4] = {0, 0, 0, 0}, zz[4] = {0, 0, 0, 0};
  int d = base;
  for (; d + 1 < end; d += 2) {
    int src0 = slist[d], src1 = slist[d + 1];
    src0 = max(0, min(src0, NN - 1)); src1 = max(0, min(src1, NN - 1));
    ushort4 x0 = *(const ushort4*)(x1g + (size_t)src0 * 64 + li * 4);
    ushort4 e0 = *(const ushort4*)(e3g + (size_t)d * 64 + li * 4);
    ushort4 x1v = *(const ushort4*)(x1g + (size_t)src1 * 64 + li * 4);
    ushort4 e1 = *(const ushort4*)(e3g + (size_t)(d + 1) * 64 + li * 4);
    float xf00 = bf2f(x0.x), xf01 = bf2f(x0.y), xf02 = bf2f(x0.z), xf03 = bf2f(x0.w);
    float ef00 = bf2f(e0.x), ef01 = bf2f(e0.y), ef02 = bf2f(e0.z), ef03 = bf2f(e0.w);
    float xf10 = bf2f(x1v.x), xf11 = bf2f(x1v.y), xf12 = bf2f(x1v.z), xf13 = bf2f(x1v.w);
    float ef10 = bf2f(e1.x), ef11 = bf2f(e1.y), ef12 = bf2f(e1.z), ef13 = bf2f(e1.w);
    float p0 = Qkf[0]*xf00 + Qkf[1]*xf01 + Qkf[2]*xf02 + Qkf[3]*xf03
             + Gf[0]*ef00 + Gf[1]*ef01 + Gf[2]*ef02 + Gf[3]*ef03;
    float p1 = Qkf[0]*xf10 + Qkf[1]*xf11 + Qkf[2]*xf12 + Qkf[3]*xf13
             + Gf[0]*ef10 + Gf[1]*ef11 + Gf[2]*ef12 + Gf[3]*ef13;
    #pragma unroll
    for (int mk = 1; mk < 16; mk <<= 1) { p0 += __shfl_xor(p0, mk); p1 += __shfl_xor(p1, mk); }
    float w0 = __expf(fminf(p0 * 0.125f, 60.f));
    float w1 = __expf(fminf(p1 * 0.125f, 60.f));
    s_run += w0 + w1;
    y[0] += w0*xf00 + w1*xf10; y[1] += w0*xf01 + w1*xf11;
    y[2] += w0*xf02 + w1*xf12; y[3] += w0*xf03 + w1*xf13;
    zz[0] += w0*ef00 + w1*ef10; zz[1] += w0*ef01 + w1*ef11;
    zz[2] += w0*ef02 + w1*ef12; zz[3] += w0*ef03 + w1*ef13;
  }
  if (d < end) {
    int src0 = slist[d];
    src0 = max(0, min(src0, NN - 1));
    ushort4 x0 = *(const ushort4*)(x1g + (size_t)src0 * 64 + li * 4);
    ushort4 e0 = *(const ushort4*)(e3g + (size_t)d * 64 + li * 4);
    float xf00 = bf2f(x0.x), xf01 = bf2f(x0.y), xf02 = bf2f(x0.z), xf03 = bf2f(x0.w);
    float ef00 = bf2f(e0.x), ef01 = bf2f(e0.y), ef02 = bf2f(e0.z), ef03 = bf2f(e0.w);
    float p0 = Qkf[0]*xf00 + Qkf[1]*xf01 + Qkf[2]*xf02 + Qkf[3]*xf03
             + Gf[0]*ef00 + Gf[1]*ef01 + Gf[2]*ef02 + Gf[3]*ef03;
    #pragma unroll
    for (int mk = 1; mk < 16; mk <<= 1) p0 += __shfl_xor(p0, mk);
    float w0 = __expf(fminf(p0 * 0.125f, 60.f));
    s_run += w0;
    y[0] += w0*xf00; y[1] += w0*xf01; y[2] += w0*xf02; y[3] += w0*xf03;
    zz[0] += w0*ef00; zz[1] += w0*ef01; zz[2] += w0*ef02; zz[3] += w0*ef03;
  }
  const float inv_s = 1.0f / (s_run + 1e-16f);
  ushort4 ynv, znv;
  ynv.x = f2bf(y[0] * inv_s); ynv.y = f2bf(y[1] * inv_s);
  ynv.z = f2bf(y[2] * inv_s); ynv.w = f2bf(y[3] * inv_s);
  znv.x = f2bf(zz[0] * inv_s); znv.y = f2bf(zz[1] * inv_s);
  znv.z = f2bf(zz[2] * inv_s); znv.w = f2bf(zz[3] * inv_s);
  *(ushort4*)(yo + (size_t)n * 256 + chb) = ynv;
  *(ushort4*)(gz + (size_t)n * 256 + chb) = znv;
}

// ---------------- post via MFMA ----------------
#define PM 64
#define PK 576
#define PAPAD 584
__global__ __launch_bounds__(256) void k_post(
    const u16* __restrict__ zng, const u16* __restrict__ yng, const u16* __restrict__ x1g,
    const u16* __restrict__ Bt, const float* __restrict__ bfac,
    const float* __restrict__ bedge, const float* __restrict__ bv, const float* __restrict__ bskip,
    const float* __restrict__ lng, const float* __restrict__ lnb,
    u16* __restrict__ postg) {
  __shared__ u16 As[PM * PAPAD];
  __shared__ float ps1[PM * 4];
  __shared__ float ps2[PM * 4];
  const int t = threadIdx.x;
  const int w = t >> 6, l = t & 63;
  const int quad = l >> 4, li = l & 15;
  const int n0 = blockIdx.x * PM;

  for (int q = t; q < 2048; q += 256) {
    int row = q >> 5, off = (q & 31) * 8;
    uint4 vz = make_uint4(0, 0, 0, 0), vy = make_uint4(0, 0, 0, 0);
    if (n0 + row < NN) {
      vz = *(const uint4*)(zng + (size_t)(n0 + row) * 256 + off);
      vy = *(const uint4*)(yng + (size_t)(n0 + row) * 256 + off);
    }
    *(uint4*)(As + row * PAPAD + off) = vz;
    *(uint4*)(As + row * PAPAD + 256 + off) = vy;
  }
  for (int q = t; q < 512; q += 256) {
    int row = q >> 3, off = (q & 7) * 8;
    uint4 v = make_uint4(0, 0, 0, 0);
    if (n0 + row < NN) v = *(const uint4*)(x1g + (size_t)(n0 + row) * 64 + off);
    *(uint4*)(As + row * PAPAD + 512 + off) = v;
  }
  __syncthreads();

  f32x4 acc[4][4];
  #pragma unroll
  for (int mt = 0; mt < 4; ++mt)
    #pragma unroll
    for (int nt = 0; nt < 4; ++nt) acc[mt][nt] = (f32x4){0.f, 0.f, 0.f, 0.f};

  const int colbase = w * 64;
  #pragma unroll
  for (int s = 0; s < 18; ++s) {
    bf16x8 bf[4];
    #pragma unroll
    for (int nt = 0; nt < 4; ++nt)
      bf[nt] = *(const bf16x8*)(Bt + (size_t)(colbase + nt * 16 + li) * PK + s * 32 + quad * 8);
    #pragma unroll
    for (int mt = 0; mt < 4; ++mt) {
      bf16x8 af = *(const bf16x8*)(As + (mt * 16 + li) * PAPAD + s * 32 + quad * 8);
      #pragma unroll
      for (int nt = 0; nt < 4; ++nt)
        acc[mt][nt] = __builtin_amdgcn_mfma_f32_16x16x32_bf16(af, bf[nt], acc[mt][nt], 0, 0, 0);
    }
  }

  float beb[4], bs4[4], g4[4], lb4[4];
  #pragma unroll
  for (int nt = 0; nt < 4; ++nt) {
    int col = colbase + nt * 16 + li;
    beb[nt] = bedge[col] + bv[col];
    bs4[nt] = bskip[col]; g4[nt] = lng[col]; lb4[nt] = lnb[col];
  }
  #pragma unroll
  for (int mt = 0; mt < 4; ++mt) {
    #pragma unroll
    for (int r = 0; r < 4; ++r) {
      int node = n0 + mt * 16 + quad * 4 + r;
      float hasE = bfac[min(node, NN - 1)];
      #pragma unroll
      for (int nt = 0; nt < 4; ++nt)
        acc[mt][nt][r] += hasE * beb[nt] + bs4[nt];
    }
  }
  #pragma unroll
  for (int mt = 0; mt < 4; ++mt)
    #pragma unroll
    for (int r = 0; r < 4; ++r) {
      float s = acc[mt][0][r] + acc[mt][1][r] + acc[mt][2][r] + acc[mt][3][r];
      #pragma unroll
      for (int mk = 1; mk < 16; mk <<= 1) s += __shfl_xor(s, mk);
      if (li == 0) ps1[(mt * 16 + quad * 4 + r) * 4 + w] = s;
    }
  __syncthreads();
  float mu[4][4];
  #pragma unroll
  for (int mt = 0; mt < 4; ++mt)
    #pragma unroll
    for (int r = 0; r < 4; ++r) {
      float4 p = *(const float4*)(ps1 + (mt * 16 + quad * 4 + r) * 4);
      mu[mt][r] = (p.x + p.y + p.z + p.w) * (1.0f / 256.0f);
    }
  #pragma unroll
  for (int mt = 0; mt < 4; ++mt)
    #pragma unroll
    for (int r = 0; r < 4; ++r) {
      float m = mu[mt][r];
      float s = 0.f;
      #pragma unroll
      for (int nt = 0; nt < 4; ++nt) { float dd = acc[mt][nt][r] - m; s += dd * dd; }
      #pragma unroll
      for (int mk = 1; mk < 16; mk <<= 1) s += __shfl_xor(s, mk);
      if (li == 0) ps2[(mt * 16 + quad * 4 + r) * 4 + w] = s;
    }
  __syncthreads();
  #pragma unroll
  for (int mt = 0; mt < 4; ++mt)
    #pragma unroll
    for (int r = 0; r < 4; ++r) {
      float4 p = *(const float4*)(ps2 + (mt * 16 + quad * 4 + r) * 4);
      float rstd = rsqrtf((p.x + p.y + p.z + p.w) * (1.0f / 256.0f) + 1e-5f);
      int node = n0 + mt * 16 + quad * 4 + r;
      if (node < NN) {
        float m = mu[mt][r];
        #pragma unroll
        for (int nt = 0; nt < 4; ++nt) {
          int col = colbase + nt * 16 + li;
          postg[(size_t)node * 256 + col] =
              f2bf(fmaxf((acc[mt][nt][r] - m) * rstd * g4[nt] + lb4[nt], 0.f));
        }
      }
    }
}

// ---------------- head via MFMA ----------------
#define HAPAD 264
#define H1PAD 136
__global__ __launch_bounds__(256) void k_head(
    const u16* __restrict__ postg, const u16* __restrict__ Bt1,
    const float* __restrict__ b1, const float* __restrict__ w2, const float* __restrict__ b2,
    float* __restrict__ outg) {
  __shared__ u16 As[64 * HAPAD];
  __shared__ u16 h1s[64 * H1PAD];
  const int t = threadIdx.x;
  const int w = t >> 6, l = t & 63;
  const int quad = l >> 4, li = l & 15;
  const int n0 = blockIdx.x * 64;

  for (int q = t; q < 2048; q += 256) {
    int row = q >> 5, off = (q & 31) * 8;
    uint4 v = make_uint4(0, 0, 0, 0);
    if (n0 + row < NN) v = *(const uint4*)(postg + (size_t)(n0 + row) * 256 + off);
    *(uint4*)(As + row * HAPAD + off) = v;
  }
  __syncthreads();

  f32x4 acc[4][2];
  #pragma unroll
  for (int mt = 0; mt < 4; ++mt)
    #pragma unroll
    for (int nt = 0; nt < 2; ++nt) acc[mt][nt] = (f32x4){0.f, 0.f, 0.f, 0.f};
  const int colbase = w * 32;
  #pragma unroll
  for (int s = 0; s < 8; ++s) {
    bf16x8 bf[2];
    #pragma unroll
    for (int nt = 0; nt < 2; ++nt)
      bf[nt] = *(const bf16x8*)(Bt1 + (size_t)(colbase + nt * 16 + li) * 256 + s * 32 + quad * 8);
    #pragma unroll
    for (int mt = 0; mt < 4; ++mt) {
      bf16x8 af = *(const bf16x8*)(As + (mt * 16 + li) * HAPAD + s * 32 + quad * 8);
      #pragma unroll
      for (int nt = 0; nt < 2; ++nt)
        acc[mt][nt] = __builtin_amdgcn_mfma_f32_16x16x32_bf16(af, bf[nt], acc[mt][nt], 0, 0, 0);
    }
  }
  float b1c[2];
  #pragma unroll
  for (int nt = 0; nt < 2; ++nt) b1c[nt] = b1[colbase + nt * 16 + li];
  #pragma unroll
  for (int mt = 0; mt < 4; ++mt)
    #pragma unroll
    for (int nt = 0; nt < 2; ++nt)
      #pragma unroll
      for (int r = 0; r < 4; ++r)
        h1s[(mt * 16 + quad * 4 + r) * H1PAD + colbase + nt * 16 + li] =
            f2bf(fmaxf(acc[mt][nt][r] + b1c[nt], 0.f));
  __syncthreads();

  const int node = t >> 2, c = t & 3;
  float lg = b2[c];
  const u16* hrow = h1s + node * H1PAD;
  #pragma unroll 4
  for (int j = 0; j < 128; ++j) lg += bf2f(hrow[j]) * w2[j * 4 + c];
  float mx = lg;
  #pragma unroll
  for (int mk = 1; mk < 4; mk <<= 1) mx = fmaxf(mx, __shfl_xor(mx, mk));
  float ex = __expf(lg - mx);
  float se = ex;
  #pragma unroll
  for (int mk = 1; mk < 4; mk <<= 1) se += __shfl_xor(se, mk);
  float res = lg - (mx + __logf(se));
  if (n0 + node < NN) outg[(size_t)(n0 + node) * 4 + c] = res;
}

extern "C" void kernel_launch(void* const* d_in, const int* in_sizes, int n_in,
                              void* d_out, int out_size, void* d_ws, size_t ws_size,
                              hipStream_t stream) {
  const float* x     = (const float*)d_in[0];
  const int*   ei    = (const int*)d_in[1];
  const float* ea    = (const float*)d_in[2];
  const float* w00   = (const float*)d_in[3];
  const float* b00   = (const float*)d_in[4];
  const float* we1   = (const float*)d_in[5];
  const float* be1   = (const float*)d_in[6];
  const float* we2   = (const float*)d_in[7];
  const float* be2   = (const float*)d_in[8];
  const float* we3   = (const float*)d_in[9];
  const float* be3   = (const float*)d_in[10];
  const float* wq    = (const float*)d_in[11];
  const float* bq    = (const float*)d_in[12];
  const float* wk    = (const float*)d_in[13];
  const float* bk    = (const float*)d_in[14];
  const float* wv    = (const float*)d_in[15];
  const float* bv    = (const float*)d_in[16];
  const float* wedge = (const float*)d_in[17];
  const float* bedge = (const float*)d_in[18];
  const float* wskip = (const float*)d_in[19];
  const float* bskip = (const float*)d_in[20];
  const float* lng   = (const float*)d_in[21];
  const float* lnb   = (const float*)d_in[22];
  const float* w1    = (const float*)d_in[23];
  const float* b1    = (const float*)d_in[24];
  const float* w2    = (const float*)d_in[25];
  const float* b2    = (const float*)d_in[26];
  float* outg = (float*)d_out;
  (void)bk;

  size_t off = 0;
  char* wsb = (char*)d_ws;
  auto carve = [&](size_t bytes) -> char* {
    char* r = wsb + off;
    off += (bytes + 255) & ~(size_t)255;
    return r;
  };
  u16* yg     = (u16*)carve((size_t)NN * 256 * 2);      // yn
  u16* Gg     = (u16*)carve((size_t)NN * 256 * 2);      // G -> zn
  u16* Qkg    = (u16*)carve((size_t)NN * 256 * 2);      // Qk
  u16* x1g    = (u16*)carve((size_t)NN * 64 * 2);
  u16* e3g    = (u16*)carve((size_t)(NE + 1) * 64 * 2); // e3 in CSR order (+1 scratch row)
  int* deg    = (int*)carve((size_t)NN * 4);
  int* rowptr = (int*)carve((size_t)(NN + 1) * 4);
  int* cursor = (int*)carve((size_t)NN * 4);
  int* slist  = (int*)carve((size_t)NE * 4);
  int* e2p    = (int*)carve((size_t)NE * 4);
  float* bfac = (float*)carve((size_t)NN * 4);
  int* bsum   = (int*)carve((size_t)SCAN_NB * 4);
  int* boff   = (int*)carve((size_t)SCAN_NB * 4);
  u16* wB00t  = (u16*)carve(2048 * 2);
  u16* wqt    = (u16*)carve(16384 * 2);
  u16* BGQ    = (u16*)carve((size_t)131072 * 2);
  u16* wB1t   = (u16*)carve(512 * 2);
  u16* wB2t   = (u16*)carve(4096 * 2);
  u16* wB3t   = (u16*)carve(4096 * 2);
  u16* Bt     = (u16*)carve((size_t)256 * 576 * 2);
  u16* Bt1    = (u16*)carve((size_t)128 * 256 * 2);
  u16* postg  = e3g;   // e3g dead after k_attn
  if (off > ws_size) return;

  k_prep_ng<<<584, 256, 0, stream>>>(w00, wq, wedge, wk, wB00t, wqt, BGQ);
  k_prep_w<<<34, 256, 0, stream>>>(we1, we2, we3, wB1t, wB2t, wB3t);
  k_prep_b<<<256, 576, 0, stream>>>(wedge, wv, wskip, Bt);
  k_prep_h<<<128, 256, 0, stream>>>(w1, Bt1);
  k_zero<<<SCAN_NB, 256, 0, stream>>>(deg);
  k_hist<<<NE / 256, 256, 0, stream>>>(ei, deg);
  k_scan_a<<<SCAN_NB, 256, 0, stream>>>(deg, bsum);
  k_scan_b<<<1, 256, 0, stream>>>(bsum, boff, rowptr);
  k_scan_c<<<SCAN_NB, 256, 0, stream>>>(deg, boff, rowptr, cursor);
  k_scatter<<<NE / 256, 256, 0, stream>>>(ei, cursor, slist, e2p);
  k_ng<<<(NN + 63) / 64, 256, 0, stream>>>(x, wB00t, b00, wqt, bq, BGQ, x1g, Gg, Qkg);
  k_edge_mlp<<<NE / EPB, 256, 0, stream>>>(ea, wB1t, wB2t, wB3t, be1, be2, be3, e2p, e3g);
  k_attn<<<NN / 4, 256, 0, stream>>>(rowptr, slist, yg, x1g, Gg, Qkg, e3g, bfac);
  k_post<<<(NN + PM - 1) / PM, 256, 0, stream>>>(Gg, yg, x1g, Bt, bfac, bedge, bv, bskip,
                                                 lng, lnb, postg);
  k_head<<<(NN + 63) / 64, 256, 0, stream>>>(postg, Bt1, b1, w2, b2, outg);
}

// Round 12
// 473.734 us; speedup vs baseline: 2.5144x; 1.0533x over previous
//
#include <hip/hip_runtime.h>
#include <hip/hip_bf16.h>

typedef unsigned short u16;
typedef __attribute__((ext_vector_type(8))) short bf16x8;
typedef __attribute__((ext_vector_type(4))) float f32x4;

#define NN 50000
#define NE 800000
#define SCAN_NB ((NN + 255) / 256)

__device__ __forceinline__ float bf2f(u16 u) { return __uint_as_float(((unsigned)u) << 16); }
__device__ __forceinline__ u16 f2bf(float f) {
  unsigned u = __float_as_uint(f);
  return (u16)((u + 0x7FFFu + ((u >> 16) & 1u)) >> 16);
}

// ---------------- CSR build ----------------
__global__ void k_hist(const int* __restrict__ ei, int* __restrict__ deg) {
  int i = blockIdx.x * 256 + threadIdx.x;
  if (i < NE) {
    int d = ei[NE + i];
    if (d >= 0 && d < NN) atomicAdd(&deg[d], 1);
  }
}

__global__ __launch_bounds__(256) void k_scan_a(const int* __restrict__ deg,
                                                int* __restrict__ bsum) {
  __shared__ int red[256];
  const int t = threadIdx.x;
  const int i = blockIdx.x * 256 + t;
  red[t] = (i < NN) ? deg[i] : 0;
  __syncthreads();
  #pragma unroll
  for (int s = 128; s > 0; s >>= 1) {
    if (t < s) red[t] += red[t + s];
    __syncthreads();
  }
  if (t == 0) bsum[blockIdx.x] = red[0];
}

__global__ __launch_bounds__(256) void k_scan_b(const int* __restrict__ bsum,
                                                int* __restrict__ boff,
                                                int* __restrict__ rowptr) {
  __shared__ int s[256];
  const int t = threadIdx.x;
  int v = (t < SCAN_NB) ? bsum[t] : 0;
  s[t] = v;
  __syncthreads();
  #pragma unroll
  for (int o = 1; o < 256; o <<= 1) {
    int u = (t >= o) ? s[t - o] : 0;
    __syncthreads();
    s[t] += u;
    __syncthreads();
  }
  if (t < SCAN_NB) boff[t] = s[t] - v;
  if (t == 255) rowptr[NN] = s[255];
}

__global__ __launch_bounds__(256) void k_scan_c(const int* __restrict__ deg,
                                                const int* __restrict__ boff,
                                                int* __restrict__ rowptr,
                                                int* __restrict__ cursor) {
  __shared__ int s[256];
  const int t = threadIdx.x;
  const int i = blockIdx.x * 256 + t;
  int v = (i < NN) ? deg[i] : 0;
  s[t] = v;
  __syncthreads();
  #pragma unroll
  for (int o = 1; o < 256; o <<= 1) {
    int u = (t >= o) ? s[t - o] : 0;
    __syncthreads();
    s[t] += u;
    __syncthreads();
  }
  if (i < NN) {
    int r = boff[blockIdx.x] + s[t] - v;
    rowptr[i] = r;
    cursor[i] = r;
  }
}

__global__ void k_scatter(const int* __restrict__ ei, int* __restrict__ cursor,
                          int* __restrict__ slist, int* __restrict__ e2p) {
  int i = blockIdx.x * 256 + threadIdx.x;
  if (i < NE) {
    int d = ei[NE + i];
    if (d >= 0 && d < NN) {
      int pos = atomicAdd(&cursor[d], 1);
      if (pos >= 0 && pos < NE) {
        e2p[i] = pos;
        int s = ei[i];
        slist[pos] = max(0, min(s, NN - 1));
      }
    }
  }
}

// ---------------- merged weight prep + deg zero ----------------
// segments: wB00t 2048 | wqt 16384 | BGQ 131072 | wB1t 512 | wB2t 4096 | wB3t 4096
//         | Bt 147456 | Bt1 32768 | deg 50000   -> total 388432
#define PREP_TOTAL 388432
__global__ void k_prep_all(
    const float* __restrict__ w00, const float* __restrict__ wq,
    const float* __restrict__ wedge, const float* __restrict__ wk,
    const float* __restrict__ we1, const float* __restrict__ we2, const float* __restrict__ we3,
    const float* __restrict__ wv, const float* __restrict__ wskip, const float* __restrict__ w1,
    u16* __restrict__ wB00t, u16* __restrict__ wqt, u16* __restrict__ BGQ,
    u16* __restrict__ wB1t, u16* __restrict__ wB2t, u16* __restrict__ wB3t,
    u16* __restrict__ Bt, u16* __restrict__ Bt1, int* __restrict__ deg) {
  int i = blockIdx.x * 256 + threadIdx.x;
  if (i < 2048) {
    int n = i >> 5, k = i & 31;
    wB00t[i] = (k < 16) ? f2bf(w00[k * 64 + n]) : (u16)0;
  } else if (i < 18432) {
    int i2 = i - 2048;
    int n = i2 >> 6, k = i2 & 63;
    wqt[i2] = f2bf(wq[k * 256 + n]);
  } else if (i < 149504) {
    int i2 = i - 18432;
    int col = i2 >> 8, k = i2 & 255;
    float v;
    if (col < 256) v = ((k >> 6) == (col >> 6)) ? wedge[(col & 63) * 256 + k] : 0.f;
    else { int c = col - 256; v = ((k >> 6) == (c >> 6)) ? wk[(c & 63) * 256 + k] : 0.f; }
    BGQ[i2] = f2bf(v);
  } else if (i < 150016) {
    int i2 = i - 149504;
    int n = i2 >> 3, k = i2 & 7;
    wB1t[i2] = f2bf(we1[k * 64 + n]);
  } else if (i < 154112) {
    int i2 = i - 150016;
    int n = i2 >> 6, k = i2 & 63;
    wB2t[i2] = f2bf(we2[k * 64 + n]);
  } else if (i < 158208) {
    int i2 = i - 154112;
    int n = i2 >> 6, k = i2 & 63;
    wB3t[i2] = f2bf(we3[k * 64 + n]);
  } else if (i < 305664) {
    int i2 = i - 158208;
    int col = i2 / 576, k = i2 - col * 576;
    float v;
    if (k < 256) v = ((k >> 6) == (col >> 6)) ? wedge[(k & 63) * 256 + col] : 0.f;
    else if (k < 512) { int k2 = k - 256; v = ((k2 >> 6) == (col >> 6)) ? wv[(k2 & 63) * 256 + col] : 0.f; }
    else v = wskip[(k - 512) * 256 + col];
    Bt[i2] = f2bf(v);
  } else if (i < 338432) {
    int i2 = i - 305664;
    int col = i2 >> 8, k = i2 & 255;
    Bt1[i2] = f2bf(w1[k * 128 + col]);
  } else if (i < PREP_TOTAL) {
    deg[i - 338432] = 0;
  }
}

// ---------------- node chain via MFMA: x -> x1 -> q -> {G, Qk} ----------------
__global__ __launch_bounds__(256) void k_ng(
    const float* __restrict__ x, const u16* __restrict__ wB00t, const float* __restrict__ b00,
    const u16* __restrict__ wqt, const float* __restrict__ bq,
    const u16* __restrict__ BGQ,
    u16* __restrict__ x1g, u16* __restrict__ Gg, u16* __restrict__ Qkg) {
  __shared__ u16 xs[64 * 32];
  __shared__ u16 x1s[64 * 72];
  __shared__ u16 qs[64 * 264];
  const int t = threadIdx.x;
  const int w = t >> 6, l = t & 63;
  const int quad = l >> 4, li = l & 15;
  const int n0 = blockIdx.x * 64;
  const f32x4 zc = {0.f, 0.f, 0.f, 0.f};

  for (int q = t; q < 2048; q += 256) {
    int row = q >> 5, k = q & 31;
    float v = (k < 16 && n0 + row < NN) ? x[(size_t)(n0 + row) * 16 + k] : 0.f;
    xs[row * 32 + k] = f2bf(v);
  }
  __syncthreads();

  {
    bf16x8 bf = *(const bf16x8*)(wB00t + (w * 16 + li) * 32 + quad * 8);
    float bc = b00[w * 16 + li];
    #pragma unroll
    for (int mt = 0; mt < 4; ++mt) {
      bf16x8 af = *(const bf16x8*)(xs + (mt * 16 + li) * 32 + quad * 8);
      f32x4 d = __builtin_amdgcn_mfma_f32_16x16x32_bf16(af, bf, zc, 0, 0, 0);
      #pragma unroll
      for (int r = 0; r < 4; ++r)
        x1s[(mt * 16 + quad * 4 + r) * 72 + w * 16 + li] = f2bf(fmaxf(d[r] + bc, 0.f));
    }
  }
  __syncthreads();

  #pragma unroll
  for (int it = 0; it < 2; ++it) {
    int i = (it * 256 + t) * 8;
    int row = i >> 6, col = i & 63;
    if (n0 + row < NN)
      *(uint4*)(x1g + (size_t)(n0 + row) * 64 + col) = *(const uint4*)(x1s + row * 72 + col);
  }

  {
    f32x4 acc[4][4];
    #pragma unroll
    for (int mt = 0; mt < 4; ++mt)
      #pragma unroll
      for (int nt = 0; nt < 4; ++nt) acc[mt][nt] = zc;
    const int colbase = w * 64;
    #pragma unroll
    for (int s = 0; s < 2; ++s) {
      bf16x8 bf[4];
      #pragma unroll
      for (int nt = 0; nt < 4; ++nt)
        bf[nt] = *(const bf16x8*)(wqt + (size_t)(colbase + nt * 16 + li) * 64 + s * 32 + quad * 8);
      #pragma unroll
      for (int mt = 0; mt < 4; ++mt) {
        bf16x8 af = *(const bf16x8*)(x1s + (mt * 16 + li) * 72 + s * 32 + quad * 8);
        #pragma unroll
        for (int nt = 0; nt < 4; ++nt)
          acc[mt][nt] = __builtin_amdgcn_mfma_f32_16x16x32_bf16(af, bf[nt], acc[mt][nt], 0, 0, 0);
      }
    }
    float bqc[4];
    #pragma unroll
    for (int nt = 0; nt < 4; ++nt) bqc[nt] = bq[colbase + nt * 16 + li];
    #pragma unroll
    for (int mt = 0; mt < 4; ++mt)
      #pragma unroll
      for (int nt = 0; nt < 4; ++nt)
        #pragma unroll
        for (int r = 0; r < 4; ++r)
          qs[(mt * 16 + quad * 4 + r) * 264 + colbase + nt * 16 + li] = f2bf(acc[mt][nt][r] + bqc[nt]);
  }
  __syncthreads();

  #pragma unroll
  for (int half = 0; half < 2; ++half) {
    f32x4 acc[4][4];
    #pragma unroll
    for (int mt = 0; mt < 4; ++mt)
      #pragma unroll
      for (int nt = 0; nt < 4; ++nt) acc[mt][nt] = zc;
    const int colbase = w * 64;
    const size_t bofs = (size_t)(half * 256) * 256;
    #pragma unroll
    for (int s = 0; s < 8; ++s) {
      bf16x8 bf[4];
      #pragma unroll
      for (int nt = 0; nt < 4; ++nt)
        bf[nt] = *(const bf16x8*)(BGQ + bofs + (size_t)(colbase + nt * 16 + li) * 256 + s * 32 + quad * 8);
      #pragma unroll
      for (int mt = 0; mt < 4; ++mt) {
        bf16x8 af = *(const bf16x8*)(qs + (mt * 16 + li) * 264 + s * 32 + quad * 8);
        #pragma unroll
        for (int nt = 0; nt < 4; ++nt)
          acc[mt][nt] = __builtin_amdgcn_mfma_f32_16x16x32_bf16(af, bf[nt], acc[mt][nt], 0, 0, 0);
      }
    }
    u16* dst = half ? Qkg : Gg;
    #pragma unroll
    for (int mt = 0; mt < 4; ++mt)
      #pragma unroll
      for (int r = 0; r < 4; ++r) {
        int node = n0 + mt * 16 + quad * 4 + r;
        if (node < NN) {
          #pragma unroll
          for (int nt = 0; nt < 4; ++nt)
            dst[(size_t)node * 256 + colbase + nt * 16 + li] = f2bf(acc[mt][nt][r]);
        }
      }
  }
}

// ---------------- edge MLP via MFMA bf16, output scattered to CSR order ----------------
#define EPB 128
#define APAD 72
__global__ __launch_bounds__(256) void k_edge_mlp(
    const float* __restrict__ ea,
    const u16* __restrict__ wB1t, const u16* __restrict__ wB2t, const u16* __restrict__ wB3t,
    const float* __restrict__ be1, const float* __restrict__ be2, const float* __restrict__ be3,
    const int* __restrict__ e2p, u16* __restrict__ e3g) {
  __shared__ u16 actA[EPB * APAD];
  __shared__ u16 actB[EPB * APAD];
  const int t = threadIdx.x;
  const int w = t >> 6, l = t & 63;
  const int quad = l >> 4, li = l & 15;
  const int e0 = blockIdx.x * EPB;
  const f32x4 zc = {0.f, 0.f, 0.f, 0.f};

  float b1c[4], b2c[4], b3c[4];
  #pragma unroll
  for (int nt = 0; nt < 4; ++nt) {
    b1c[nt] = be1[nt * 16 + li];
    b2c[nt] = be2[nt * 16 + li];
    b3c[nt] = be3[nt * 16 + li];
  }

  bf16x8 b1f[4];
  #pragma unroll
  for (int nt = 0; nt < 4; ++nt) {
    bf16x8 z = {};
    if (quad == 0) z = *(const bf16x8*)(wB1t + (nt * 16 + li) * 8);
    b1f[nt] = z;
  }
  #pragma unroll
  for (int mi = 0; mi < 2; ++mi) {
    const int mt = w * 2 + mi;
    bf16x8 af = {};
    if (quad == 0) {
      const float4* pa = (const float4*)(ea + (size_t)(e0 + mt * 16 + li) * 8);
      float4 p0 = pa[0], p1 = pa[1];
      af[0] = (short)f2bf(p0.x); af[1] = (short)f2bf(p0.y);
      af[2] = (short)f2bf(p0.z); af[3] = (short)f2bf(p0.w);
      af[4] = (short)f2bf(p1.x); af[5] = (short)f2bf(p1.y);
      af[6] = (short)f2bf(p1.z); af[7] = (short)f2bf(p1.w);
    }
    #pragma unroll
    for (int nt = 0; nt < 4; ++nt) {
      f32x4 d = __builtin_amdgcn_mfma_f32_16x16x32_bf16(af, b1f[nt], zc, 0, 0, 0);
      #pragma unroll
      for (int r = 0; r < 4; ++r)
        actA[(mt * 16 + quad * 4 + r) * APAD + nt * 16 + li] = f2bf(fmaxf(d[r] + b1c[nt], 0.f));
    }
  }
  __syncthreads();

  {
    bf16x8 bf[4][2];
    #pragma unroll
    for (int nt = 0; nt < 4; ++nt)
      #pragma unroll
      for (int kk = 0; kk < 2; ++kk)
        bf[nt][kk] = *(const bf16x8*)(wB2t + (nt * 16 + li) * 64 + kk * 32 + quad * 8);
    #pragma unroll
    for (int mi = 0; mi < 2; ++mi) {
      const int mt = w * 2 + mi;
      bf16x8 a0 = *(const bf16x8*)(actA + (mt * 16 + li) * APAD + quad * 8);
      bf16x8 a1 = *(const bf16x8*)(actA + (mt * 16 + li) * APAD + 32 + quad * 8);
      #pragma unroll
      for (int nt = 0; nt < 4; ++nt) {
        f32x4 d = __builtin_amdgcn_mfma_f32_16x16x32_bf16(a0, bf[nt][0], zc, 0, 0, 0);
        d = __builtin_amdgcn_mfma_f32_16x16x32_bf16(a1, bf[nt][1], d, 0, 0, 0);
        #pragma unroll
        for (int r = 0; r < 4; ++r)
          actB[(mt * 16 + quad * 4 + r) * APAD + nt * 16 + li] = f2bf(fmaxf(d[r] + b2c[nt], 0.f));
      }
    }
  }
  __syncthreads();

  {
    bf16x8 bf[4][2];
    #pragma unroll
    for (int nt = 0; nt < 4; ++nt)
      #pragma unroll
      for (int kk = 0; kk < 2; ++kk)
        bf[nt][kk] = *(const bf16x8*)(wB3t + (nt * 16 + li) * 64 + kk * 32 + quad * 8);
    #pragma unroll
    for (int mi = 0; mi < 2; ++mi) {
      const int mt = w * 2 + mi;
      bf16x8 a0 = *(const bf16x8*)(actB + (mt * 16 + li) * APAD + quad * 8);
      bf16x8 a1 = *(const bf16x8*)(actB + (mt * 16 + li) * APAD + 32 + quad * 8);
      #pragma unroll
      for (int nt = 0; nt < 4; ++nt) {
        f32x4 d = __builtin_amdgcn_mfma_f32_16x16x32_bf16(a0, bf[nt][0], zc, 0, 0, 0);
        d = __builtin_amdgcn_mfma_f32_16x16x32_bf16(a1, bf[nt][1], d, 0, 0, 0);
        #pragma unroll
        for (int r = 0; r < 4; ++r)
          actA[(mt * 16 + quad * 4 + r) * APAD + nt * 16 + li] = f2bf(fmaxf(d[r] + b3c[nt], 0.f));
      }
    }
  }
  __syncthreads();

  #pragma unroll
  for (int it = 0; it < 4; ++it) {
    int flat = it * 2048 + t * 8;
    int el = flat >> 6, c = flat & 63;
    int pos = e2p[e0 + el];
    pos = ((unsigned)pos <= (unsigned)(NE - 1)) ? pos : NE;
    uint4 v = *(const uint4*)(actA + el * APAD + c);
    *(uint4*)(e3g + (size_t)pos * 64 + c) = v;
  }
}

// ---------------- attention gather: sequential e3 (CSR order), 4-edge unroll ----------------
__global__ __launch_bounds__(256) void k_attn(
    const int* __restrict__ rowptr, const int* __restrict__ slist,
    u16* yo, const u16* __restrict__ x1g, u16* gz, const u16* __restrict__ Qkg,
    const u16* __restrict__ e3g, float* __restrict__ bfac) {
  const int t = threadIdx.x;
  const int w = t >> 6;
  const int l = t & 63;
  const int grp = l >> 4;
  const int li = l & 15;
  const int chb = grp * 64 + li * 4;
  const int n = blockIdx.x * 4 + w;
  int base = rowptr[n];
  int end  = rowptr[n + 1];
  base = max(0, min(base, NE));
  end  = max(base, min(end, NE));
  if (l == 0) bfac[n] = (end > base) ? 1.f : 0.f;

  float Qkf[4], Gf[4];
  {
    ushort4 kv = *(const ushort4*)(Qkg + (size_t)n * 256 + chb);
    Qkf[0] = bf2f(kv.x); Qkf[1] = bf2f(kv.y); Qkf[2] = bf2f(kv.z); Qkf[3] = bf2f(kv.w);
    ushort4 gv = *(const ushort4*)(gz + (size_t)n * 256 + chb);
    Gf[0] = bf2f(gv.x); Gf[1] = bf2f(gv.y); Gf[2] = bf2f(gv.z); Gf[3] = bf2f(gv.w);
  }

  float s_run = 0.f;
  float y[4] = {0, 0, 0, 0}, zz[4] = {0, 0, 0, 0};
  int d = base;
  for (; d + 3 < end; d += 4) {
    int src[4];
    #pragma unroll
    for (int u = 0; u < 4; ++u) {
      int s = slist[d + u];
      src[u] = max(0, min(s, NN - 1));
    }
    ushort4 xv[4], ev[4];
    #pragma unroll
    for (int u = 0; u < 4; ++u) {
      xv[u] = *(const ushort4*)(x1g + (size_t)src[u] * 64 + li * 4);
      ev[u] = *(const ushort4*)(e3g + (size_t)(d + u) * 64 + li * 4);
    }
    float xf[4][4], ef[4][4], p[4];
    #pragma unroll
    for (int u = 0; u < 4; ++u) {
      xf[u][0] = bf2f(xv[u].x); xf[u][1] = bf2f(xv[u].y);
      xf[u][2] = bf2f(xv[u].z); xf[u][3] = bf2f(xv[u].w);
      ef[u][0] = bf2f(ev[u].x); ef[u][1] = bf2f(ev[u].y);
      ef[u][2] = bf2f(ev[u].z); ef[u][3] = bf2f(ev[u].w);
      p[u] = Qkf[0]*xf[u][0] + Qkf[1]*xf[u][1] + Qkf[2]*xf[u][2] + Qkf[3]*xf[u][3]
           + Gf[0]*ef[u][0] + Gf[1]*ef[u][1] + Gf[2]*ef[u][2] + Gf[3]*ef[u][3];
    }
    #pragma unroll
    for (int mk = 1; mk < 16; mk <<= 1) {
      p[0] += __shfl_xor(p[0], mk); p[1] += __shfl_xor(p[1], mk);
      p[2] += __shfl_xor(p[2], mk); p[3] += __shfl_xor(p[3], mk);
    }
    float wt[4];
    #pragma unroll
    for (int u = 0; u < 4; ++u) wt[u] = __expf(fminf(p[u] * 0.125f, 60.f));
    s_run += (wt[0] + wt[1]) + (wt[2] + wt[3]);
    #pragma unroll
    for (int u = 0; u < 4; ++u) {
      y[0] += wt[u]*xf[u][0]; y[1] += wt[u]*xf[u][1];
      y[2] += wt[u]*xf[u][2]; y[3] += wt[u]*xf[u][3];
      zz[0] += wt[u]*ef[u][0]; zz[1] += wt[u]*ef[u][1];
      zz[2] += wt[u]*ef[u][2]; zz[3] += wt[u]*ef[u][3];
    }
  }
  for (; d < end; ++d) {
    int src0 = slist[d];
    src0 = max(0, min(src0, NN - 1));
    ushort4 x0 = *(const ushort4*)(x1g + (size_t)src0 * 64 + li * 4);
    ushort4 e0 = *(const ushort4*)(e3g + (size_t)d * 64 + li * 4);
    float xf00 = bf2f(x0.x), xf01 = bf2f(x0.y), xf02 = bf2f(x0.z), xf03 = bf2f(x0.w);
    float ef00 = bf2f(e0.x), ef01 = bf2f(e0.y), ef02 = bf2f(e0.z), ef03 = bf2f(e0.w);
    float p0 = Qkf[0]*xf00 + Qkf[1]*xf01 + Qkf[2]*xf02 + Qkf[3]*xf03
             + Gf[0]*ef00 + Gf[1]*ef01 + Gf[2]*ef02 + Gf[3]*ef03;
    #pragma unroll
    for (int mk = 1; mk < 16; mk <<= 1) p0 += __shfl_xor(p0, mk);
    float w0 = __expf(fminf(p0 * 0.125f, 60.f));
    s_run += w0;
    y[0] += w0*xf00; y[1] += w0*xf01; y[2] += w0*xf02; y[3] += w0*xf03;
    zz[0] += w0*ef00; zz[1] += w0*ef01; zz[2] += w0*ef02; zz[3] += w0*ef03;
  }
  const float inv_s = 1.0f / (s_run + 1e-16f);
  ushort4 ynv, znv;
  ynv.x = f2bf(y[0] * inv_s); ynv.y = f2bf(y[1] * inv_s);
  ynv.z = f2bf(y[2] * inv_s); ynv.w = f2bf(y[3] * inv_s);
  znv.x = f2bf(zz[0] * inv_s); znv.y = f2bf(zz[1] * inv_s);
  znv.z = f2bf(zz[2] * inv_s); znv.w = f2bf(zz[3] * inv_s);
  *(ushort4*)(yo + (size_t)n * 256 + chb) = ynv;
  *(ushort4*)(gz + (size_t)n * 256 + chb) = znv;
}

// ---------------- fused post+head via MFMA ----------------
// post = LN(relu-in): out_node = [zn|yn|x1]@Bt^T + hasE*(bedge+bv) + bskip -> LN -> relu
// then  h1 = relu(post@w1+b1); out = log_softmax(h1@w2+b2)
#define PM 64
#define PK 576
#define PAPAD 584
#define HAPAD 264
#define H1PAD 136
__global__ __launch_bounds__(256) void k_posthead(
    const u16* __restrict__ zng, const u16* __restrict__ yng, const u16* __restrict__ x1g,
    const u16* __restrict__ Bt, const float* __restrict__ bfac,
    const float* __restrict__ bedge, const float* __restrict__ bv, const float* __restrict__ bskip,
    const float* __restrict__ lng, const float* __restrict__ lnb,
    const u16* __restrict__ Bt1, const float* __restrict__ b1,
    const float* __restrict__ w2, const float* __restrict__ b2,
    float* __restrict__ outg) {
  __shared__ u16 As[PM * PAPAD];          // staging for post-GEMM; later aliased: postL | h1s
  __shared__ float ps1[PM * 4];
  __shared__ float ps2[PM * 4];
  const int t = threadIdx.x;
  const int w = t >> 6, l = t & 63;
  const int quad = l >> 4, li = l & 15;
  const int n0 = blockIdx.x * PM;
  const f32x4 zc = {0.f, 0.f, 0.f, 0.f};

  for (int q = t; q < 2048; q += 256) {
    int row = q >> 5, off = (q & 31) * 8;
    uint4 vz = make_uint4(0, 0, 0, 0), vy = make_uint4(0, 0, 0, 0);
    if (n0 + row < NN) {
      vz = *(const uint4*)(zng + (size_t)(n0 + row) * 256 + off);
      vy = *(const uint4*)(yng + (size_t)(n0 + row) * 256 + off);
    }
    *(uint4*)(As + row * PAPAD + off) = vz;
    *(uint4*)(As + row * PAPAD + 256 + off) = vy;
  }
  for (int q = t; q < 512; q += 256) {
    int row = q >> 3, off = (q & 7) * 8;
    uint4 v = make_uint4(0, 0, 0, 0);
    if (n0 + row < NN) v = *(const uint4*)(x1g + (size_t)(n0 + row) * 64 + off);
    *(uint4*)(As + row * PAPAD + 512 + off) = v;
  }
  __syncthreads();

  f32x4 acc[4][4];
  #pragma unroll
  for (int mt = 0; mt < 4; ++mt)
    #pragma unroll
    for (int nt = 0; nt < 4; ++nt) acc[mt][nt] = zc;

  const int colbase = w * 64;
  #pragma unroll
  for (int s = 0; s < 18; ++s) {
    bf16x8 bf[4];
    #pragma unroll
    for (int nt = 0; nt < 4; ++nt)
      bf[nt] = *(const bf16x8*)(Bt + (size_t)(colbase + nt * 16 + li) * PK + s * 32 + quad * 8);
    #pragma unroll
    for (int mt = 0; mt < 4; ++mt) {
      bf16x8 af = *(const bf16x8*)(As + (mt * 16 + li) * PAPAD + s * 32 + quad * 8);
      #pragma unroll
      for (int nt = 0; nt < 4; ++nt)
        acc[mt][nt] = __builtin_amdgcn_mfma_f32_16x16x32_bf16(af, bf[nt], acc[mt][nt], 0, 0, 0);
    }
  }

  float beb[4], bs4[4], g4[4], lb4[4];
  #pragma unroll
  for (int nt = 0; nt < 4; ++nt) {
    int col = colbase + nt * 16 + li;
    beb[nt] = bedge[col] + bv[col];
    bs4[nt] = bskip[col]; g4[nt] = lng[col]; lb4[nt] = lnb[col];
  }
  #pragma unroll
  for (int mt = 0; mt < 4; ++mt) {
    #pragma unroll
    for (int r = 0; r < 4; ++r) {
      int node = n0 + mt * 16 + quad * 4 + r;
      float hasE = bfac[min(node, NN - 1)];
      #pragma unroll
      for (int nt = 0; nt < 4; ++nt)
        acc[mt][nt][r] += hasE * beb[nt] + bs4[nt];
    }
  }
  #pragma unroll
  for (int mt = 0; mt < 4; ++mt)
    #pragma unroll
    for (int r = 0; r < 4; ++r) {
      float s = acc[mt][0][r] + acc[mt][1][r] + acc[mt][2][r] + acc[mt][3][r];
      #pragma unroll
      for (int mk = 1; mk < 16; mk <<= 1) s += __shfl_xor(s, mk);
      if (li == 0) ps1[(mt * 16 + quad * 4 + r) * 4 + w] = s;
    }
  __syncthreads();
  float mu[4][4];
  #pragma unroll
  for (int mt = 0; mt < 4; ++mt)
    #pragma unroll
    for (int r = 0; r < 4; ++r) {
      float4 p = *(const float4*)(ps1 + (mt * 16 + quad * 4 + r) * 4);
      mu[mt][r] = (p.x + p.y + p.z + p.w) * (1.0f / 256.0f);
    }
  #pragma unroll
  for (int mt = 0; mt < 4; ++mt)
    #pragma unroll
    for (int r = 0; r < 4; ++r) {
      float m = mu[mt][r];
      float s = 0.f;
      #pragma unroll
      for (int nt = 0; nt < 4; ++nt) { float dd = acc[mt][nt][r] - m; s += dd * dd; }
      #pragma unroll
      for (int mk = 1; mk < 16; mk <<= 1) s += __shfl_xor(s, mk);
      if (li == 0) ps2[(mt * 16 + quad * 4 + r) * 4 + w] = s;
    }
  __syncthreads();
  // alias post tile + h1 over the (now dead) As buffer
  u16* postL = As;                        // 64 x HAPAD
  u16* h1s   = As + 64 * HAPAD;           // 64 x H1PAD
  #pragma unroll
  for (int mt = 0; mt < 4; ++mt)
    #pragma unroll
    for (int r = 0; r < 4; ++r) {
      float4 p = *(const float4*)(ps2 + (mt * 16 + quad * 4 + r) * 4);
      float rstd = rsqrtf((p.x + p.y + p.z + p.w) * (1.0f / 256.0f) + 1e-5f);
      float m = mu[mt][r];
      int row = mt * 16 + quad * 4 + r;
      #pragma unroll
      for (int nt = 0; nt < 4; ++nt) {
        int col = colbase + nt * 16 + li;
        postL[row * HAPAD + col] =
            f2bf(fmaxf((acc[mt][nt][r] - m) * rstd * g4[nt] + lb4[nt], 0.f));
      }
    }
  __syncthreads();

  // ---- head layer 1: h1 = relu(post @ w1 + b1) ----
  {
    f32x4 hacc[4][2];
    #pragma unroll
    for (int mt = 0; mt < 4; ++mt)
      #pragma unroll
      for (int nt = 0; nt < 2; ++nt) hacc[mt][nt] = zc;
    const int hcb = w * 32;
    #pragma unroll
    for (int s = 0; s < 8; ++s) {
      bf16x8 bf[2];
      #pragma unroll
      for (int nt = 0; nt < 2; ++nt)
        bf[nt] = *(const bf16x8*)(Bt1 + (size_t)(hcb + nt * 16 + li) * 256 + s * 32 + quad * 8);
      #pragma unroll
      for (int mt = 0; mt < 4; ++mt) {
        bf16x8 af = *(const bf16x8*)(postL + (mt * 16 + li) * HAPAD + s * 32 + quad * 8);
        #pragma unroll
        for (int nt = 0; nt < 2; ++nt)
          hacc[mt][nt] = __builtin_amdgcn_mfma_f32_16x16x32_bf16(af, bf[nt], hacc[mt][nt], 0, 0, 0);
      }
    }
    float b1c[2];
    #pragma unroll
    for (int nt = 0; nt < 2; ++nt) b1c[nt] = b1[hcb + nt * 16 + li];
    #pragma unroll
    for (int mt = 0; mt < 4; ++mt)
      #pragma unroll
      for (int nt = 0; nt < 2; ++nt)
        #pragma unroll
        for (int r = 0; r < 4; ++r)
          h1s[(mt * 16 + quad * 4 + r) * H1PAD + hcb + nt * 16 + li] =
              f2bf(fmaxf(hacc[mt][nt][r] + b1c[nt], 0.f));
  }
  __syncthreads();

  // ---- head layer 2 + log_softmax ----
  const int node = t >> 2, c = t & 3;
  float lg = b2[c];
  const u16* hrow = h1s + node * H1PAD;
  #pragma unroll 4
  for (int j = 0; j < 128; ++j) lg += bf2f(hrow[j]) * w2[j * 4 + c];
  float mx = lg;
  #pragma unroll
  for (int mk = 1; mk < 4; mk <<= 1) mx = fmaxf(mx, __shfl_xor(mx, mk));
  float ex = __expf(lg - mx);
  float se = ex;
  #pragma unroll
  for (int mk = 1; mk < 4; mk <<= 1) se += __shfl_xor(se, mk);
  float res = lg - (mx + __logf(se));
  if (n0 + node < NN) outg[(size_t)(n0 + node) * 4 + c] = res;
}

extern "C" void kernel_launch(void* const* d_in, const int* in_sizes, int n_in,
                              void* d_out, int out_size, void* d_ws, size_t ws_size,
                              hipStream_t stream) {
  const float* x     = (const float*)d_in[0];
  const int*   ei    = (const int*)d_in[1];
  const float* ea    = (const float*)d_in[2];
  const float* w00   = (const float*)d_in[3];
  const float* b00   = (const float*)d_in[4];
  const float* we1   = (const float*)d_in[5];
  const float* be1   = (const float*)d_in[6];
  const float* we2   = (const float*)d_in[7];
  const float* be2   = (const float*)d_in[8];
  const float* we3   = (const float*)d_in[9];
  const float* be3   = (const float*)d_in[10];
  const float* wq    = (const float*)d_in[11];
  const float* bq    = (const float*)d_in[12];
  const float* wk    = (const float*)d_in[13];
  const float* bk    = (const float*)d_in[14];
  const float* wv    = (const float*)d_in[15];
  const float* bv    = (const float*)d_in[16];
  const float* wedge = (const float*)d_in[17];
  const float* bedge = (const float*)d_in[18];
  const float* wskip = (const float*)d_in[19];
  const float* bskip = (const float*)d_in[20];
  const float* lng   = (const float*)d_in[21];
  const float* lnb   = (const float*)d_in[22];
  const float* w1    = (const float*)d_in[23];
  const float* b1    = (const float*)d_in[24];
  const float* w2    = (const float*)d_in[25];
  const float* b2    = (const float*)d_in[26];
  float* outg = (float*)d_out;
  (void)bk;

  size_t off = 0;
  char* wsb = (char*)d_ws;
  auto carve = [&](size_t bytes) -> char* {
    char* r = wsb + off;
    off += (bytes + 255) & ~(size_t)255;
    return r;
  };
  u16* yg     = (u16*)carve((size_t)NN * 256 * 2);      // yn
  u16* Gg     = (u16*)carve((size_t)NN * 256 * 2);      // G -> zn
  u16* Qkg    = (u16*)carve((size_t)NN * 256 * 2);      // Qk
  u16* x1g    = (u16*)carve((size_t)NN * 64 * 2);
  u16* e3g    = (u16*)carve((size_t)(NE + 1) * 64 * 2); // e3 in CSR order (+1 scratch row)
  int* deg    = (int*)carve((size_t)NN * 4);
  int* rowptr = (int*)carve((size_t)(NN + 1) * 4);
  int* cursor = (int*)carve((size_t)NN * 4);
  int* slist  = (int*)carve((size_t)NE * 4);
  int* e2p    = (int*)carve((size_t)NE * 4);
  float* bfac = (float*)carve((size_t)NN * 4);
  int* bsum   = (int*)carve((size_t)SCAN_NB * 4);
  int* boff   = (int*)carve((size_t)SCAN_NB * 4);
  u16* wB00t  = (u16*)carve(2048 * 2);
  u16* wqt    = (u16*)carve(16384 * 2);
  u16* BGQ    = (u16*)carve((size_t)131072 * 2);
  u16* wB1t   = (u16*)carve(512 * 2);
  u16* wB2t   = (u16*)carve(4096 * 2);
  u16* wB3t   = (u16*)carve(4096 * 2);
  u16* Bt     = (u16*)carve((size_t)256 * 576 * 2);
  u16* Bt1    = (u16*)carve((size_t)128 * 256 * 2);
  if (off > ws_size) return;

  k_prep_all<<<(PREP_TOTAL + 255) / 256, 256, 0, stream>>>(
      w00, wq, wedge, wk, we1, we2, we3, wv, wskip, w1,
      wB00t, wqt, BGQ, wB1t, wB2t, wB3t, Bt, Bt1, deg);
  k_hist<<<NE / 256, 256, 0, stream>>>(ei, deg);
  k_scan_a<<<SCAN_NB, 256, 0, stream>>>(deg, bsum);
  k_scan_b<<<1, 256, 0, stream>>>(bsum, boff, rowptr);
  k_scan_c<<<SCAN_NB, 256, 0, stream>>>(deg, boff, rowptr, cursor);
  k_scatter<<<NE / 256, 256, 0, stream>>>(ei, cursor, slist, e2p);
  k_ng<<<(NN + 63) / 64, 256, 0, stream>>>(x, wB00t, b00, wqt, bq, BGQ, x1g, Gg, Qkg);
  k_edge_mlp<<<NE / EPB, 256, 0, stream>>>(ea, wB1t, wB2t, wB3t, be1, be2, be3, e2p, e3g);
  k_attn<<<NN / 4, 256, 0, stream>>>(rowptr, slist, yg, x1g, Gg, Qkg, e3g, bfac);
  k_posthead<<<(NN + PM - 1) / PM, 256, 0, stream>>>(
      Gg, yg, x1g, Bt, bfac, bedge, bv, bskip, lng, lnb, Bt1, b1, w2, b2, outg);
}